// Round 1
// baseline (1193.607 us; speedup 1.0000x reference)
//
#include <hip/hip_runtime.h>

#define BB   4
#define LL   2048
#define DD   512
#define HH   8
#define DH   64
#define BH   32          // B*H
#define KTOP 38
#define SCALEF 0.125f    // 1/sqrt(64)

// ---------------------------------------------------------------------------
// GEMM: Y = x @ W + b, output permuted to [BH, L, DH] layout.
// x: [B*L, D] row-major, W: [D, D] row-major, b: [D]
// Y[((b*H + h)*L + l)*DH + dh]  where r = b*L + l, c = h*DH + dh
// 64x64 tile, BK=16, 256 threads, 4x4 per thread. fp32.
// ---------------------------------------------------------------------------
__global__ __launch_bounds__(256) void gemm_proj(const float* __restrict__ X,
                                                 const float* __restrict__ W,
                                                 const float* __restrict__ bias,
                                                 float* __restrict__ Y) {
    __shared__ float As[64][17];   // +1 pad breaks 4-way bank conflict on a-reads
    __shared__ float Bs[16][65];
    const int t  = threadIdx.x;
    const int tx = t & 15, ty = t >> 4;
    const int row0 = blockIdx.y * 64;
    const int col0 = blockIdx.x * 64;

    float acc[4][4] = {};
    for (int k0 = 0; k0 < DD; k0 += 16) {
        // A tile: 64 rows x 16 k, float4 per thread
        {
            int e  = t * 4;
            int rr = e >> 4, kk = e & 15;
            const float4 v = *(const float4*)&X[(size_t)(row0 + rr) * DD + k0 + kk];
            As[rr][kk + 0] = v.x; As[rr][kk + 1] = v.y;
            As[rr][kk + 2] = v.z; As[rr][kk + 3] = v.w;
        }
        // B tile: 16 k x 64 cols
        {
            int e  = t * 4;
            int kk = e >> 6, cc = e & 63;
            const float4 v = *(const float4*)&W[(size_t)(k0 + kk) * DD + col0 + cc];
            Bs[kk][cc + 0] = v.x; Bs[kk][cc + 1] = v.y;
            Bs[kk][cc + 2] = v.z; Bs[kk][cc + 3] = v.w;
        }
        __syncthreads();
        #pragma unroll
        for (int kk = 0; kk < 16; kk++) {
            float a[4], b[4];
            #pragma unroll
            for (int i = 0; i < 4; i++) a[i] = As[ty * 4 + i][kk];
            #pragma unroll
            for (int j = 0; j < 4; j++) b[j] = Bs[kk][tx * 4 + j];
            #pragma unroll
            for (int i = 0; i < 4; i++)
                #pragma unroll
                for (int j = 0; j < 4; j++) acc[i][j] += a[i] * b[j];
        }
        __syncthreads();
    }
    #pragma unroll
    for (int i = 0; i < 4; i++) {
        int r = row0 + ty * 4 + i;
        int b = r / LL, l = r % LL;
        #pragma unroll
        for (int j = 0; j < 4; j++) {
            int c  = col0 + tx * 4 + j;
            int h  = c >> 6, dh = c & 63;
            Y[(((size_t)(b * HH + h) * LL) + l) * DH + dh] = acc[i][j] + bias[c];
        }
    }
}

// ---------------------------------------------------------------------------
// Output GEMM: out = context_merged @ Wo + bo.
// context stored [BH, L, DH]; logical A[r][k] = ctx[((b*H + k/64)*L + l)*64 + k%64]
// ---------------------------------------------------------------------------
__global__ __launch_bounds__(256) void gemm_out(const float* __restrict__ CTX,
                                                const float* __restrict__ W,
                                                const float* __restrict__ bias,
                                                float* __restrict__ OUT) {
    __shared__ float As[64][17];
    __shared__ float Bs[16][65];
    const int t  = threadIdx.x;
    const int tx = t & 15, ty = t >> 4;
    const int row0 = blockIdx.y * 64;
    const int col0 = blockIdx.x * 64;

    float acc[4][4] = {};
    for (int k0 = 0; k0 < DD; k0 += 16) {
        {
            int e  = t * 4;
            int rr = e >> 4, kk = e & 15;      // kk in {0,4,8,12}; k0 multiple of 16
            int r  = row0 + rr;
            int b  = r / LL, l = r % LL;
            int k  = k0 + kk;
            int h  = k >> 6, dh = k & 63;      // dh..dh+3 within one head chunk
            const float4 v = *(const float4*)&CTX[(((size_t)(b * HH + h) * LL) + l) * DH + dh];
            As[rr][kk + 0] = v.x; As[rr][kk + 1] = v.y;
            As[rr][kk + 2] = v.z; As[rr][kk + 3] = v.w;
        }
        {
            int e  = t * 4;
            int kk = e >> 6, cc = e & 63;
            const float4 v = *(const float4*)&W[(size_t)(k0 + kk) * DD + col0 + cc];
            Bs[kk][cc + 0] = v.x; Bs[kk][cc + 1] = v.y;
            Bs[kk][cc + 2] = v.z; Bs[kk][cc + 3] = v.w;
        }
        __syncthreads();
        #pragma unroll
        for (int kk = 0; kk < 16; kk++) {
            float a[4], b[4];
            #pragma unroll
            for (int i = 0; i < 4; i++) a[i] = As[ty * 4 + i][kk];
            #pragma unroll
            for (int j = 0; j < 4; j++) b[j] = Bs[kk][tx * 4 + j];
            #pragma unroll
            for (int i = 0; i < 4; i++)
                #pragma unroll
                for (int j = 0; j < 4; j++) acc[i][j] += a[i] * b[j];
        }
        __syncthreads();
    }
    #pragma unroll
    for (int i = 0; i < 4; i++) {
        int r = row0 + ty * 4 + i;
        #pragma unroll
        for (int j = 0; j < 4; j++) {
            int c = col0 + tx * 4 + j;
            OUT[(size_t)r * DD + c] = acc[i][j] + bias[c];
        }
    }
}

// ---------------------------------------------------------------------------
// Per-head mean of K and V over L: out[bh][d]
// grid (BH, 2): y==0 -> Kmean, y==1 -> Vmean. 256 threads: 64 d x 4 l-chunks.
// ---------------------------------------------------------------------------
__global__ __launch_bounds__(256) void mean_kernel(const float* __restrict__ Kp,
                                                   const float* __restrict__ Vp,
                                                   float* __restrict__ Kmean,
                                                   float* __restrict__ Vmean) {
    __shared__ float red[256];
    const int bh = blockIdx.x;
    const float* src = blockIdx.y ? Vp : Kp;
    float* dst       = blockIdx.y ? Vmean : Kmean;
    const int t = threadIdx.x;
    const int d = t & 63, ch = t >> 6;
    float s = 0.f;
    for (int l = ch * (LL / 4); l < (ch + 1) * (LL / 4); l++)
        s += src[((size_t)bh * LL + l) * DH + d];
    red[t] = s;
    __syncthreads();
    if (t < 64)
        dst[bh * DH + d] = (red[t] + red[t + 64] + red[t + 128] + red[t + 192]) * (1.0f / LL);
}

// ---------------------------------------------------------------------------
// M[bh][q] = SCALE * max_k (Q[q].K[k])  -  SCALE * (Q[q].Kmean)
// Block: (q-tile 64, bh). 256 threads 16x16, 4 q x 4 k per thread per K-tile,
// full DH=64 dot per pair, running max; never materializes scores.
// ---------------------------------------------------------------------------
__global__ __launch_bounds__(256) void stats_kernel(const float* __restrict__ Q,
                                                    const float* __restrict__ K,
                                                    const float* __restrict__ Kmean,
                                                    float* __restrict__ M) {
    __shared__ float Qs[64][65];
    __shared__ float Ks[64][65];
    __shared__ float Km[64];
    const int bh = blockIdx.y;
    const int q0 = blockIdx.x * 64;
    const int t  = threadIdx.x;
    const int tx = t & 15, ty = t >> 4;

    // load Q tile (64 q x 64 d)
    #pragma unroll
    for (int i = 0; i < 4; i++) {
        int e = t * 4 + i * 1024;
        int q = e >> 6, d = e & 63;
        const float4 v = *(const float4*)&Q[((size_t)bh * LL + q0 + q) * DH + d];
        Qs[q][d + 0] = v.x; Qs[q][d + 1] = v.y; Qs[q][d + 2] = v.z; Qs[q][d + 3] = v.w;
    }
    if (t < 64) Km[t] = Kmean[bh * DH + t];

    float maxv[4] = {-3.4e38f, -3.4e38f, -3.4e38f, -3.4e38f};

    for (int kt = 0; kt < LL / 64; kt++) {
        __syncthreads();
        #pragma unroll
        for (int i = 0; i < 4; i++) {
            int e = t * 4 + i * 1024;
            int k = e >> 6, d = e & 63;
            const float4 v = *(const float4*)&K[((size_t)bh * LL + kt * 64 + k) * DH + d];
            Ks[k][d + 0] = v.x; Ks[k][d + 1] = v.y; Ks[k][d + 2] = v.z; Ks[k][d + 3] = v.w;
        }
        __syncthreads();
        float acc[4][4] = {};
        #pragma unroll 8
        for (int dd = 0; dd < 64; dd++) {
            float a[4], b[4];
            #pragma unroll
            for (int i = 0; i < 4; i++) a[i] = Qs[ty * 4 + i][dd];
            #pragma unroll
            for (int j = 0; j < 4; j++) b[j] = Ks[tx * 4 + j][dd];
            #pragma unroll
            for (int i = 0; i < 4; i++)
                #pragma unroll
                for (int j = 0; j < 4; j++) acc[i][j] += a[i] * b[j];
        }
        #pragma unroll
        for (int i = 0; i < 4; i++)
            #pragma unroll
            for (int j = 0; j < 4; j++) maxv[i] = fmaxf(maxv[i], acc[i][j]);
    }

    // reduce max across the 16 tx lanes (contiguous within a wave)
    #pragma unroll
    for (int off = 8; off >= 1; off >>= 1)
        #pragma unroll
        for (int i = 0; i < 4; i++)
            maxv[i] = fmaxf(maxv[i], __shfl_xor(maxv[i], off));

    if (tx == 0) {
        #pragma unroll
        for (int i = 0; i < 4; i++) {
            int qr = ty * 4 + i;
            float md = 0.f;
            for (int d = 0; d < 64; d++) md += Qs[qr][d] * Km[d];
            M[(size_t)bh * LL + q0 + qr] = SCALEF * maxv[i] - SCALEF * md;
        }
    }
}

// ---------------------------------------------------------------------------
// Top-38 per head via iterative block argmax (lowest index wins ties, matching
// lax.top_k first-occurrence). One block per bh.
// ---------------------------------------------------------------------------
__global__ __launch_bounds__(256) void topk_kernel(const float* __restrict__ M,
                                                   int* __restrict__ top_idx) {
    __shared__ float vals[LL];
    __shared__ float rv[256];
    __shared__ int   ri[256];
    const int bh = blockIdx.x;
    const int t  = threadIdx.x;
    for (int i = t; i < LL; i += 256) vals[i] = M[(size_t)bh * LL + i];
    __syncthreads();
    for (int it = 0; it < KTOP; it++) {
        float best = -3.4e38f; int bi = LL;
        for (int i = t; i < LL; i += 256) {
            float v = vals[i];
            if (v > best) { best = v; bi = i; }   // scan order ascending -> first occurrence
        }
        rv[t] = best; ri[t] = bi;
        __syncthreads();
        for (int s = 128; s > 0; s >>= 1) {
            if (t < s) {
                if (rv[t + s] > rv[t] || (rv[t + s] == rv[t] && ri[t + s] < ri[t])) {
                    rv[t] = rv[t + s]; ri[t] = ri[t + s];
                }
            }
            __syncthreads();
        }
        if (t == 0) { top_idx[bh * KTOP + it] = ri[0]; vals[ri[0]] = -3.4e38f; }
        __syncthreads();
    }
}

// ---------------------------------------------------------------------------
// Fill context with per-head V mean.
// ---------------------------------------------------------------------------
__global__ __launch_bounds__(256) void fill_kernel(const float* __restrict__ Vmean,
                                                   float* __restrict__ CTX) {
    size_t idx = (size_t)blockIdx.x * 256 + threadIdx.x;   // over BH*L*DH
    int d  = idx & 63;
    int bh = (int)(idx >> 17);                              // / (2048*64)
    CTX[idx] = Vmean[bh * DH + d];
}

// ---------------------------------------------------------------------------
// Sparse attention for one (bh, topk-slot): softmax(SCALE*Q[q].K) @ V,
// scattered into CTX at row q. Scores live in LDS (2048 floats).
// ---------------------------------------------------------------------------
__global__ __launch_bounds__(256) void sparse_kernel(const float* __restrict__ Q,
                                                     const float* __restrict__ K,
                                                     const float* __restrict__ V,
                                                     const int* __restrict__ top_idx,
                                                     float* __restrict__ CTX) {
    __shared__ float sc[LL];
    __shared__ float qrow[DH];
    __shared__ float red[256];
    const int bh = blockIdx.y;
    const int q  = top_idx[bh * KTOP + blockIdx.x];
    const int t  = threadIdx.x;

    if (t < DH) qrow[t] = Q[((size_t)bh * LL + q) * DH + t];
    __syncthreads();

    float lmax = -3.4e38f;
    for (int k = t; k < LL; k += 256) {
        const float* kr = &K[((size_t)bh * LL + k) * DH];
        float s = 0.f;
        #pragma unroll 16
        for (int d = 0; d < DH; d++) s += qrow[d] * kr[d];
        s *= SCALEF;
        sc[k] = s;
        lmax = fmaxf(lmax, s);
    }
    red[t] = lmax; __syncthreads();
    for (int s = 128; s > 0; s >>= 1) {
        if (t < s) red[t] = fmaxf(red[t], red[t + s]);
        __syncthreads();
    }
    const float mx = red[0];
    __syncthreads();

    float lsum = 0.f;
    for (int k = t; k < LL; k += 256) {
        float e = __expf(sc[k] - mx);
        sc[k] = e;
        lsum += e;
    }
    red[t] = lsum; __syncthreads();
    for (int s = 128; s > 0; s >>= 1) {
        if (t < s) red[t] += red[t + s];
        __syncthreads();
    }
    const float inv = 1.0f / red[0];
    __syncthreads();

    // weighted V sum: 64 d-lanes x 4 k-chunks
    const int d = t & 63, ch = t >> 6;
    float acc = 0.f;
    for (int k = ch * (LL / 4); k < (ch + 1) * (LL / 4); k++)
        acc += sc[k] * V[((size_t)bh * LL + k) * DH + d];
    red[t] = acc; __syncthreads();
    if (t < 64) {
        float r = red[t] + red[t + 64] + red[t + 128] + red[t + 192];
        CTX[((size_t)bh * LL + q) * DH + d] = r * inv;
    }
}

// ---------------------------------------------------------------------------
extern "C" void kernel_launch(void* const* d_in, const int* in_sizes, int n_in,
                              void* d_out, int out_size, void* d_ws, size_t ws_size,
                              hipStream_t stream) {
    const float* x  = (const float*)d_in[0];
    const float* Wq = (const float*)d_in[1];
    const float* bq = (const float*)d_in[2];
    const float* Wk = (const float*)d_in[3];
    const float* bk = (const float*)d_in[4];
    const float* Wv = (const float*)d_in[5];
    const float* bv = (const float*)d_in[6];
    const float* Wo = (const float*)d_in[7];
    const float* bo = (const float*)d_in[8];
    float* out = (float*)d_out;

    float* ws = (float*)d_ws;
    const size_t QSZ = (size_t)BH * LL * DH;   // 4,194,304 floats
    float* Qp    = ws;
    float* Kp    = ws + QSZ;
    float* Vp    = ws + 2 * QSZ;
    float* CTX   = ws + 3 * QSZ;
    float* Mp    = ws + 4 * QSZ;               // BH*L
    float* KMEAN = Mp + (size_t)BH * LL;       // BH*DH
    float* VMEAN = KMEAN + BH * DH;
    int*   TIDX  = (int*)(VMEAN + BH * DH);    // BH*KTOP

    const dim3 gemm_grid(DD / 64, (BB * LL) / 64);   // (8, 128)

    gemm_proj<<<gemm_grid, 256, 0, stream>>>(x, Wq, bq, Qp);
    gemm_proj<<<gemm_grid, 256, 0, stream>>>(x, Wk, bk, Kp);
    gemm_proj<<<gemm_grid, 256, 0, stream>>>(x, Wv, bv, Vp);

    mean_kernel<<<dim3(BH, 2), 256, 0, stream>>>(Kp, Vp, KMEAN, VMEAN);

    stats_kernel<<<dim3(LL / 64, BH), 256, 0, stream>>>(Qp, Kp, KMEAN, Mp);

    topk_kernel<<<BH, 256, 0, stream>>>(Mp, TIDX);

    fill_kernel<<<(BH * LL * DH) / 256, 256, 0, stream>>>(VMEAN, CTX);

    sparse_kernel<<<dim3(KTOP, BH), 256, 0, stream>>>(Qp, Kp, Vp, TIDX, CTX);

    gemm_out<<<gemm_grid, 256, 0, stream>>>(CTX, Wo, bo, out);
}

// Round 2
// 1142.837 us; speedup vs baseline: 1.0444x; 1.0444x over previous
//
#include <hip/hip_runtime.h>

#define BB   4
#define LL   2048
#define DD   512
#define HH   8
#define DH   64
#define BH   32          // B*H
#define KTOP 38
#define NCAND 64         // approx-M candidate pool for exact refinement
#define SCALEF 0.125f    // 1/sqrt(64)

typedef __attribute__((ext_vector_type(8))) short bf16x8;
typedef __attribute__((ext_vector_type(4))) float f32x4;

__device__ __forceinline__ ushort f32_to_bf16_rn(float x) {
    unsigned u = __float_as_uint(x);
    u += 0x7fffu + ((u >> 16) & 1u);
    return (ushort)(u >> 16);
}
__device__ __forceinline__ float bf16_to_f32(ushort h) {
    return __uint_as_float(((unsigned)h) << 16);
}

// ---------------------------------------------------------------------------
// GEMM: Y = x @ W + b, output permuted to [BH, L, DH] layout. (unchanged R1)
// ---------------------------------------------------------------------------
__global__ __launch_bounds__(256) void gemm_proj(const float* __restrict__ X,
                                                 const float* __restrict__ W,
                                                 const float* __restrict__ bias,
                                                 float* __restrict__ Y) {
    __shared__ float As[64][17];
    __shared__ float Bs[16][65];
    const int t  = threadIdx.x;
    const int tx = t & 15, ty = t >> 4;
    const int row0 = blockIdx.y * 64;
    const int col0 = blockIdx.x * 64;

    float acc[4][4] = {};
    for (int k0 = 0; k0 < DD; k0 += 16) {
        {
            int e  = t * 4;
            int rr = e >> 4, kk = e & 15;
            const float4 v = *(const float4*)&X[(size_t)(row0 + rr) * DD + k0 + kk];
            As[rr][kk + 0] = v.x; As[rr][kk + 1] = v.y;
            As[rr][kk + 2] = v.z; As[rr][kk + 3] = v.w;
        }
        {
            int e  = t * 4;
            int kk = e >> 6, cc = e & 63;
            const float4 v = *(const float4*)&W[(size_t)(k0 + kk) * DD + col0 + cc];
            Bs[kk][cc + 0] = v.x; Bs[kk][cc + 1] = v.y;
            Bs[kk][cc + 2] = v.z; Bs[kk][cc + 3] = v.w;
        }
        __syncthreads();
        #pragma unroll
        for (int kk = 0; kk < 16; kk++) {
            float a[4], b[4];
            #pragma unroll
            for (int i = 0; i < 4; i++) a[i] = As[ty * 4 + i][kk];
            #pragma unroll
            for (int j = 0; j < 4; j++) b[j] = Bs[kk][tx * 4 + j];
            #pragma unroll
            for (int i = 0; i < 4; i++)
                #pragma unroll
                for (int j = 0; j < 4; j++) acc[i][j] += a[i] * b[j];
        }
        __syncthreads();
    }
    #pragma unroll
    for (int i = 0; i < 4; i++) {
        int r = row0 + ty * 4 + i;
        int b = r / LL, l = r % LL;
        #pragma unroll
        for (int j = 0; j < 4; j++) {
            int c  = col0 + tx * 4 + j;
            int h  = c >> 6, dh = c & 63;
            Y[(((size_t)(b * HH + h) * LL) + l) * DH + dh] = acc[i][j] + bias[c];
        }
    }
}

// ---------------------------------------------------------------------------
// Output GEMM: out = context_merged @ Wo + bo. (unchanged R1)
// ---------------------------------------------------------------------------
__global__ __launch_bounds__(256) void gemm_out(const float* __restrict__ CTX,
                                                const float* __restrict__ W,
                                                const float* __restrict__ bias,
                                                float* __restrict__ OUT) {
    __shared__ float As[64][17];
    __shared__ float Bs[16][65];
    const int t  = threadIdx.x;
    const int tx = t & 15, ty = t >> 4;
    const int row0 = blockIdx.y * 64;
    const int col0 = blockIdx.x * 64;

    float acc[4][4] = {};
    for (int k0 = 0; k0 < DD; k0 += 16) {
        {
            int e  = t * 4;
            int rr = e >> 4, kk = e & 15;
            int r  = row0 + rr;
            int b  = r / LL, l = r % LL;
            int k  = k0 + kk;
            int h  = k >> 6, dh = k & 63;
            const float4 v = *(const float4*)&CTX[(((size_t)(b * HH + h) * LL) + l) * DH + dh];
            As[rr][kk + 0] = v.x; As[rr][kk + 1] = v.y;
            As[rr][kk + 2] = v.z; As[rr][kk + 3] = v.w;
        }
        {
            int e  = t * 4;
            int kk = e >> 6, cc = e & 63;
            const float4 v = *(const float4*)&W[(size_t)(k0 + kk) * DD + col0 + cc];
            Bs[kk][cc + 0] = v.x; Bs[kk][cc + 1] = v.y;
            Bs[kk][cc + 2] = v.z; Bs[kk][cc + 3] = v.w;
        }
        __syncthreads();
        #pragma unroll
        for (int kk = 0; kk < 16; kk++) {
            float a[4], b[4];
            #pragma unroll
            for (int i = 0; i < 4; i++) a[i] = As[ty * 4 + i][kk];
            #pragma unroll
            for (int j = 0; j < 4; j++) b[j] = Bs[kk][tx * 4 + j];
            #pragma unroll
            for (int i = 0; i < 4; i++)
                #pragma unroll
                for (int j = 0; j < 4; j++) acc[i][j] += a[i] * b[j];
        }
        __syncthreads();
    }
    #pragma unroll
    for (int i = 0; i < 4; i++) {
        int r = row0 + ty * 4 + i;
        #pragma unroll
        for (int j = 0; j < 4; j++) {
            int c = col0 + tx * 4 + j;
            OUT[(size_t)r * DD + c] = acc[i][j] + bias[c];
        }
    }
}

// ---------------------------------------------------------------------------
// Per-head mean of K and V over L. (unchanged R1)
// ---------------------------------------------------------------------------
__global__ __launch_bounds__(256) void mean_kernel(const float* __restrict__ Kp,
                                                   const float* __restrict__ Vp,
                                                   float* __restrict__ Kmean,
                                                   float* __restrict__ Vmean) {
    __shared__ float red[256];
    const int bh = blockIdx.x;
    const float* src = blockIdx.y ? Vp : Kp;
    float* dst       = blockIdx.y ? Vmean : Kmean;
    const int t = threadIdx.x;
    const int d = t & 63, ch = t >> 6;
    float s = 0.f;
    for (int l = ch * (LL / 4); l < (ch + 1) * (LL / 4); l++)
        s += src[((size_t)bh * LL + l) * DH + d];
    red[t] = s;
    __syncthreads();
    if (t < 64)
        dst[bh * DH + d] = (red[t] + red[t + 64] + red[t + 128] + red[t + 192]) * (1.0f / LL);
}

// ---------------------------------------------------------------------------
// Approx M via split-bf16 MFMA:
//   M[bh][q] ~= SCALE*max_k(Q[q].K[k]) - SCALE*(Q[q].Kmean)
// Block: 256 thr = 4 waves, covers 64 queries (16 q per wave), all 2048 keys.
// K is converted fp32 -> bf16 hi/lo during LDS staging (128 keys per stage).
// MFMA 16x16x32 layouts (HW-verified): A[m=lane&15][k=quad*8+j],
// B[k=quad*8+j][n=lane&15], C: col=lane&15, row=quad*4+reg.
// Error ~6e-5 on pre-scale scores -> only used for CANDIDATE ranking.
// ---------------------------------------------------------------------------
__global__ __launch_bounds__(256) void mfma_stats(const float* __restrict__ Qp,
                                                  const float* __restrict__ Kp,
                                                  const float* __restrict__ Kmean,
                                                  float* __restrict__ M) {
    // 128 key rows, 72-short (144B) stride: hi region then lo region
    __shared__ ushort KS[2 * 128 * 72];
    __shared__ float  Km[64];
    __shared__ float  mdS[64];

    const int bh = blockIdx.y;
    const int q0 = blockIdx.x * 64;
    const int t    = threadIdx.x;
    const int wave = t >> 6;
    const int lane = t & 63;
    const int quad = lane >> 4;
    const int n16  = lane & 15;
    const int qbase = q0 + wave * 16;

    if (t < 64) Km[t] = Kmean[bh * DH + t];
    __syncthreads();
    // exact fp32 mean term per query (feeds approx M ordering)
    if (t < 64) {
        const float4* qr = (const float4*)&Qp[((size_t)bh * LL + q0 + t) * DH];
        const float4* km4 = (const float4*)Km;
        float md = 0.f;
        #pragma unroll
        for (int i = 0; i < 16; i++) {
            float4 a = qr[i], b = km4[i];
            md += a.x * b.x + a.y * b.y + a.z * b.z + a.w * b.w;
        }
        mdS[t] = md;
    }

    // Q fragments (hi/lo x two d-chunks), converted in registers
    bf16x8 aH0, aL0, aH1, aL1;
    {
        const float* qrp = &Qp[((size_t)bh * LL + qbase + n16) * DH + quad * 8];
        float v[16];
        *(float4*)&v[0]  = *(const float4*)(qrp);
        *(float4*)&v[4]  = *(const float4*)(qrp + 4);
        *(float4*)&v[8]  = *(const float4*)(qrp + 32);
        *(float4*)&v[12] = *(const float4*)(qrp + 36);
        #pragma unroll
        for (int j = 0; j < 8; j++) {
            ushort h0 = f32_to_bf16_rn(v[j]);
            aH0[j] = (short)h0;
            aL0[j] = (short)f32_to_bf16_rn(v[j] - bf16_to_f32(h0));
            ushort h1 = f32_to_bf16_rn(v[8 + j]);
            aH1[j] = (short)h1;
            aL1[j] = (short)f32_to_bf16_rn(v[8 + j] - bf16_to_f32(h1));
        }
    }

    float maxv[4] = {-3.4e38f, -3.4e38f, -3.4e38f, -3.4e38f};

    for (int kt0 = 0; kt0 < LL; kt0 += 128) {
        __syncthreads();   // prior tile fully consumed
        // stage 128 keys: fp32 -> bf16 hi/lo into LDS
        for (int c = t; c < 2048; c += 256) {
            int row = c >> 4, f4 = c & 15;
            const float4 v = *(const float4*)&Kp[((size_t)(bh * LL + kt0 + row)) * DH + f4 * 4];
            ushort4 h, l;
            h.x = f32_to_bf16_rn(v.x); l.x = f32_to_bf16_rn(v.x - bf16_to_f32(h.x));
            h.y = f32_to_bf16_rn(v.y); l.y = f32_to_bf16_rn(v.y - bf16_to_f32(h.y));
            h.z = f32_to_bf16_rn(v.z); l.z = f32_to_bf16_rn(v.z - bf16_to_f32(h.z));
            h.w = f32_to_bf16_rn(v.w); l.w = f32_to_bf16_rn(v.w - bf16_to_f32(h.w));
            *(ushort4*)&KS[row * 72 + f4 * 4]            = h;
            *(ushort4*)&KS[9216 + row * 72 + f4 * 4]     = l;
        }
        __syncthreads();

        for (int ktl = 0; ktl < 128; ktl += 16) {
            const ushort* bp = &KS[(size_t)(ktl + n16) * 72 + quad * 8];
            bf16x8 bH0 = *(const bf16x8*)(bp);
            bf16x8 bH1 = *(const bf16x8*)(bp + 32);
            bf16x8 bL0 = *(const bf16x8*)(bp + 9216);
            bf16x8 bL1 = *(const bf16x8*)(bp + 9216 + 32);

            f32x4 acc = {0.f, 0.f, 0.f, 0.f};
            acc = __builtin_amdgcn_mfma_f32_16x16x32_bf16(aH0, bH0, acc, 0, 0, 0);
            acc = __builtin_amdgcn_mfma_f32_16x16x32_bf16(aH1, bH1, acc, 0, 0, 0);
            acc = __builtin_amdgcn_mfma_f32_16x16x32_bf16(aH0, bL0, acc, 0, 0, 0);
            acc = __builtin_amdgcn_mfma_f32_16x16x32_bf16(aH1, bL1, acc, 0, 0, 0);
            acc = __builtin_amdgcn_mfma_f32_16x16x32_bf16(aL0, bH0, acc, 0, 0, 0);
            acc = __builtin_amdgcn_mfma_f32_16x16x32_bf16(aL1, bH1, acc, 0, 0, 0);
            acc = __builtin_amdgcn_mfma_f32_16x16x32_bf16(aL0, bL0, acc, 0, 0, 0);
            acc = __builtin_amdgcn_mfma_f32_16x16x32_bf16(aL1, bL1, acc, 0, 0, 0);

            maxv[0] = fmaxf(maxv[0], acc[0]);
            maxv[1] = fmaxf(maxv[1], acc[1]);
            maxv[2] = fmaxf(maxv[2], acc[2]);
            maxv[3] = fmaxf(maxv[3], acc[3]);
        }
    }

    // reduce max over the 16 key-columns (lanes within a quad)
    #pragma unroll
    for (int off = 1; off < 16; off <<= 1) {
        #pragma unroll
        for (int r = 0; r < 4; r++)
            maxv[r] = fmaxf(maxv[r], __shfl_xor(maxv[r], off));
    }

    if (n16 == 0) {
        #pragma unroll
        for (int r = 0; r < 4; r++) {
            int lq = wave * 16 + quad * 4 + r;
            M[(size_t)bh * LL + q0 + lq] = SCALEF * maxv[r] - SCALEF * mdS[lq];
        }
    }
}

// ---------------------------------------------------------------------------
// Iterative block argmax top-k (first occurrence wins ties). One block per bh.
// ---------------------------------------------------------------------------
__global__ __launch_bounds__(256) void topk_kernel(const float* __restrict__ M,
                                                   int* __restrict__ out_idx,
                                                   int kcount, int ostride) {
    __shared__ float vals[LL];
    __shared__ float rv[256];
    __shared__ int   ri[256];
    const int bh = blockIdx.x;
    const int t  = threadIdx.x;
    for (int i = t; i < LL; i += 256) vals[i] = M[(size_t)bh * LL + i];
    __syncthreads();
    for (int it = 0; it < kcount; it++) {
        float best = -3.4e38f; int bi = LL;
        for (int i = t; i < LL; i += 256) {
            float v = vals[i];
            if (v > best) { best = v; bi = i; }
        }
        rv[t] = best; ri[t] = bi;
        __syncthreads();
        for (int s = 128; s > 0; s >>= 1) {
            if (t < s) {
                if (rv[t + s] > rv[t] || (rv[t + s] == rv[t] && ri[t + s] < ri[t])) {
                    rv[t] = rv[t + s]; ri[t] = ri[t + s];
                }
            }
            __syncthreads();
        }
        if (t == 0) { out_idx[bh * ostride + it] = ri[0]; vals[ri[0]] = -3.4e38f; }
        __syncthreads();
    }
}

// ---------------------------------------------------------------------------
// Exact fp32 M for one candidate (grid: NCAND x BH). 256 threads stream keys.
// ---------------------------------------------------------------------------
__global__ __launch_bounds__(256) void exact_kernel(const float* __restrict__ Qp,
                                                    const float* __restrict__ Kp,
                                                    const float* __restrict__ Kmean,
                                                    const int* __restrict__ CAND,
                                                    float* __restrict__ EM) {
    __shared__ float qrow[DH];
    __shared__ float red[256];
    __shared__ int   qs;
    const int bh = blockIdx.y;
    const int j  = blockIdx.x;
    const int t  = threadIdx.x;
    if (t == 0) qs = CAND[bh * NCAND + j];
    __syncthreads();
    const int q = qs;
    if (t < DH) qrow[t] = Qp[((size_t)bh * LL + q) * DH + t];
    __syncthreads();

    float mx = -3.4e38f;
    for (int k = t; k < LL; k += 256) {
        const float4* kr = (const float4*)&Kp[((size_t)bh * LL + k) * DH];
        const float4* q4 = (const float4*)qrow;
        float s = 0.f;
        #pragma unroll
        for (int i = 0; i < 16; i++) {
            float4 kv = kr[i], qv = q4[i];
            s += qv.x * kv.x + qv.y * kv.y + qv.z * kv.z + qv.w * kv.w;
        }
        mx = fmaxf(mx, s);
    }
    red[t] = mx;
    __syncthreads();
    for (int s = 128; s > 0; s >>= 1) {
        if (t < s) red[t] = fmaxf(red[t], red[t + s]);
        __syncthreads();
    }
    if (t == 0) {
        const float4* q4 = (const float4*)qrow;
        const float4* k4 = (const float4*)&Kmean[bh * DH];
        float md = 0.f;
        #pragma unroll
        for (int i = 0; i < 16; i++) {
            float4 a = q4[i], b = k4[i];
            md += a.x * b.x + a.y * b.y + a.z * b.z + a.w * b.w;
        }
        EM[bh * NCAND + j] = SCALEF * red[0] - SCALEF * md;
    }
}

// ---------------------------------------------------------------------------
// Final top-38 among 64 candidates by exact M (value desc, index asc on ties).
// One wave per bh.
// ---------------------------------------------------------------------------
__global__ __launch_bounds__(64) void select_kernel(const float* __restrict__ EM,
                                                    const int* __restrict__ CAND,
                                                    int* __restrict__ TIDX) {
    const int bh = blockIdx.x;
    const int t  = threadIdx.x;   // 64 threads = 1 wave
    float v  = EM[bh * NCAND + t];
    int   qi = CAND[bh * NCAND + t];
    for (int it = 0; it < KTOP; it++) {
        float bv = v; int bq = qi;
        #pragma unroll
        for (int off = 1; off < 64; off <<= 1) {
            float ov = __shfl_xor(bv, off);
            int   oq = __shfl_xor(bq, off);
            if (ov > bv || (ov == bv && oq < bq)) { bv = ov; bq = oq; }
        }
        if (t == 0) TIDX[bh * KTOP + it] = bq;
        if (qi == bq) v = -3.4e38f;
    }
}

// ---------------------------------------------------------------------------
// Fill context with per-head V mean. (unchanged R1)
// ---------------------------------------------------------------------------
__global__ __launch_bounds__(256) void fill_kernel(const float* __restrict__ Vmean,
                                                   float* __restrict__ CTX) {
    size_t idx = (size_t)blockIdx.x * 256 + threadIdx.x;
    int d  = idx & 63;
    int bh = (int)(idx >> 17);
    CTX[idx] = Vmean[bh * DH + d];
}

// ---------------------------------------------------------------------------
// Sparse attention per (bh, topk-slot). (unchanged R1)
// ---------------------------------------------------------------------------
__global__ __launch_bounds__(256) void sparse_kernel(const float* __restrict__ Q,
                                                     const float* __restrict__ K,
                                                     const float* __restrict__ V,
                                                     const int* __restrict__ top_idx,
                                                     float* __restrict__ CTX) {
    __shared__ float sc[LL];
    __shared__ float qrow[DH];
    __shared__ float red[256];
    const int bh = blockIdx.y;
    const int q  = top_idx[bh * KTOP + blockIdx.x];
    const int t  = threadIdx.x;

    if (t < DH) qrow[t] = Q[((size_t)bh * LL + q) * DH + t];
    __syncthreads();

    float lmax = -3.4e38f;
    for (int k = t; k < LL; k += 256) {
        const float* kr = &K[((size_t)bh * LL + k) * DH];
        float s = 0.f;
        #pragma unroll 16
        for (int d = 0; d < DH; d++) s += qrow[d] * kr[d];
        s *= SCALEF;
        sc[k] = s;
        lmax = fmaxf(lmax, s);
    }
    red[t] = lmax; __syncthreads();
    for (int s = 128; s > 0; s >>= 1) {
        if (t < s) red[t] = fmaxf(red[t], red[t + s]);
        __syncthreads();
    }
    const float mx = red[0];
    __syncthreads();

    float lsum = 0.f;
    for (int k = t; k < LL; k += 256) {
        float e = __expf(sc[k] - mx);
        sc[k] = e;
        lsum += e;
    }
    red[t] = lsum; __syncthreads();
    for (int s = 128; s > 0; s >>= 1) {
        if (t < s) red[t] += red[t + s];
        __syncthreads();
    }
    const float inv = 1.0f / red[0];
    __syncthreads();

    const int d = t & 63, ch = t >> 6;
    float acc = 0.f;
    for (int k = ch * (LL / 4); k < (ch + 1) * (LL / 4); k++)
        acc += sc[k] * V[((size_t)bh * LL + k) * DH + d];
    red[t] = acc; __syncthreads();
    if (t < 64) {
        float r = red[t] + red[t + 64] + red[t + 128] + red[t + 192];
        CTX[((size_t)bh * LL + q) * DH + d] = r * inv;
    }
}

// ---------------------------------------------------------------------------
extern "C" void kernel_launch(void* const* d_in, const int* in_sizes, int n_in,
                              void* d_out, int out_size, void* d_ws, size_t ws_size,
                              hipStream_t stream) {
    const float* x  = (const float*)d_in[0];
    const float* Wq = (const float*)d_in[1];
    const float* bq = (const float*)d_in[2];
    const float* Wk = (const float*)d_in[3];
    const float* bk = (const float*)d_in[4];
    const float* Wv = (const float*)d_in[5];
    const float* bv = (const float*)d_in[6];
    const float* Wo = (const float*)d_in[7];
    const float* bo = (const float*)d_in[8];
    float* out = (float*)d_out;

    float* ws = (float*)d_ws;
    const size_t QSZ = (size_t)BH * LL * DH;   // 4,194,304 floats
    float* Qp    = ws;
    float* Kp    = ws + QSZ;
    float* Vp    = ws + 2 * QSZ;
    float* CTX   = ws + 3 * QSZ;
    float* Mp    = ws + 4 * QSZ;               // BH*L (approx M)
    float* KMEAN = Mp + (size_t)BH * LL;       // BH*DH
    float* VMEAN = KMEAN + BH * DH;
    float* EM    = VMEAN + BH * DH;            // BH*NCAND (exact M of candidates)
    int*   CAND  = (int*)(EM + BH * NCAND);    // BH*NCAND
    int*   TIDX  = CAND + BH * NCAND;          // BH*KTOP

    const dim3 gemm_grid(DD / 64, (BB * LL) / 64);   // (8, 128)

    gemm_proj<<<gemm_grid, 256, 0, stream>>>(x, Wq, bq, Qp);
    gemm_proj<<<gemm_grid, 256, 0, stream>>>(x, Wk, bk, Kp);
    gemm_proj<<<gemm_grid, 256, 0, stream>>>(x, Wv, bv, Vp);

    mean_kernel<<<dim3(BH, 2), 256, 0, stream>>>(Kp, Vp, KMEAN, VMEAN);

    mfma_stats<<<dim3(LL / 64, BH), 256, 0, stream>>>(Qp, Kp, KMEAN, Mp);

    topk_kernel<<<BH, 256, 0, stream>>>(Mp, CAND, NCAND, NCAND);

    exact_kernel<<<dim3(NCAND, BH), 256, 0, stream>>>(Qp, Kp, KMEAN, CAND, EM);

    select_kernel<<<BH, 64, 0, stream>>>(EM, CAND, TIDX);

    fill_kernel<<<(BH * LL * DH) / 256, 256, 0, stream>>>(VMEAN, CTX);

    sparse_kernel<<<dim3(KTOP, BH), 256, 0, stream>>>(Qp, Kp, Vp, TIDX, CTX);

    gemm_out<<<gemm_grid, 256, 0, stream>>>(CTX, Wo, bo, out);
}

// Round 3
// 733.840 us; speedup vs baseline: 1.6265x; 1.5573x over previous
//
#include <hip/hip_runtime.h>

#define BB   4
#define LL   2048
#define DD   512
#define HH   8
#define DH   64
#define BH   32          // B*H
#define KTOP 38
#define NCAND 64         // approx-M candidate pool for exact refinement
#define SCALEF 0.125f    // 1/sqrt(64)

typedef __attribute__((ext_vector_type(8))) short bf16x8;
typedef __attribute__((ext_vector_type(8))) unsigned short ushort8;
typedef __attribute__((ext_vector_type(4))) float f32x4;

__device__ __forceinline__ ushort f32_to_bf16_rn(float x) {
    unsigned u = __float_as_uint(x);
    u += 0x7fffu + ((u >> 16) & 1u);
    return (ushort)(u >> 16);
}
__device__ __forceinline__ float bf16_to_f32(ushort h) {
    return __uint_as_float(((unsigned)h) << 16);
}

// ---------------------------------------------------------------------------
// Prep: transpose + split 4 weight matrices W[k][n] (512x512 fp32) into
// WT_H/WT_L [n][k] bf16 hi/lo. Grid (16,16,4), 256 thr, 32x32 tiles.
// ---------------------------------------------------------------------------
__global__ __launch_bounds__(256) void split_wT(const float* __restrict__ W0,
                                                const float* __restrict__ W1,
                                                const float* __restrict__ W2,
                                                const float* __restrict__ W3,
                                                ushort* __restrict__ WTH,
                                                ushort* __restrict__ WTL) {
    __shared__ float tile[32][33];
    const int z = blockIdx.z;
    const float* W = (z == 0) ? W0 : (z == 1) ? W1 : (z == 2) ? W2 : W3;
    ushort* oh = WTH + (size_t)z * DD * DD;
    ushort* ol = WTL + (size_t)z * DD * DD;
    const int n0 = blockIdx.x * 32, k0 = blockIdx.y * 32;
    const int t = threadIdx.x;
    const int r = t >> 5, c = t & 31;
    #pragma unroll
    for (int i = 0; i < 4; i++)
        tile[r + i * 8][c] = W[(size_t)(k0 + r + i * 8) * DD + n0 + c];
    __syncthreads();
    #pragma unroll
    for (int i = 0; i < 4; i++) {
        int row = r + i * 8;                 // output n-local
        float v = tile[c][row];              // = W[k0+c][n0+row]
        ushort h = f32_to_bf16_rn(v);
        oh[(size_t)(n0 + row) * DD + k0 + c] = h;
        ol[(size_t)(n0 + row) * DD + k0 + c] = f32_to_bf16_rn(v - bf16_to_f32(h));
    }
}

// ---------------------------------------------------------------------------
// Split-bf16 MFMA GEMM: Y = A[8192x512] @ B[512x512] + bias.
// B pre-split/transposed (BTH/BTL = [n][k] bf16). A split fp32->hi/lo during
// LDS staging. 3-term MFMA (hh + hl + lh); lo*lo dropped (~4e-6 abs).
// Tile 128x64, BK=32, 256 thr (4 waves), wave owns 32 rows x 64 cols
// (2 m-tiles x 4 n-tiles of 16x16x32).
// APERM: A read from permuted CTX layout [bh][l][dh]. YPERM: Y written to
// permuted [bh][l][dh] layout (projections).
// ---------------------------------------------------------------------------
template <int APERM, int YPERM>
__global__ __launch_bounds__(256) void mfma_gemm(const float* __restrict__ A,
                                                 const ushort* __restrict__ BTH,
                                                 const ushort* __restrict__ BTL,
                                                 const float* __restrict__ bias,
                                                 float* __restrict__ Y) {
    __shared__ ushort AHs[128 * 40];   // stride 40 shorts (80B): frag reads at b128 bank floor
    __shared__ ushort ALs[128 * 40];
    __shared__ ushort BHs[64 * 32];
    __shared__ ushort BLs[64 * 32];

    const int t = threadIdx.x;
    const int w = t >> 6, lane = t & 63;
    const int quad = lane >> 4, n16 = lane & 15;
    const int row0 = blockIdx.y * 128;
    const int n0   = blockIdx.x * 64;

    f32x4 acc[2][4] = {};

    const int arow = t >> 1, ahalf = t & 1;   // A staging: 128 rows x 2 k-halves (16 k each)
    const int brow = t >> 2, bkc   = t & 3;   // B staging: 64 rows x 4 chunks (8 k each)

    for (int k0 = 0; k0 < DD; k0 += 32) {
        // ---- stage B (pre-split bf16, straight copy) ----
        {
            const size_t goff = (size_t)(n0 + brow) * DD + k0 + bkc * 8;
            const uint4 vh = *(const uint4*)&BTH[goff];
            const uint4 vl = *(const uint4*)&BTL[goff];
            *(uint4*)&BHs[brow * 32 + bkc * 8] = vh;
            *(uint4*)&BLs[brow * 32 + bkc * 8] = vl;
        }
        // ---- stage A (fp32 -> bf16 hi/lo) ----
        {
            const int kk = k0 + ahalf * 16;
            const float* src;
            if (APERM) {
                int R = row0 + arow;
                int b = R >> 11, l = R & 2047;
                int h = kk >> 6, dh = kk & 63;   // 16-chunk always within one head block
                src = &A[(((size_t)(b * HH + h)) * LL + l) * DH + dh];
            } else {
                src = &A[(size_t)(row0 + arow) * DD + kk];
            }
            float v[16];
            *(float4*)&v[0]  = *(const float4*)(src);
            *(float4*)&v[4]  = *(const float4*)(src + 4);
            *(float4*)&v[8]  = *(const float4*)(src + 8);
            *(float4*)&v[12] = *(const float4*)(src + 12);
            ushort8 ha, hb, la, lb;
            #pragma unroll
            for (int j = 0; j < 8; j++) {
                ushort h0 = f32_to_bf16_rn(v[j]);
                ha[j] = h0;
                la[j] = f32_to_bf16_rn(v[j] - bf16_to_f32(h0));
                ushort h1 = f32_to_bf16_rn(v[8 + j]);
                hb[j] = h1;
                lb[j] = f32_to_bf16_rn(v[8 + j] - bf16_to_f32(h1));
            }
            const int lo = arow * 40 + ahalf * 16;
            *(ushort8*)&AHs[lo]     = ha;
            *(ushort8*)&AHs[lo + 8] = hb;
            *(ushort8*)&ALs[lo]     = la;
            *(ushort8*)&ALs[lo + 8] = lb;
        }
        __syncthreads();

        bf16x8 ah[2], al[2], bh[4], bl[4];
        #pragma unroll
        for (int mt = 0; mt < 2; mt++) {
            int off = (w * 32 + mt * 16 + n16) * 40 + quad * 8;
            ah[mt] = *(const bf16x8*)&AHs[off];
            al[mt] = *(const bf16x8*)&ALs[off];
        }
        #pragma unroll
        for (int nt = 0; nt < 4; nt++) {
            int off = (nt * 16 + n16) * 32 + quad * 8;
            bh[nt] = *(const bf16x8*)&BHs[off];
            bl[nt] = *(const bf16x8*)&BLs[off];
        }
        #pragma unroll
        for (int mt = 0; mt < 2; mt++)
            #pragma unroll
            for (int nt = 0; nt < 4; nt++) {
                acc[mt][nt] = __builtin_amdgcn_mfma_f32_16x16x32_bf16(ah[mt], bh[nt], acc[mt][nt], 0, 0, 0);
                acc[mt][nt] = __builtin_amdgcn_mfma_f32_16x16x32_bf16(ah[mt], bl[nt], acc[mt][nt], 0, 0, 0);
                acc[mt][nt] = __builtin_amdgcn_mfma_f32_16x16x32_bf16(al[mt], bh[nt], acc[mt][nt], 0, 0, 0);
            }
        __syncthreads();
    }

    // epilogue: C layout col = lane&15, row = quad*4 + reg
    #pragma unroll
    for (int mt = 0; mt < 2; mt++)
        #pragma unroll
        for (int nt = 0; nt < 4; nt++) {
            const int c = n0 + nt * 16 + n16;
            const float bv = bias[c];
            #pragma unroll
            for (int r = 0; r < 4; r++) {
                int m = w * 32 + mt * 16 + quad * 4 + r;
                int R = row0 + m;
                float v = acc[mt][nt][r] + bv;
                if (YPERM) {
                    int b = R >> 11, l = R & 2047;
                    int h = c >> 6, dh = c & 63;
                    Y[(((size_t)(b * HH + h)) * LL + l) * DH + dh] = v;
                } else {
                    Y[(size_t)R * DD + c] = v;
                }
            }
        }
}

// ---------------------------------------------------------------------------
// Per-head mean of K and V over L. (unchanged)
// ---------------------------------------------------------------------------
__global__ __launch_bounds__(256) void mean_kernel(const float* __restrict__ Kp,
                                                   const float* __restrict__ Vp,
                                                   float* __restrict__ Kmean,
                                                   float* __restrict__ Vmean) {
    __shared__ float red[256];
    const int bh = blockIdx.x;
    const float* src = blockIdx.y ? Vp : Kp;
    float* dst       = blockIdx.y ? Vmean : Kmean;
    const int t = threadIdx.x;
    const int d = t & 63, ch = t >> 6;
    float s = 0.f;
    for (int l = ch * (LL / 4); l < (ch + 1) * (LL / 4); l++)
        s += src[((size_t)bh * LL + l) * DH + d];
    red[t] = s;
    __syncthreads();
    if (t < 64)
        dst[bh * DH + d] = (red[t] + red[t + 64] + red[t + 128] + red[t + 192]) * (1.0f / LL);
}

// ---------------------------------------------------------------------------
// Approx M via split-bf16 MFMA. (unchanged from R2 — verified correct)
// ---------------------------------------------------------------------------
__global__ __launch_bounds__(256) void mfma_stats(const float* __restrict__ Qp,
                                                  const float* __restrict__ Kp,
                                                  const float* __restrict__ Kmean,
                                                  float* __restrict__ M) {
    __shared__ ushort KS[2 * 128 * 72];
    __shared__ float  Km[64];
    __shared__ float  mdS[64];

    const int bh = blockIdx.y;
    const int q0 = blockIdx.x * 64;
    const int t    = threadIdx.x;
    const int wave = t >> 6;
    const int lane = t & 63;
    const int quad = lane >> 4;
    const int n16  = lane & 15;
    const int qbase = q0 + wave * 16;

    if (t < 64) Km[t] = Kmean[bh * DH + t];
    __syncthreads();
    if (t < 64) {
        const float4* qr = (const float4*)&Qp[((size_t)bh * LL + q0 + t) * DH];
        const float4* km4 = (const float4*)Km;
        float md = 0.f;
        #pragma unroll
        for (int i = 0; i < 16; i++) {
            float4 a = qr[i], b = km4[i];
            md += a.x * b.x + a.y * b.y + a.z * b.z + a.w * b.w;
        }
        mdS[t] = md;
    }

    bf16x8 aH0, aL0, aH1, aL1;
    {
        const float* qrp = &Qp[((size_t)bh * LL + qbase + n16) * DH + quad * 8];
        float v[16];
        *(float4*)&v[0]  = *(const float4*)(qrp);
        *(float4*)&v[4]  = *(const float4*)(qrp + 4);
        *(float4*)&v[8]  = *(const float4*)(qrp + 32);
        *(float4*)&v[12] = *(const float4*)(qrp + 36);
        #pragma unroll
        for (int j = 0; j < 8; j++) {
            ushort h0 = f32_to_bf16_rn(v[j]);
            aH0[j] = (short)h0;
            aL0[j] = (short)f32_to_bf16_rn(v[j] - bf16_to_f32(h0));
            ushort h1 = f32_to_bf16_rn(v[8 + j]);
            aH1[j] = (short)h1;
            aL1[j] = (short)f32_to_bf16_rn(v[8 + j] - bf16_to_f32(h1));
        }
    }

    float maxv[4] = {-3.4e38f, -3.4e38f, -3.4e38f, -3.4e38f};

    for (int kt0 = 0; kt0 < LL; kt0 += 128) {
        __syncthreads();
        for (int c = t; c < 2048; c += 256) {
            int row = c >> 4, f4 = c & 15;
            const float4 v = *(const float4*)&Kp[((size_t)(bh * LL + kt0 + row)) * DH + f4 * 4];
            ushort4 h, l;
            h.x = f32_to_bf16_rn(v.x); l.x = f32_to_bf16_rn(v.x - bf16_to_f32(h.x));
            h.y = f32_to_bf16_rn(v.y); l.y = f32_to_bf16_rn(v.y - bf16_to_f32(h.y));
            h.z = f32_to_bf16_rn(v.z); l.z = f32_to_bf16_rn(v.z - bf16_to_f32(h.z));
            h.w = f32_to_bf16_rn(v.w); l.w = f32_to_bf16_rn(v.w - bf16_to_f32(h.w));
            *(ushort4*)&KS[row * 72 + f4 * 4]        = h;
            *(ushort4*)&KS[9216 + row * 72 + f4 * 4] = l;
        }
        __syncthreads();

        for (int ktl = 0; ktl < 128; ktl += 16) {
            const ushort* bp = &KS[(size_t)(ktl + n16) * 72 + quad * 8];
            bf16x8 bH0 = *(const bf16x8*)(bp);
            bf16x8 bH1 = *(const bf16x8*)(bp + 32);
            bf16x8 bL0 = *(const bf16x8*)(bp + 9216);
            bf16x8 bL1 = *(const bf16x8*)(bp + 9216 + 32);

            f32x4 acc = {0.f, 0.f, 0.f, 0.f};
            acc = __builtin_amdgcn_mfma_f32_16x16x32_bf16(aH0, bH0, acc, 0, 0, 0);
            acc = __builtin_amdgcn_mfma_f32_16x16x32_bf16(aH1, bH1, acc, 0, 0, 0);
            acc = __builtin_amdgcn_mfma_f32_16x16x32_bf16(aH0, bL0, acc, 0, 0, 0);
            acc = __builtin_amdgcn_mfma_f32_16x16x32_bf16(aH1, bL1, acc, 0, 0, 0);
            acc = __builtin_amdgcn_mfma_f32_16x16x32_bf16(aL0, bH0, acc, 0, 0, 0);
            acc = __builtin_amdgcn_mfma_f32_16x16x32_bf16(aL1, bH1, acc, 0, 0, 0);
            acc = __builtin_amdgcn_mfma_f32_16x16x32_bf16(aL0, bL0, acc, 0, 0, 0);
            acc = __builtin_amdgcn_mfma_f32_16x16x32_bf16(aL1, bL1, acc, 0, 0, 0);

            maxv[0] = fmaxf(maxv[0], acc[0]);
            maxv[1] = fmaxf(maxv[1], acc[1]);
            maxv[2] = fmaxf(maxv[2], acc[2]);
            maxv[3] = fmaxf(maxv[3], acc[3]);
        }
    }

    #pragma unroll
    for (int off = 1; off < 16; off <<= 1) {
        #pragma unroll
        for (int r = 0; r < 4; r++)
            maxv[r] = fmaxf(maxv[r], __shfl_xor(maxv[r], off));
    }

    if (n16 == 0) {
        #pragma unroll
        for (int r = 0; r < 4; r++) {
            int lq = wave * 16 + quad * 4 + r;
            M[(size_t)bh * LL + q0 + lq] = SCALEF * maxv[r] - SCALEF * mdS[lq];
        }
    }
}

// ---------------------------------------------------------------------------
// Iterative block argmax top-k (first occurrence wins ties). One block per bh.
// ---------------------------------------------------------------------------
__global__ __launch_bounds__(256) void topk_kernel(const float* __restrict__ M,
                                                   int* __restrict__ out_idx,
                                                   int kcount, int ostride) {
    __shared__ float vals[LL];
    __shared__ float rv[256];
    __shared__ int   ri[256];
    const int bh = blockIdx.x;
    const int t  = threadIdx.x;
    for (int i = t; i < LL; i += 256) vals[i] = M[(size_t)bh * LL + i];
    __syncthreads();
    for (int it = 0; it < kcount; it++) {
        float best = -3.4e38f; int bi = LL;
        for (int i = t; i < LL; i += 256) {
            float v = vals[i];
            if (v > best) { best = v; bi = i; }
        }
        rv[t] = best; ri[t] = bi;
        __syncthreads();
        for (int s = 128; s > 0; s >>= 1) {
            if (t < s) {
                if (rv[t + s] > rv[t] || (rv[t + s] == rv[t] && ri[t + s] < ri[t])) {
                    rv[t] = rv[t + s]; ri[t] = ri[t + s];
                }
            }
            __syncthreads();
        }
        if (t == 0) { out_idx[bh * ostride + it] = ri[0]; vals[ri[0]] = -3.4e38f; }
        __syncthreads();
    }
}

// ---------------------------------------------------------------------------
// Exact fp32 M for one candidate. (unchanged)
// ---------------------------------------------------------------------------
__global__ __launch_bounds__(256) void exact_kernel(const float* __restrict__ Qp,
                                                    const float* __restrict__ Kp,
                                                    const float* __restrict__ Kmean,
                                                    const int* __restrict__ CAND,
                                                    float* __restrict__ EM) {
    __shared__ float qrow[DH];
    __shared__ float red[256];
    __shared__ int   qs;
    const int bh = blockIdx.y;
    const int j  = blockIdx.x;
    const int t  = threadIdx.x;
    if (t == 0) qs = CAND[bh * NCAND + j];
    __syncthreads();
    const int q = qs;
    if (t < DH) qrow[t] = Qp[((size_t)bh * LL + q) * DH + t];
    __syncthreads();

    float mx = -3.4e38f;
    for (int k = t; k < LL; k += 256) {
        const float4* kr = (const float4*)&Kp[((size_t)bh * LL + k) * DH];
        const float4* q4 = (const float4*)qrow;
        float s = 0.f;
        #pragma unroll
        for (int i = 0; i < 16; i++) {
            float4 kv = kr[i], qv = q4[i];
            s += qv.x * kv.x + qv.y * kv.y + qv.z * kv.z + qv.w * kv.w;
        }
        mx = fmaxf(mx, s);
    }
    red[t] = mx;
    __syncthreads();
    for (int s = 128; s > 0; s >>= 1) {
        if (t < s) red[t] = fmaxf(red[t], red[t + s]);
        __syncthreads();
    }
    if (t == 0) {
        const float4* q4 = (const float4*)qrow;
        const float4* k4 = (const float4*)&Kmean[bh * DH];
        float md = 0.f;
        #pragma unroll
        for (int i = 0; i < 16; i++) {
            float4 a = q4[i], b = k4[i];
            md += a.x * b.x + a.y * b.y + a.z * b.z + a.w * b.w;
        }
        EM[bh * NCAND + j] = SCALEF * red[0] - SCALEF * md;
    }
}

// ---------------------------------------------------------------------------
// Final top-38 among 64 candidates by exact M. (unchanged)
// ---------------------------------------------------------------------------
__global__ __launch_bounds__(64) void select_kernel(const float* __restrict__ EM,
                                                    const int* __restrict__ CAND,
                                                    int* __restrict__ TIDX) {
    const int bh = blockIdx.x;
    const int t  = threadIdx.x;
    float v  = EM[bh * NCAND + t];
    int   qi = CAND[bh * NCAND + t];
    for (int it = 0; it < KTOP; it++) {
        float bv = v; int bq = qi;
        #pragma unroll
        for (int off = 1; off < 64; off <<= 1) {
            float ov = __shfl_xor(bv, off);
            int   oq = __shfl_xor(bq, off);
            if (ov > bv || (ov == bv && oq < bq)) { bv = ov; bq = oq; }
        }
        if (t == 0) TIDX[bh * KTOP + it] = bq;
        if (qi == bq) v = -3.4e38f;
    }
}

// ---------------------------------------------------------------------------
// Fill context with per-head V mean. (unchanged)
// ---------------------------------------------------------------------------
__global__ __launch_bounds__(256) void fill_kernel(const float* __restrict__ Vmean,
                                                   float* __restrict__ CTX) {
    size_t idx = (size_t)blockIdx.x * 256 + threadIdx.x;
    int d  = idx & 63;
    int bh = (int)(idx >> 17);
    CTX[idx] = Vmean[bh * DH + d];
}

// ---------------------------------------------------------------------------
// Sparse attention V2: LDS-staged K tiles (coalesced), stride-65 conflict-free
// dot reads, float4 PV. One block per (topk-slot, bh).
// ---------------------------------------------------------------------------
__global__ __launch_bounds__(256) void sparse_kernel(const float* __restrict__ Q,
                                                     const float* __restrict__ K,
                                                     const float* __restrict__ V,
                                                     const int* __restrict__ top_idx,
                                                     float* __restrict__ CTX) {
    __shared__ float Kt[128][65];   // K tile (also reused as PV scratch region via sc)
    __shared__ float sc[LL];
    __shared__ float qrow[DH];
    __shared__ float red[256];
    const int bh = blockIdx.y;
    const int q  = top_idx[bh * KTOP + blockIdx.x];
    const int t  = threadIdx.x;

    if (t < DH) qrow[t] = Q[((size_t)bh * LL + q) * DH + t];
    __syncthreads();

    const int kk = t & 127, half = t >> 7;   // key-in-tile, d-half
    for (int kt = 0; kt < LL / 128; kt++) {
        // stage 128 K rows, coalesced float4
        #pragma unroll
        for (int i = 0; i < 8; i++) {
            int f = i * 256 + t;
            int row = f >> 4, c4 = f & 15;
            const float4 v = *(const float4*)&K[((size_t)(bh * LL + kt * 128 + row)) * DH + c4 * 4];
            *(float4*)&Kt[row][c4 * 4] = v;
        }
        __syncthreads();
        // half-dot from LDS (Kt reads stride-65 => conflict-free)
        float s = 0.f;
        #pragma unroll
        for (int c = 0; c < 8; c++) {
            const float4 kv = *(const float4*)&Kt[kk][half * 32 + c * 4];
            const float4 qv = *(const float4*)&qrow[half * 32 + c * 4];
            s += qv.x * kv.x + qv.y * kv.y + qv.z * kv.z + qv.w * kv.w;
        }
        red[t] = s;
        __syncthreads();
        if (t < 128) sc[kt * 128 + t] = (red[t] + red[t + 128]) * SCALEF;
        __syncthreads();
    }

    // softmax over sc[0..2047]
    float m1 = -3.4e38f;
    #pragma unroll
    for (int i = 0; i < 8; i++) m1 = fmaxf(m1, sc[i * 256 + t]);
    red[t] = m1; __syncthreads();
    for (int s = 128; s > 0; s >>= 1) {
        if (t < s) red[t] = fmaxf(red[t], red[t + s]);
        __syncthreads();
    }
    const float mx = red[0];
    __syncthreads();
    float s1 = 0.f;
    #pragma unroll
    for (int i = 0; i < 8; i++) {
        float e = __expf(sc[i * 256 + t] - mx);
        sc[i * 256 + t] = e;
        s1 += e;
    }
    red[t] = s1; __syncthreads();
    for (int s = 128; s > 0; s >>= 1) {
        if (t < s) red[t] += red[t + s];
        __syncthreads();
    }
    const float inv = 1.0f / red[0];
    __syncthreads();

    // PV: thread -> (d4 = 4 dims, ch = 128-key chunk), float4 V loads
    const int d4 = (t & 15) * 4, ch = t >> 4;
    float4 acc = {0.f, 0.f, 0.f, 0.f};
    for (int i = 0; i < 128; i++) {
        int k = ch * 128 + i;
        const float4 v = *(const float4*)&V[((size_t)(bh * LL + k)) * DH + d4];
        const float p = sc[k];
        acc.x += p * v.x; acc.y += p * v.y; acc.z += p * v.z; acc.w += p * v.w;
    }
    __syncthreads();                 // all sc reads done; reuse sc as scratch
    *(float4*)&sc[ch * 64 + d4] = acc;   // partials [16][64]
    __syncthreads();
    if (t < 64) {
        float r = 0.f;
        #pragma unroll
        for (int c = 0; c < 16; c++) r += sc[c * 64 + t];
        CTX[((size_t)bh * LL + q) * DH + t] = r * inv;
    }
}

// ---------------------------------------------------------------------------
extern "C" void kernel_launch(void* const* d_in, const int* in_sizes, int n_in,
                              void* d_out, int out_size, void* d_ws, size_t ws_size,
                              hipStream_t stream) {
    const float* x  = (const float*)d_in[0];
    const float* Wq = (const float*)d_in[1];
    const float* bq = (const float*)d_in[2];
    const float* Wk = (const float*)d_in[3];
    const float* bk = (const float*)d_in[4];
    const float* Wv = (const float*)d_in[5];
    const float* bv = (const float*)d_in[6];
    const float* Wo = (const float*)d_in[7];
    const float* bo = (const float*)d_in[8];
    float* out = (float*)d_out;

    float* ws = (float*)d_ws;
    const size_t QSZ = (size_t)BH * LL * DH;   // 4,194,304 floats
    float* Qp    = ws;
    float* Kp    = ws + QSZ;
    float* Vp    = ws + 2 * QSZ;
    float* CTX   = ws + 3 * QSZ;
    float* Mp    = ws + 4 * QSZ;               // BH*L
    float* KMEAN = Mp + (size_t)BH * LL;
    float* VMEAN = KMEAN + BH * DH;
    float* EM    = VMEAN + BH * DH;            // BH*NCAND
    int*   CAND  = (int*)(EM + BH * NCAND);
    int*   TIDX  = CAND + BH * NCAND;
    ushort* WTH  = (ushort*)(ws + 4 * QSZ + 131072);   // 4 x 512x512 bf16 hi
    ushort* WTL  = WTH + (size_t)4 * DD * DD;          // 4 x 512x512 bf16 lo
    const size_t WOFF = (size_t)DD * DD;

    split_wT<<<dim3(16, 16, 4), 256, 0, stream>>>(Wq, Wk, Wv, Wo, WTH, WTL);

    const dim3 gemm_grid(DD / 64, (BB * LL) / 128);    // (8, 64)
    mfma_gemm<0, 1><<<gemm_grid, 256, 0, stream>>>(x, WTH,            WTL,            bq, Qp);
    mfma_gemm<0, 1><<<gemm_grid, 256, 0, stream>>>(x, WTH + WOFF,     WTL + WOFF,     bk, Kp);
    mfma_gemm<0, 1><<<gemm_grid, 256, 0, stream>>>(x, WTH + 2 * WOFF, WTL + 2 * WOFF, bv, Vp);

    mean_kernel<<<dim3(BH, 2), 256, 0, stream>>>(Kp, Vp, KMEAN, VMEAN);

    mfma_stats<<<dim3(LL / 64, BH), 256, 0, stream>>>(Qp, Kp, KMEAN, Mp);

    topk_kernel<<<BH, 256, 0, stream>>>(Mp, CAND, NCAND, NCAND);

    exact_kernel<<<dim3(NCAND, BH), 256, 0, stream>>>(Qp, Kp, KMEAN, CAND, EM);

    select_kernel<<<BH, 64, 0, stream>>>(EM, CAND, TIDX);

    fill_kernel<<<(BH * LL * DH) / 256, 256, 0, stream>>>(VMEAN, CTX);

    sparse_kernel<<<dim3(KTOP, BH), 256, 0, stream>>>(Qp, Kp, Vp, TIDX, CTX);

    mfma_gemm<1, 0><<<gemm_grid, 256, 0, stream>>>(CTX, WTH + 3 * WOFF, WTL + 3 * WOFF, bo, out);
}

// Round 4
// 658.159 us; speedup vs baseline: 1.8136x; 1.1150x over previous
//
#include <hip/hip_runtime.h>

#define BB   4
#define LL   2048
#define DD   512
#define HH   8
#define DH   64
#define BH   32          // B*H
#define KTOP 38
#define NCAND 64         // approx-M candidate pool for exact refinement
#define SCALEF 0.125f    // 1/sqrt(64)

typedef __attribute__((ext_vector_type(8))) short bf16x8;
typedef __attribute__((ext_vector_type(8))) unsigned short ushort8;
typedef __attribute__((ext_vector_type(4))) float f32x4;

__device__ __forceinline__ ushort f32_to_bf16_rn(float x) {
    unsigned u = __float_as_uint(x);
    u += 0x7fffu + ((u >> 16) & 1u);
    return (ushort)(u >> 16);
}
__device__ __forceinline__ float bf16_to_f32(ushort h) {
    return __uint_as_float(((unsigned)h) << 16);
}

// ---------------------------------------------------------------------------
// Elementwise split: fp32 array -> bf16 hi + lo arrays (layout-preserving).
// n/4 float4 chunks; grid*256 threads, 1 chunk each.
// ---------------------------------------------------------------------------
__global__ __launch_bounds__(256) void split_x(const float* __restrict__ X,
                                               ushort* __restrict__ XH,
                                               ushort* __restrict__ XL) {
    const size_t c = (size_t)blockIdx.x * 256 + threadIdx.x;
    const float4 v = *(const float4*)&X[c * 4];
    ushort4 h, l;
    h.x = f32_to_bf16_rn(v.x); l.x = f32_to_bf16_rn(v.x - bf16_to_f32(h.x));
    h.y = f32_to_bf16_rn(v.y); l.y = f32_to_bf16_rn(v.y - bf16_to_f32(h.y));
    h.z = f32_to_bf16_rn(v.z); l.z = f32_to_bf16_rn(v.z - bf16_to_f32(h.z));
    h.w = f32_to_bf16_rn(v.w); l.w = f32_to_bf16_rn(v.w - bf16_to_f32(h.w));
    *(ushort4*)&XH[c * 4] = h;
    *(ushort4*)&XL[c * 4] = l;
}

// ---------------------------------------------------------------------------
// Prep: transpose + split 4 weight matrices W[k][n] into WT_H/WT_L [n][k] bf16.
// ---------------------------------------------------------------------------
__global__ __launch_bounds__(256) void split_wT(const float* __restrict__ W0,
                                                const float* __restrict__ W1,
                                                const float* __restrict__ W2,
                                                const float* __restrict__ W3,
                                                ushort* __restrict__ WTH,
                                                ushort* __restrict__ WTL) {
    __shared__ float tile[32][33];
    const int z = blockIdx.z;
    const float* W = (z == 0) ? W0 : (z == 1) ? W1 : (z == 2) ? W2 : W3;
    ushort* oh = WTH + (size_t)z * DD * DD;
    ushort* ol = WTL + (size_t)z * DD * DD;
    const int n0 = blockIdx.x * 32, k0 = blockIdx.y * 32;
    const int t = threadIdx.x;
    const int r = t >> 5, c = t & 31;
    #pragma unroll
    for (int i = 0; i < 4; i++)
        tile[r + i * 8][c] = W[(size_t)(k0 + r + i * 8) * DD + n0 + c];
    __syncthreads();
    #pragma unroll
    for (int i = 0; i < 4; i++) {
        int row = r + i * 8;
        float v = tile[c][row];
        ushort h = f32_to_bf16_rn(v);
        oh[(size_t)(n0 + row) * DD + k0 + c] = h;
        ol[(size_t)(n0 + row) * DD + k0 + c] = f32_to_bf16_rn(v - bf16_to_f32(h));
    }
}

// ---------------------------------------------------------------------------
// Split-bf16 MFMA GEMM V2: Y = A[8192x512] @ B[512x512] + bias.
// A pre-split bf16 (AH/AL global) -> fragments loaded DIRECT global->VGPR
// (no cross-wave A reuse in a 32-rows-per-wave tile; LDS staging was waste).
// B pre-split/transposed bf16 in LDS (stride-40 rows, near-floor banks).
// 3-term MFMA (hh + hl + lh). Tile 128x64, BK=32, 256 thr (4 waves).
// WSPLIT: epilogue also writes bf16-hi of Y (fused K split).
// ---------------------------------------------------------------------------
template <int APERM, int YPERM, int WSPLIT>
__global__ __launch_bounds__(256) void mfma_gemm(const ushort* __restrict__ AH,
                                                 const ushort* __restrict__ AL,
                                                 const ushort* __restrict__ BTH,
                                                 const ushort* __restrict__ BTL,
                                                 const float* __restrict__ bias,
                                                 float* __restrict__ Y,
                                                 ushort* __restrict__ YH) {
    __shared__ ushort BHs[64 * 40];
    __shared__ ushort BLs[64 * 40];

    const int t = threadIdx.x;
    const int w = t >> 6, lane = t & 63;
    const int quad = lane >> 4, n16 = lane & 15;
    const int row0 = blockIdx.y * 128;
    const int n0   = blockIdx.x * 64;

    f32x4 acc[2][4] = {};

    // A row addressing (constant across K-loop except k-offset)
    size_t arow_off[2];
    #pragma unroll
    for (int mt = 0; mt < 2; mt++) {
        int R = row0 + w * 32 + mt * 16 + n16;
        if (APERM) {
            int b = R >> 11, l = R & 2047;
            arow_off[mt] = ((size_t)b * HH) * LL * DH + (size_t)l * DH;  // + h*LL*DH + dh
        } else {
            arow_off[mt] = (size_t)R * DD;
        }
    }

    const int brow = t >> 2, bc8 = t & 3;   // B staging: 64 rows x 4 chunks of 8

    for (int k0 = 0; k0 < DD; k0 += 32) {
        // stage B (straight bf16 copy)
        {
            const size_t goff = (size_t)(n0 + brow) * DD + k0 + bc8 * 8;
            const uint4 vh = *(const uint4*)&BTH[goff];
            const uint4 vl = *(const uint4*)&BTL[goff];
            *(uint4*)&BHs[brow * 40 + bc8 * 8] = vh;
            *(uint4*)&BLs[brow * 40 + bc8 * 8] = vl;
        }
        // A fragments direct from global
        bf16x8 ah[2], al[2];
        #pragma unroll
        for (int mt = 0; mt < 2; mt++) {
            int k = k0 + quad * 8;
            size_t off;
            if (APERM) {
                int h = k >> 6, dh = k & 63;
                off = arow_off[mt] + (size_t)h * LL * DH + dh;
            } else {
                off = arow_off[mt] + k;
            }
            ah[mt] = *(const bf16x8*)&AH[off];
            al[mt] = *(const bf16x8*)&AL[off];
        }
        __syncthreads();

        bf16x8 bh[4], bl[4];
        #pragma unroll
        for (int nt = 0; nt < 4; nt++) {
            int off = (nt * 16 + n16) * 40 + quad * 8;
            bh[nt] = *(const bf16x8*)&BHs[off];
            bl[nt] = *(const bf16x8*)&BLs[off];
        }
        #pragma unroll
        for (int mt = 0; mt < 2; mt++)
            #pragma unroll
            for (int nt = 0; nt < 4; nt++) {
                acc[mt][nt] = __builtin_amdgcn_mfma_f32_16x16x32_bf16(ah[mt], bh[nt], acc[mt][nt], 0, 0, 0);
                acc[mt][nt] = __builtin_amdgcn_mfma_f32_16x16x32_bf16(ah[mt], bl[nt], acc[mt][nt], 0, 0, 0);
                acc[mt][nt] = __builtin_amdgcn_mfma_f32_16x16x32_bf16(al[mt], bh[nt], acc[mt][nt], 0, 0, 0);
            }
        __syncthreads();
    }

    // epilogue: C layout col = lane&15, row = quad*4 + reg
    #pragma unroll
    for (int mt = 0; mt < 2; mt++)
        #pragma unroll
        for (int nt = 0; nt < 4; nt++) {
            const int c = n0 + nt * 16 + n16;
            const float bv = bias[c];
            #pragma unroll
            for (int r = 0; r < 4; r++) {
                int m = w * 32 + mt * 16 + quad * 4 + r;
                int R = row0 + m;
                float v = acc[mt][nt][r] + bv;
                size_t off;
                if (YPERM) {
                    int b = R >> 11, l = R & 2047;
                    int h = c >> 6, dh = c & 63;
                    off = (((size_t)(b * HH + h)) * LL + l) * DH + dh;
                } else {
                    off = (size_t)R * DD + c;
                }
                Y[off] = v;
                if (WSPLIT) YH[off] = f32_to_bf16_rn(v);
            }
        }
}

// ---------------------------------------------------------------------------
// Per-head mean of K and V over L. (unchanged)
// ---------------------------------------------------------------------------
__global__ __launch_bounds__(256) void mean_kernel(const float* __restrict__ Kp,
                                                   const float* __restrict__ Vp,
                                                   float* __restrict__ Kmean,
                                                   float* __restrict__ Vmean) {
    __shared__ float red[256];
    const int bh = blockIdx.x;
    const float* src = blockIdx.y ? Vp : Kp;
    float* dst       = blockIdx.y ? Vmean : Kmean;
    const int t = threadIdx.x;
    const int d = t & 63, ch = t >> 6;
    float s = 0.f;
    for (int l = ch * (LL / 4); l < (ch + 1) * (LL / 4); l++)
        s += src[((size_t)bh * LL + l) * DH + d];
    red[t] = s;
    __syncthreads();
    if (t < 64)
        dst[bh * DH + d] = (red[t] + red[t + 64] + red[t + 128] + red[t + 192]) * (1.0f / LL);
}

// ---------------------------------------------------------------------------
// Approx M V2: 2-term MFMA (Qhi+Qlo)*Khi; K pre-split bf16 (KH), copy-staged.
// Block 256 thr / 4 waves, q-tile 128 (2 m-frags per wave), 128-key stages.
// LDS rows stride 72 shorts -> frag reads at b128 bank floor.
// Error ~1.1e-3 on scores: candidate-ranking only (exact refinement follows).
// ---------------------------------------------------------------------------
__global__ __launch_bounds__(256) void mfma_stats(const float* __restrict__ Qp,
                                                  const ushort* __restrict__ KH,
                                                  const float* __restrict__ Kmean,
                                                  float* __restrict__ M) {
    __shared__ ushort KS[128 * 72];
    __shared__ float  Km[64];
    __shared__ float  mdS[128];

    const int bh = blockIdx.y;
    const int q0 = blockIdx.x * 128;
    const int t    = threadIdx.x;
    const int w    = t >> 6;
    const int lane = t & 63;
    const int quad = lane >> 4;
    const int n16  = lane & 15;

    if (t < 64) Km[t] = Kmean[bh * DH + t];
    __syncthreads();
    if (t < 128) {
        const float4* qr = (const float4*)&Qp[((size_t)bh * LL + q0 + t) * DH];
        const float4* km4 = (const float4*)Km;
        float md = 0.f;
        #pragma unroll
        for (int i = 0; i < 16; i++) {
            float4 a = qr[i], b = km4[i];
            md += a.x * b.x + a.y * b.y + a.z * b.z + a.w * b.w;
        }
        mdS[t] = md;
    }

    // Q fragments: per m-tile, hi+lo x two d-chunks (converted once)
    bf16x8 aH[2][2], aL[2][2];
    #pragma unroll
    for (int mt = 0; mt < 2; mt++) {
        const float* qrp = &Qp[((size_t)bh * LL + q0 + w * 32 + mt * 16 + n16) * DH + quad * 8];
        float v[16];
        *(float4*)&v[0]  = *(const float4*)(qrp);
        *(float4*)&v[4]  = *(const float4*)(qrp + 4);
        *(float4*)&v[8]  = *(const float4*)(qrp + 32);
        *(float4*)&v[12] = *(const float4*)(qrp + 36);
        #pragma unroll
        for (int j = 0; j < 8; j++) {
            ushort h0 = f32_to_bf16_rn(v[j]);
            aH[mt][0][j] = (short)h0;
            aL[mt][0][j] = (short)f32_to_bf16_rn(v[j] - bf16_to_f32(h0));
            ushort h1 = f32_to_bf16_rn(v[8 + j]);
            aH[mt][1][j] = (short)h1;
            aL[mt][1][j] = (short)f32_to_bf16_rn(v[8 + j] - bf16_to_f32(h1));
        }
    }

    f32x4 maxv[2] = {{-3.4e38f, -3.4e38f, -3.4e38f, -3.4e38f},
                     {-3.4e38f, -3.4e38f, -3.4e38f, -3.4e38f}};

    for (int kt0 = 0; kt0 < LL; kt0 += 128) {
        __syncthreads();
        // stage 128 pre-split K rows (copy only): 1024 uint4 / 256 thr
        #pragma unroll
        for (int i = 0; i < 4; i++) {
            int f = i * 256 + t;
            int row = f >> 3, c8 = f & 7;
            const uint4 v = *(const uint4*)&KH[((size_t)(bh * LL + kt0 + row)) * DH + c8 * 8];
            *(uint4*)&KS[row * 72 + c8 * 8] = v;
        }
        __syncthreads();

        for (int ktl = 0; ktl < 128; ktl += 16) {
            const ushort* bp = &KS[(size_t)(ktl + n16) * 72 + quad * 8];
            bf16x8 bH0 = *(const bf16x8*)(bp);
            bf16x8 bH1 = *(const bf16x8*)(bp + 32);
            #pragma unroll
            for (int mt = 0; mt < 2; mt++) {
                f32x4 acc = {0.f, 0.f, 0.f, 0.f};
                acc = __builtin_amdgcn_mfma_f32_16x16x32_bf16(aH[mt][0], bH0, acc, 0, 0, 0);
                acc = __builtin_amdgcn_mfma_f32_16x16x32_bf16(aH[mt][1], bH1, acc, 0, 0, 0);
                acc = __builtin_amdgcn_mfma_f32_16x16x32_bf16(aL[mt][0], bH0, acc, 0, 0, 0);
                acc = __builtin_amdgcn_mfma_f32_16x16x32_bf16(aL[mt][1], bH1, acc, 0, 0, 0);
                maxv[mt][0] = fmaxf(maxv[mt][0], acc[0]);
                maxv[mt][1] = fmaxf(maxv[mt][1], acc[1]);
                maxv[mt][2] = fmaxf(maxv[mt][2], acc[2]);
                maxv[mt][3] = fmaxf(maxv[mt][3], acc[3]);
            }
        }
    }

    // reduce max over the 16 key-columns (n16 lanes within a quad)
    #pragma unroll
    for (int off = 1; off < 16; off <<= 1)
        #pragma unroll
        for (int mt = 0; mt < 2; mt++)
            #pragma unroll
            for (int r = 0; r < 4; r++)
                maxv[mt][r] = fmaxf(maxv[mt][r], __shfl_xor(maxv[mt][r], off));

    if (n16 == 0) {
        #pragma unroll
        for (int mt = 0; mt < 2; mt++)
            #pragma unroll
            for (int r = 0; r < 4; r++) {
                int lq = w * 32 + mt * 16 + quad * 4 + r;
                M[(size_t)bh * LL + q0 + lq] = SCALEF * maxv[mt][r] - SCALEF * mdS[lq];
            }
    }
}

// ---------------------------------------------------------------------------
// Iterative block argmax top-k (first occurrence wins ties). One block per bh.
// ---------------------------------------------------------------------------
__global__ __launch_bounds__(256) void topk_kernel(const float* __restrict__ M,
                                                   int* __restrict__ out_idx,
                                                   int kcount, int ostride) {
    __shared__ float vals[LL];
    __shared__ float rv[256];
    __shared__ int   ri[256];
    const int bh = blockIdx.x;
    const int t  = threadIdx.x;
    for (int i = t; i < LL; i += 256) vals[i] = M[(size_t)bh * LL + i];
    __syncthreads();
    for (int it = 0; it < kcount; it++) {
        float best = -3.4e38f; int bi = LL;
        for (int i = t; i < LL; i += 256) {
            float v = vals[i];
            if (v > best) { best = v; bi = i; }
        }
        rv[t] = best; ri[t] = bi;
        __syncthreads();
        for (int s = 128; s > 0; s >>= 1) {
            if (t < s) {
                if (rv[t + s] > rv[t] || (rv[t + s] == rv[t] && ri[t + s] < ri[t])) {
                    rv[t] = rv[t + s]; ri[t] = ri[t + s];
                }
            }
            __syncthreads();
        }
        if (t == 0) { out_idx[bh * ostride + it] = ri[0]; vals[ri[0]] = -3.4e38f; }
        __syncthreads();
    }
}

// ---------------------------------------------------------------------------
// Exact fp32 M for one candidate. (unchanged)
// ---------------------------------------------------------------------------
__global__ __launch_bounds__(256) void exact_kernel(const float* __restrict__ Qp,
                                                    const float* __restrict__ Kp,
                                                    const float* __restrict__ Kmean,
                                                    const int* __restrict__ CAND,
                                                    float* __restrict__ EM) {
    __shared__ float qrow[DH];
    __shared__ float red[256];
    __shared__ int   qs;
    const int bh = blockIdx.y;
    const int j  = blockIdx.x;
    const int t  = threadIdx.x;
    if (t == 0) qs = CAND[bh * NCAND + j];
    __syncthreads();
    const int q = qs;
    if (t < DH) qrow[t] = Qp[((size_t)bh * LL + q) * DH + t];
    __syncthreads();

    float mx = -3.4e38f;
    for (int k = t; k < LL; k += 256) {
        const float4* kr = (const float4*)&Kp[((size_t)bh * LL + k) * DH];
        const float4* q4 = (const float4*)qrow;
        float s = 0.f;
        #pragma unroll
        for (int i = 0; i < 16; i++) {
            float4 kv = kr[i], qv = q4[i];
            s += qv.x * kv.x + qv.y * kv.y + qv.z * kv.z + qv.w * kv.w;
        }
        mx = fmaxf(mx, s);
    }
    red[t] = mx;
    __syncthreads();
    for (int s = 128; s > 0; s >>= 1) {
        if (t < s) red[t] = fmaxf(red[t], red[t + s]);
        __syncthreads();
    }
    if (t == 0) {
        const float4* q4 = (const float4*)qrow;
        const float4* k4 = (const float4*)&Kmean[bh * DH];
        float md = 0.f;
        #pragma unroll
        for (int i = 0; i < 16; i++) {
            float4 a = q4[i], b = k4[i];
            md += a.x * b.x + a.y * b.y + a.z * b.z + a.w * b.w;
        }
        EM[bh * NCAND + j] = SCALEF * red[0] - SCALEF * md;
    }
}

// ---------------------------------------------------------------------------
// Final top-38 among 64 candidates by exact M. (unchanged)
// ---------------------------------------------------------------------------
__global__ __launch_bounds__(64) void select_kernel(const float* __restrict__ EM,
                                                    const int* __restrict__ CAND,
                                                    int* __restrict__ TIDX) {
    const int bh = blockIdx.x;
    const int t  = threadIdx.x;
    float v  = EM[bh * NCAND + t];
    int   qi = CAND[bh * NCAND + t];
    for (int it = 0; it < KTOP; it++) {
        float bv = v; int bq = qi;
        #pragma unroll
        for (int off = 1; off < 64; off <<= 1) {
            float ov = __shfl_xor(bv, off);
            int   oq = __shfl_xor(bq, off);
            if (ov > bv || (ov == bv && oq < bq)) { bv = ov; bq = oq; }
        }
        if (t == 0) TIDX[bh * KTOP + it] = bq;
        if (qi == bq) v = -3.4e38f;
    }
}

// ---------------------------------------------------------------------------
// Fill context (bf16 hi/lo) with per-head V mean. float4-vectorized.
// ---------------------------------------------------------------------------
__global__ __launch_bounds__(256) void fill_kernel(const float* __restrict__ Vmean,
                                                   ushort* __restrict__ CH,
                                                   ushort* __restrict__ CL) {
    const size_t c = (size_t)blockIdx.x * 256 + threadIdx.x;   // chunk of 4
    const int d4 = (int)(c & 15) * 4;
    const int bh = (int)(c >> 15);                              // / (2048*64/4)
    const float4 v = *(const float4*)&Vmean[bh * DH + d4];
    ushort4 h, l;
    h.x = f32_to_bf16_rn(v.x); l.x = f32_to_bf16_rn(v.x - bf16_to_f32(h.x));
    h.y = f32_to_bf16_rn(v.y); l.y = f32_to_bf16_rn(v.y - bf16_to_f32(h.y));
    h.z = f32_to_bf16_rn(v.z); l.z = f32_to_bf16_rn(v.z - bf16_to_f32(h.z));
    h.w = f32_to_bf16_rn(v.w); l.w = f32_to_bf16_rn(v.w - bf16_to_f32(h.w));
    *(ushort4*)&CH[c * 4] = h;
    *(ushort4*)&CL[c * 4] = l;
}

// ---------------------------------------------------------------------------
// Sparse attention: context row -> bf16 hi/lo (fused split). LDS-staged K.
// ---------------------------------------------------------------------------
__global__ __launch_bounds__(256) void sparse_kernel(const float* __restrict__ Q,
                                                     const float* __restrict__ K,
                                                     const float* __restrict__ V,
                                                     const int* __restrict__ top_idx,
                                                     ushort* __restrict__ CH,
                                                     ushort* __restrict__ CL) {
    __shared__ float Kt[128][65];
    __shared__ float sc[LL];
    __shared__ float qrow[DH];
    __shared__ float red[256];
    const int bh = blockIdx.y;
    const int q  = top_idx[bh * KTOP + blockIdx.x];
    const int t  = threadIdx.x;

    if (t < DH) qrow[t] = Q[((size_t)bh * LL + q) * DH + t];
    __syncthreads();

    const int kk = t & 127, half = t >> 7;
    for (int kt = 0; kt < LL / 128; kt++) {
        #pragma unroll
        for (int i = 0; i < 8; i++) {
            int f = i * 256 + t;
            int row = f >> 4, c4 = f & 15;
            const float4 v = *(const float4*)&K[((size_t)(bh * LL + kt * 128 + row)) * DH + c4 * 4];
            *(float4*)&Kt[row][c4 * 4] = v;
        }
        __syncthreads();
        float s = 0.f;
        #pragma unroll
        for (int c = 0; c < 8; c++) {
            const float4 kv = *(const float4*)&Kt[kk][half * 32 + c * 4];
            const float4 qv = *(const float4*)&qrow[half * 32 + c * 4];
            s += qv.x * kv.x + qv.y * kv.y + qv.z * kv.z + qv.w * kv.w;
        }
        red[t] = s;
        __syncthreads();
        if (t < 128) sc[kt * 128 + t] = (red[t] + red[t + 128]) * SCALEF;
        __syncthreads();
    }

    float m1 = -3.4e38f;
    #pragma unroll
    for (int i = 0; i < 8; i++) m1 = fmaxf(m1, sc[i * 256 + t]);
    red[t] = m1; __syncthreads();
    for (int s = 128; s > 0; s >>= 1) {
        if (t < s) red[t] = fmaxf(red[t], red[t + s]);
        __syncthreads();
    }
    const float mx = red[0];
    __syncthreads();
    float s1 = 0.f;
    #pragma unroll
    for (int i = 0; i < 8; i++) {
        float e = __expf(sc[i * 256 + t] - mx);
        sc[i * 256 + t] = e;
        s1 += e;
    }
    red[t] = s1; __syncthreads();
    for (int s = 128; s > 0; s >>= 1) {
        if (t < s) red[t] += red[t + s];
        __syncthreads();
    }
    const float inv = 1.0f / red[0];
    __syncthreads();

    const int d4 = (t & 15) * 4, ch = t >> 4;
    float4 acc = {0.f, 0.f, 0.f, 0.f};
    for (int i = 0; i < 128; i++) {
        int k = ch * 128 + i;
        const float4 v = *(const float4*)&V[((size_t)(bh * LL + k)) * DH + d4];
        const float p = sc[k];
        acc.x += p * v.x; acc.y += p * v.y; acc.z += p * v.z; acc.w += p * v.w;
    }
    __syncthreads();
    *(float4*)&sc[ch * 64 + d4] = acc;
    __syncthreads();
    if (t < 64) {
        float r = 0.f;
        #pragma unroll
        for (int c = 0; c < 16; c++) r += sc[c * 64 + t];
        const float v = r * inv;
        const size_t off = ((size_t)bh * LL + q) * DH + t;
        const ushort h = f32_to_bf16_rn(v);
        CH[off] = h;
        CL[off] = f32_to_bf16_rn(v - bf16_to_f32(h));
    }
}

// ---------------------------------------------------------------------------
extern "C" void kernel_launch(void* const* d_in, const int* in_sizes, int n_in,
                              void* d_out, int out_size, void* d_ws, size_t ws_size,
                              hipStream_t stream) {
    const float* x  = (const float*)d_in[0];
    const float* Wq = (const float*)d_in[1];
    const float* bq = (const float*)d_in[2];
    const float* Wk = (const float*)d_in[3];
    const float* bk = (const float*)d_in[4];
    const float* Wv = (const float*)d_in[5];
    const float* bv = (const float*)d_in[6];
    const float* Wo = (const float*)d_in[7];
    const float* bo = (const float*)d_in[8];
    float* out = (float*)d_out;

    float* ws = (float*)d_ws;
    const size_t QSZ = (size_t)BH * LL * DH;   // 4,194,304 elements
    float* Qp    = ws;
    float* Kp    = ws + QSZ;
    float* Vp    = ws + 2 * QSZ;
    float* Mp    = ws + 3 * QSZ;               // BH*L
    float* KMEAN = Mp + (size_t)BH * LL;
    float* VMEAN = KMEAN + BH * DH;
    float* EM    = VMEAN + BH * DH;            // BH*NCAND
    int*   CAND  = (int*)(EM + BH * NCAND);
    int*   TIDX  = CAND + BH * NCAND;
    ushort* WTH  = (ushort*)(ws + 3 * QSZ + 131072);   // 4 x 512x512 bf16 hi
    ushort* WTL  = WTH + (size_t)4 * DD * DD;          // 4 x 512x512 bf16 lo
    ushort* XH   = WTL + (size_t)4 * DD * DD;          // x split hi (8192x512)
    ushort* XL   = XH + QSZ;
    ushort* CH   = XH;                                 // CTX split aliases X (x dead after projections)
    ushort* CL   = XL;
    ushort* KH   = XL + QSZ;                           // K split hi [bh][l][dh]
    const size_t WOFF = (size_t)DD * DD;

    split_wT<<<dim3(16, 16, 4), 256, 0, stream>>>(Wq, Wk, Wv, Wo, WTH, WTL);
    split_x<<<(int)(QSZ / 1024), 256, 0, stream>>>(x, XH, XL);

    const dim3 gemm_grid(DD / 64, (BB * LL) / 128);    // (8, 64)
    mfma_gemm<0, 1, 0><<<gemm_grid, 256, 0, stream>>>(XH, XL, WTH,            WTL,            bq, Qp, nullptr);
    mfma_gemm<0, 1, 1><<<gemm_grid, 256, 0, stream>>>(XH, XL, WTH + WOFF,     WTL + WOFF,     bk, Kp, KH);
    mfma_gemm<0, 1, 0><<<gemm_grid, 256, 0, stream>>>(XH, XL, WTH + 2 * WOFF, WTL + 2 * WOFF, bv, Vp, nullptr);

    mean_kernel<<<dim3(BH, 2), 256, 0, stream>>>(Kp, Vp, KMEAN, VMEAN);

    mfma_stats<<<dim3(LL / 128, BH), 256, 0, stream>>>(Qp, KH, KMEAN, Mp);

    topk_kernel<<<BH, 256, 0, stream>>>(Mp, CAND, NCAND, NCAND);

    exact_kernel<<<dim3(NCAND, BH), 256, 0, stream>>>(Qp, Kp, KMEAN, CAND, EM);

    select_kernel<<<BH, 64, 0, stream>>>(EM, CAND, TIDX);

    fill_kernel<<<(int)(QSZ / 1024), 256, 0, stream>>>(VMEAN, CH, CL);

    sparse_kernel<<<dim3(KTOP, BH), 256, 0, stream>>>(Qp, Kp, Vp, TIDX, CH, CL);

    mfma_gemm<1, 0, 0><<<gemm_grid, 256, 0, stream>>>(CH, CL, WTH + 3 * WOFF, WTL + 3 * WOFF, bo, out, nullptr);
}

// Round 5
// 526.253 us; speedup vs baseline: 2.2681x; 1.2507x over previous
//
#include <hip/hip_runtime.h>

#define BB   4
#define LL   2048
#define DD   512
#define HH   8
#define DH   64
#define BH   32          // B*H
#define KTOP 38
#define NCAND 64         // approx-M candidate pool for exact refinement
#define SCALEF 0.125f    // 1/sqrt(64)

typedef __attribute__((ext_vector_type(8))) short bf16x8;
typedef __attribute__((ext_vector_type(8))) unsigned short ushort8;
typedef __attribute__((ext_vector_type(4))) float f32x4;

__device__ __forceinline__ ushort f32_to_bf16_rn(float x) {
    unsigned u = __float_as_uint(x);
    u += 0x7fffu + ((u >> 16) & 1u);
    return (ushort)(u >> 16);
}
__device__ __forceinline__ float bf16_to_f32(ushort h) {
    return __uint_as_float(((unsigned)h) << 16);
}

// ---------------------------------------------------------------------------
// Elementwise split: fp32 array -> bf16 hi + lo arrays (layout-preserving).
// ---------------------------------------------------------------------------
__global__ __launch_bounds__(256) void split_x(const float* __restrict__ X,
                                               ushort* __restrict__ XH,
                                               ushort* __restrict__ XL) {
    const size_t c = (size_t)blockIdx.x * 256 + threadIdx.x;
    const float4 v = *(const float4*)&X[c * 4];
    ushort4 h, l;
    h.x = f32_to_bf16_rn(v.x); l.x = f32_to_bf16_rn(v.x - bf16_to_f32(h.x));
    h.y = f32_to_bf16_rn(v.y); l.y = f32_to_bf16_rn(v.y - bf16_to_f32(h.y));
    h.z = f32_to_bf16_rn(v.z); l.z = f32_to_bf16_rn(v.z - bf16_to_f32(h.z));
    h.w = f32_to_bf16_rn(v.w); l.w = f32_to_bf16_rn(v.w - bf16_to_f32(h.w));
    *(ushort4*)&XH[c * 4] = h;
    *(ushort4*)&XL[c * 4] = l;
}

// ---------------------------------------------------------------------------
// Prep: transpose + split 4 weight matrices W[k][n] into WT_H/WT_L [n][k] bf16.
// ---------------------------------------------------------------------------
__global__ __launch_bounds__(256) void split_wT(const float* __restrict__ W0,
                                                const float* __restrict__ W1,
                                                const float* __restrict__ W2,
                                                const float* __restrict__ W3,
                                                ushort* __restrict__ WTH,
                                                ushort* __restrict__ WTL) {
    __shared__ float tile[32][33];
    const int z = blockIdx.z;
    const float* W = (z == 0) ? W0 : (z == 1) ? W1 : (z == 2) ? W2 : W3;
    ushort* oh = WTH + (size_t)z * DD * DD;
    ushort* ol = WTL + (size_t)z * DD * DD;
    const int n0 = blockIdx.x * 32, k0 = blockIdx.y * 32;
    const int t = threadIdx.x;
    const int r = t >> 5, c = t & 31;
    #pragma unroll
    for (int i = 0; i < 4; i++)
        tile[r + i * 8][c] = W[(size_t)(k0 + r + i * 8) * DD + n0 + c];
    __syncthreads();
    #pragma unroll
    for (int i = 0; i < 4; i++) {
        int row = r + i * 8;
        float v = tile[c][row];
        ushort h = f32_to_bf16_rn(v);
        oh[(size_t)(n0 + row) * DD + k0 + c] = h;
        ol[(size_t)(n0 + row) * DD + k0 + c] = f32_to_bf16_rn(v - bf16_to_f32(h));
    }
}

// ---------------------------------------------------------------------------
// Split-bf16 MFMA GEMM: A direct-from-global fragments, B LDS-staged.
// (unchanged R4)
// ---------------------------------------------------------------------------
template <int APERM, int YPERM, int WSPLIT>
__global__ __launch_bounds__(256) void mfma_gemm(const ushort* __restrict__ AH,
                                                 const ushort* __restrict__ AL,
                                                 const ushort* __restrict__ BTH,
                                                 const ushort* __restrict__ BTL,
                                                 const float* __restrict__ bias,
                                                 float* __restrict__ Y,
                                                 ushort* __restrict__ YH) {
    __shared__ ushort BHs[64 * 40];
    __shared__ ushort BLs[64 * 40];

    const int t = threadIdx.x;
    const int w = t >> 6, lane = t & 63;
    const int quad = lane >> 4, n16 = lane & 15;
    const int row0 = blockIdx.y * 128;
    const int n0   = blockIdx.x * 64;

    f32x4 acc[2][4] = {};

    size_t arow_off[2];
    #pragma unroll
    for (int mt = 0; mt < 2; mt++) {
        int R = row0 + w * 32 + mt * 16 + n16;
        if (APERM) {
            int b = R >> 11, l = R & 2047;
            arow_off[mt] = ((size_t)b * HH) * LL * DH + (size_t)l * DH;
        } else {
            arow_off[mt] = (size_t)R * DD;
        }
    }

    const int brow = t >> 2, bc8 = t & 3;

    for (int k0 = 0; k0 < DD; k0 += 32) {
        {
            const size_t goff = (size_t)(n0 + brow) * DD + k0 + bc8 * 8;
            const uint4 vh = *(const uint4*)&BTH[goff];
            const uint4 vl = *(const uint4*)&BTL[goff];
            *(uint4*)&BHs[brow * 40 + bc8 * 8] = vh;
            *(uint4*)&BLs[brow * 40 + bc8 * 8] = vl;
        }
        bf16x8 ah[2], al[2];
        #pragma unroll
        for (int mt = 0; mt < 2; mt++) {
            int k = k0 + quad * 8;
            size_t off;
            if (APERM) {
                int h = k >> 6, dh = k & 63;
                off = arow_off[mt] + (size_t)h * LL * DH + dh;
            } else {
                off = arow_off[mt] + k;
            }
            ah[mt] = *(const bf16x8*)&AH[off];
            al[mt] = *(const bf16x8*)&AL[off];
        }
        __syncthreads();

        bf16x8 bh[4], bl[4];
        #pragma unroll
        for (int nt = 0; nt < 4; nt++) {
            int off = (nt * 16 + n16) * 40 + quad * 8;
            bh[nt] = *(const bf16x8*)&BHs[off];
            bl[nt] = *(const bf16x8*)&BLs[off];
        }
        #pragma unroll
        for (int mt = 0; mt < 2; mt++)
            #pragma unroll
            for (int nt = 0; nt < 4; nt++) {
                acc[mt][nt] = __builtin_amdgcn_mfma_f32_16x16x32_bf16(ah[mt], bh[nt], acc[mt][nt], 0, 0, 0);
                acc[mt][nt] = __builtin_amdgcn_mfma_f32_16x16x32_bf16(ah[mt], bl[nt], acc[mt][nt], 0, 0, 0);
                acc[mt][nt] = __builtin_amdgcn_mfma_f32_16x16x32_bf16(al[mt], bh[nt], acc[mt][nt], 0, 0, 0);
            }
        __syncthreads();
    }

    #pragma unroll
    for (int mt = 0; mt < 2; mt++)
        #pragma unroll
        for (int nt = 0; nt < 4; nt++) {
            const int c = n0 + nt * 16 + n16;
            const float bv = bias[c];
            #pragma unroll
            for (int r = 0; r < 4; r++) {
                int m = w * 32 + mt * 16 + quad * 4 + r;
                int R = row0 + m;
                float v = acc[mt][nt][r] + bv;
                size_t off;
                if (YPERM) {
                    int b = R >> 11, l = R & 2047;
                    int h = c >> 6, dh = c & 63;
                    off = (((size_t)(b * HH + h)) * LL + l) * DH + dh;
                } else {
                    off = (size_t)R * DD + c;
                }
                Y[off] = v;
                if (WSPLIT) YH[off] = f32_to_bf16_rn(v);
            }
        }
}

// ---------------------------------------------------------------------------
// Mean V2 phase 1: partial sums. grid (BH, 2, 16); block sums 128 rows.
// partial[((bh*2+src)*16+z)*64 + d]
// ---------------------------------------------------------------------------
__global__ __launch_bounds__(256) void mean_partial(const float* __restrict__ Kp,
                                                    const float* __restrict__ Vp,
                                                    float* __restrict__ partial) {
    __shared__ float red[256];
    const int bh = blockIdx.x;
    const int srcI = blockIdx.y;
    const int z  = blockIdx.z;
    const float* src = srcI ? Vp : Kp;
    const int t = threadIdx.x;
    const int d = t & 63, ch = t >> 6;
    const int l0 = z * 128 + ch * 32;
    float s = 0.f;
    for (int l = l0; l < l0 + 32; l++)
        s += src[((size_t)bh * LL + l) * DH + d];
    red[t] = s;
    __syncthreads();
    if (t < 64)
        partial[((size_t)((bh * 2 + srcI) * 16 + z)) * 64 + t] =
            red[t] + red[t + 64] + red[t + 128] + red[t + 192];
}

// ---------------------------------------------------------------------------
// Mean V2 phase 2: fold 16 partials. grid (BH, 2), 64 thr.
// ---------------------------------------------------------------------------
__global__ __launch_bounds__(64) void mean_reduce(const float* __restrict__ partial,
                                                  float* __restrict__ Kmean,
                                                  float* __restrict__ Vmean) {
    const int bh = blockIdx.x;
    const int srcI = blockIdx.y;
    const int t  = threadIdx.x;
    float s = 0.f;
    #pragma unroll
    for (int z = 0; z < 16; z++)
        s += partial[((size_t)((bh * 2 + srcI) * 16 + z)) * 64 + t];
    float* dst = srcI ? Vmean : Kmean;
    dst[bh * DH + t] = s * (1.0f / LL);
}

// ---------------------------------------------------------------------------
// Approx M V2: 2-term MFMA (Qhi+Qlo)*Khi. (unchanged R4)
// ---------------------------------------------------------------------------
__global__ __launch_bounds__(256) void mfma_stats(const float* __restrict__ Qp,
                                                  const ushort* __restrict__ KH,
                                                  const float* __restrict__ Kmean,
                                                  float* __restrict__ M) {
    __shared__ ushort KS[128 * 72];
    __shared__ float  Km[64];
    __shared__ float  mdS[128];

    const int bh = blockIdx.y;
    const int q0 = blockIdx.x * 128;
    const int t    = threadIdx.x;
    const int w    = t >> 6;
    const int lane = t & 63;
    const int quad = lane >> 4;
    const int n16  = lane & 15;

    if (t < 64) Km[t] = Kmean[bh * DH + t];
    __syncthreads();
    if (t < 128) {
        const float4* qr = (const float4*)&Qp[((size_t)bh * LL + q0 + t) * DH];
        const float4* km4 = (const float4*)Km;
        float md = 0.f;
        #pragma unroll
        for (int i = 0; i < 16; i++) {
            float4 a = qr[i], b = km4[i];
            md += a.x * b.x + a.y * b.y + a.z * b.z + a.w * b.w;
        }
        mdS[t] = md;
    }

    bf16x8 aH[2][2], aL[2][2];
    #pragma unroll
    for (int mt = 0; mt < 2; mt++) {
        const float* qrp = &Qp[((size_t)bh * LL + q0 + w * 32 + mt * 16 + n16) * DH + quad * 8];
        float v[16];
        *(float4*)&v[0]  = *(const float4*)(qrp);
        *(float4*)&v[4]  = *(const float4*)(qrp + 4);
        *(float4*)&v[8]  = *(const float4*)(qrp + 32);
        *(float4*)&v[12] = *(const float4*)(qrp + 36);
        #pragma unroll
        for (int j = 0; j < 8; j++) {
            ushort h0 = f32_to_bf16_rn(v[j]);
            aH[mt][0][j] = (short)h0;
            aL[mt][0][j] = (short)f32_to_bf16_rn(v[j] - bf16_to_f32(h0));
            ushort h1 = f32_to_bf16_rn(v[8 + j]);
            aH[mt][1][j] = (short)h1;
            aL[mt][1][j] = (short)f32_to_bf16_rn(v[8 + j] - bf16_to_f32(h1));
        }
    }

    f32x4 maxv[2] = {{-3.4e38f, -3.4e38f, -3.4e38f, -3.4e38f},
                     {-3.4e38f, -3.4e38f, -3.4e38f, -3.4e38f}};

    for (int kt0 = 0; kt0 < LL; kt0 += 128) {
        __syncthreads();
        #pragma unroll
        for (int i = 0; i < 4; i++) {
            int f = i * 256 + t;
            int row = f >> 3, c8 = f & 7;
            const uint4 v = *(const uint4*)&KH[((size_t)(bh * LL + kt0 + row)) * DH + c8 * 8];
            *(uint4*)&KS[row * 72 + c8 * 8] = v;
        }
        __syncthreads();

        for (int ktl = 0; ktl < 128; ktl += 16) {
            const ushort* bp = &KS[(size_t)(ktl + n16) * 72 + quad * 8];
            bf16x8 bH0 = *(const bf16x8*)(bp);
            bf16x8 bH1 = *(const bf16x8*)(bp + 32);
            #pragma unroll
            for (int mt = 0; mt < 2; mt++) {
                f32x4 acc = {0.f, 0.f, 0.f, 0.f};
                acc = __builtin_amdgcn_mfma_f32_16x16x32_bf16(aH[mt][0], bH0, acc, 0, 0, 0);
                acc = __builtin_amdgcn_mfma_f32_16x16x32_bf16(aH[mt][1], bH1, acc, 0, 0, 0);
                acc = __builtin_amdgcn_mfma_f32_16x16x32_bf16(aL[mt][0], bH0, acc, 0, 0, 0);
                acc = __builtin_amdgcn_mfma_f32_16x16x32_bf16(aL[mt][1], bH1, acc, 0, 0, 0);
                maxv[mt][0] = fmaxf(maxv[mt][0], acc[0]);
                maxv[mt][1] = fmaxf(maxv[mt][1], acc[1]);
                maxv[mt][2] = fmaxf(maxv[mt][2], acc[2]);
                maxv[mt][3] = fmaxf(maxv[mt][3], acc[3]);
            }
        }
    }

    #pragma unroll
    for (int off = 1; off < 16; off <<= 1)
        #pragma unroll
        for (int mt = 0; mt < 2; mt++)
            #pragma unroll
            for (int r = 0; r < 4; r++)
                maxv[mt][r] = fmaxf(maxv[mt][r], __shfl_xor(maxv[mt][r], off));

    if (n16 == 0) {
        #pragma unroll
        for (int mt = 0; mt < 2; mt++)
            #pragma unroll
            for (int r = 0; r < 4; r++) {
                int lq = w * 32 + mt * 16 + quad * 4 + r;
                M[(size_t)bh * LL + q0 + lq] = SCALEF * maxv[mt][r] - SCALEF * mdS[lq];
            }
    }
}

// ---------------------------------------------------------------------------
// Top-k V2: values in registers (8/thread), shuffle-based argmax.
// idx = i*256 + t. First occurrence (lowest index) wins ties.
// ---------------------------------------------------------------------------
__global__ __launch_bounds__(256) void topk_kernel(const float* __restrict__ M,
                                                   int* __restrict__ out_idx,
                                                   int kcount, int ostride) {
    __shared__ float wv[4];
    __shared__ int   wi[4];
    const int bh = blockIdx.x;
    const int t  = threadIdx.x;
    const int w  = t >> 6;
    float v[8];
    #pragma unroll
    for (int i = 0; i < 8; i++) v[i] = M[(size_t)bh * LL + i * 256 + t];

    for (int it = 0; it < kcount; it++) {
        float bv = v[0]; int bi = 0;
        #pragma unroll
        for (int i = 1; i < 8; i++)
            if (v[i] > bv) { bv = v[i]; bi = i; }
        int bidx = bi * 256 + t;
        #pragma unroll
        for (int off = 1; off < 64; off <<= 1) {
            float ov = __shfl_xor(bv, off);
            int   oi = __shfl_xor(bidx, off);
            if (ov > bv || (ov == bv && oi < bidx)) { bv = ov; bidx = oi; }
        }
        if ((t & 63) == 0) { wv[w] = bv; wi[w] = bidx; }
        __syncthreads();
        float fv = wv[0]; int fi = wi[0];
        #pragma unroll
        for (int j = 1; j < 4; j++)
            if (wv[j] > fv || (wv[j] == fv && wi[j] < fi)) { fv = wv[j]; fi = wi[j]; }
        if (t == 0) out_idx[bh * ostride + it] = fi;
        if ((fi & 255) == t) v[fi >> 8] = -3.4e38f;
        __syncthreads();
    }
}

// ---------------------------------------------------------------------------
// Exact fp32 M for one candidate. (unchanged)
// ---------------------------------------------------------------------------
__global__ __launch_bounds__(256) void exact_kernel(const float* __restrict__ Qp,
                                                    const float* __restrict__ Kp,
                                                    const float* __restrict__ Kmean,
                                                    const int* __restrict__ CAND,
                                                    float* __restrict__ EM) {
    __shared__ float qrow[DH];
    __shared__ float red[256];
    __shared__ int   qs;
    const int bh = blockIdx.y;
    const int j  = blockIdx.x;
    const int t  = threadIdx.x;
    if (t == 0) qs = CAND[bh * NCAND + j];
    __syncthreads();
    const int q = qs;
    if (t < DH) qrow[t] = Qp[((size_t)bh * LL + q) * DH + t];
    __syncthreads();

    float mx = -3.4e38f;
    for (int k = t; k < LL; k += 256) {
        const float4* kr = (const float4*)&Kp[((size_t)bh * LL + k) * DH];
        const float4* q4 = (const float4*)qrow;
        float s = 0.f;
        #pragma unroll
        for (int i = 0; i < 16; i++) {
            float4 kv = kr[i], qv = q4[i];
            s += qv.x * kv.x + qv.y * kv.y + qv.z * kv.z + qv.w * kv.w;
        }
        mx = fmaxf(mx, s);
    }
    red[t] = mx;
    __syncthreads();
    for (int s = 128; s > 0; s >>= 1) {
        if (t < s) red[t] = fmaxf(red[t], red[t + s]);
        __syncthreads();
    }
    if (t == 0) {
        const float4* q4 = (const float4*)qrow;
        const float4* k4 = (const float4*)&Kmean[bh * DH];
        float md = 0.f;
        #pragma unroll
        for (int i = 0; i < 16; i++) {
            float4 a = q4[i], b = k4[i];
            md += a.x * b.x + a.y * b.y + a.z * b.z + a.w * b.w;
        }
        EM[bh * NCAND + j] = SCALEF * red[0] - SCALEF * md;
    }
}

// ---------------------------------------------------------------------------
// Final top-38 among 64 candidates by exact M. (unchanged)
// ---------------------------------------------------------------------------
__global__ __launch_bounds__(64) void select_kernel(const float* __restrict__ EM,
                                                    const int* __restrict__ CAND,
                                                    int* __restrict__ TIDX) {
    const int bh = blockIdx.x;
    const int t  = threadIdx.x;
    float v  = EM[bh * NCAND + t];
    int   qi = CAND[bh * NCAND + t];
    for (int it = 0; it < KTOP; it++) {
        float bv = v; int bq = qi;
        #pragma unroll
        for (int off = 1; off < 64; off <<= 1) {
            float ov = __shfl_xor(bv, off);
            int   oq = __shfl_xor(bq, off);
            if (ov > bv || (ov == bv && oq < bq)) { bv = ov; bq = oq; }
        }
        if (t == 0) TIDX[bh * KTOP + it] = bq;
        if (qi == bq) v = -3.4e38f;
    }
}

// ---------------------------------------------------------------------------
// Fill context (bf16 hi/lo) with per-head V mean. (unchanged)
// ---------------------------------------------------------------------------
__global__ __launch_bounds__(256) void fill_kernel(const float* __restrict__ Vmean,
                                                   ushort* __restrict__ CH,
                                                   ushort* __restrict__ CL) {
    const size_t c = (size_t)blockIdx.x * 256 + threadIdx.x;
    const int d4 = (int)(c & 15) * 4;
    const int bh = (int)(c >> 15);
    const float4 v = *(const float4*)&Vmean[bh * DH + d4];
    ushort4 h, l;
    h.x = f32_to_bf16_rn(v.x); l.x = f32_to_bf16_rn(v.x - bf16_to_f32(h.x));
    h.y = f32_to_bf16_rn(v.y); l.y = f32_to_bf16_rn(v.y - bf16_to_f32(h.y));
    h.z = f32_to_bf16_rn(v.z); l.z = f32_to_bf16_rn(v.z - bf16_to_f32(h.z));
    h.w = f32_to_bf16_rn(v.w); l.w = f32_to_bf16_rn(v.w - bf16_to_f32(h.w));
    *(ushort4*)&CH[c * 4] = h;
    *(ushort4*)&CL[c * 4] = l;
}

// ---------------------------------------------------------------------------
// Sparse attention: context row -> bf16 hi/lo. (unchanged)
// ---------------------------------------------------------------------------
__global__ __launch_bounds__(256) void sparse_kernel(const float* __restrict__ Q,
                                                     const float* __restrict__ K,
                                                     const float* __restrict__ V,
                                                     const int* __restrict__ top_idx,
                                                     ushort* __restrict__ CH,
                                                     ushort* __restrict__ CL) {
    __shared__ float Kt[128][65];
    __shared__ float sc[LL];
    __shared__ float qrow[DH];
    __shared__ float red[256];
    const int bh = blockIdx.y;
    const int q  = top_idx[bh * KTOP + blockIdx.x];
    const int t  = threadIdx.x;

    if (t < DH) qrow[t] = Q[((size_t)bh * LL + q) * DH + t];
    __syncthreads();

    const int kk = t & 127, half = t >> 7;
    for (int kt = 0; kt < LL / 128; kt++) {
        #pragma unroll
        for (int i = 0; i < 8; i++) {
            int f = i * 256 + t;
            int row = f >> 4, c4 = f & 15;
            const float4 v = *(const float4*)&K[((size_t)(bh * LL + kt * 128 + row)) * DH + c4 * 4];
            *(float4*)&Kt[row][c4 * 4] = v;
        }
        __syncthreads();
        float s = 0.f;
        #pragma unroll
        for (int c = 0; c < 8; c++) {
            const float4 kv = *(const float4*)&Kt[kk][half * 32 + c * 4];
            const float4 qv = *(const float4*)&qrow[half * 32 + c * 4];
            s += qv.x * kv.x + qv.y * kv.y + qv.z * kv.z + qv.w * kv.w;
        }
        red[t] = s;
        __syncthreads();
        if (t < 128) sc[kt * 128 + t] = (red[t] + red[t + 128]) * SCALEF;
        __syncthreads();
    }

    float m1 = -3.4e38f;
    #pragma unroll
    for (int i = 0; i < 8; i++) m1 = fmaxf(m1, sc[i * 256 + t]);
    red[t] = m1; __syncthreads();
    for (int s = 128; s > 0; s >>= 1) {
        if (t < s) red[t] = fmaxf(red[t], red[t + s]);
        __syncthreads();
    }
    const float mx = red[0];
    __syncthreads();
    float s1 = 0.f;
    #pragma unroll
    for (int i = 0; i < 8; i++) {
        float e = __expf(sc[i * 256 + t] - mx);
        sc[i * 256 + t] = e;
        s1 += e;
    }
    red[t] = s1; __syncthreads();
    for (int s = 128; s > 0; s >>= 1) {
        if (t < s) red[t] += red[t + s];
        __syncthreads();
    }
    const float inv = 1.0f / red[0];
    __syncthreads();

    const int d4 = (t & 15) * 4, ch = t >> 4;
    float4 acc = {0.f, 0.f, 0.f, 0.f};
    for (int i = 0; i < 128; i++) {
        int k = ch * 128 + i;
        const float4 v = *(const float4*)&V[((size_t)(bh * LL + k)) * DH + d4];
        const float p = sc[k];
        acc.x += p * v.x; acc.y += p * v.y; acc.z += p * v.z; acc.w += p * v.w;
    }
    __syncthreads();
    *(float4*)&sc[ch * 64 + d4] = acc;
    __syncthreads();
    if (t < 64) {
        float r = 0.f;
        #pragma unroll
        for (int c = 0; c < 16; c++) r += sc[c * 64 + t];
        const float v = r * inv;
        const size_t off = ((size_t)bh * LL + q) * DH + t;
        const ushort h = f32_to_bf16_rn(v);
        CH[off] = h;
        CL[off] = f32_to_bf16_rn(v - bf16_to_f32(h));
    }
}

// ---------------------------------------------------------------------------
extern "C" void kernel_launch(void* const* d_in, const int* in_sizes, int n_in,
                              void* d_out, int out_size, void* d_ws, size_t ws_size,
                              hipStream_t stream) {
    const float* x  = (const float*)d_in[0];
    const float* Wq = (const float*)d_in[1];
    const float* bq = (const float*)d_in[2];
    const float* Wk = (const float*)d_in[3];
    const float* bk = (const float*)d_in[4];
    const float* Wv = (const float*)d_in[5];
    const float* bv = (const float*)d_in[6];
    const float* Wo = (const float*)d_in[7];
    const float* bo = (const float*)d_in[8];
    float* out = (float*)d_out;

    float* ws = (float*)d_ws;
    const size_t QSZ = (size_t)BH * LL * DH;   // 4,194,304 elements
    float* Qp    = ws;
    float* Kp    = ws + QSZ;
    float* Vp    = ws + 2 * QSZ;
    float* Mp    = ws + 3 * QSZ;               // BH*L
    float* KMEAN = Mp + (size_t)BH * LL;
    float* VMEAN = KMEAN + BH * DH;
    float* EM    = VMEAN + BH * DH;            // BH*NCAND
    int*   CAND  = (int*)(EM + BH * NCAND);
    int*   TIDX  = CAND + BH * NCAND;
    float* MEANP = (float*)(TIDX + BH * KTOP); // 64*16*64 = 65536 floats
    ushort* WTH  = (ushort*)(ws + 3 * QSZ + 262144);   // 4 x 512x512 bf16 hi
    ushort* WTL  = WTH + (size_t)4 * DD * DD;
    ushort* XH   = WTL + (size_t)4 * DD * DD;          // x split hi
    ushort* XL   = XH + QSZ;
    ushort* CH   = XH;                                 // CTX aliases X
    ushort* CL   = XL;
    ushort* KH   = XL + QSZ;                           // K split hi
    const size_t WOFF = (size_t)DD * DD;

    split_wT<<<dim3(16, 16, 4), 256, 0, stream>>>(Wq, Wk, Wv, Wo, WTH, WTL);
    split_x<<<(int)(QSZ / 1024), 256, 0, stream>>>(x, XH, XL);

    const dim3 gemm_grid(DD / 64, (BB * LL) / 128);    // (8, 64)
    mfma_gemm<0, 1, 0><<<gemm_grid, 256, 0, stream>>>(XH, XL, WTH,            WTL,            bq, Qp, nullptr);
    mfma_gemm<0, 1, 1><<<gemm_grid, 256, 0, stream>>>(XH, XL, WTH + WOFF,     WTL + WOFF,     bk, Kp, KH);
    mfma_gemm<0, 1, 0><<<gemm_grid, 256, 0, stream>>>(XH, XL, WTH + 2 * WOFF, WTL + 2 * WOFF, bv, Vp, nullptr);

    mean_partial<<<dim3(BH, 2, 16), 256, 0, stream>>>(Kp, Vp, MEANP);
    mean_reduce<<<dim3(BH, 2), 64, 0, stream>>>(MEANP, KMEAN, VMEAN);

    mfma_stats<<<dim3(LL / 128, BH), 256, 0, stream>>>(Qp, KH, KMEAN, Mp);

    topk_kernel<<<BH, 256, 0, stream>>>(Mp, CAND, NCAND, NCAND);

    exact_kernel<<<dim3(NCAND, BH), 256, 0, stream>>>(Qp, Kp, KMEAN, CAND, EM);

    select_kernel<<<BH, 64, 0, stream>>>(EM, CAND, TIDX);

    fill_kernel<<<(int)(QSZ / 1024), 256, 0, stream>>>(VMEAN, CH, CL);

    sparse_kernel<<<dim3(KTOP, BH), 256, 0, stream>>>(Qp, Kp, Vp, TIDX, CH, CL);

    mfma_gemm<1, 0, 0><<<gemm_grid, 256, 0, stream>>>(CH, CL, WTH + 3 * WOFF, WTL + 3 * WOFF, bo, out, nullptr);
}

// Round 6
// 429.459 us; speedup vs baseline: 2.7793x; 1.2254x over previous
//
#include <hip/hip_runtime.h>

#define BB   4
#define LL   2048
#define DD   512
#define HH   8
#define DH   64
#define BH   32          // B*H
#define KTOP 38
#define NCAND 64         // approx-M candidate pool for exact refinement
#define SCALEF 0.125f    // 1/sqrt(64)

typedef __attribute__((ext_vector_type(8))) short bf16x8;
typedef __attribute__((ext_vector_type(8))) unsigned short ushort8;
typedef __attribute__((ext_vector_type(4))) float f32x4;

__device__ __forceinline__ ushort f32_to_bf16_rn(float x) {
    unsigned u = __float_as_uint(x);
    u += 0x7fffu + ((u >> 16) & 1u);
    return (ushort)(u >> 16);
}
__device__ __forceinline__ float bf16_to_f32(ushort h) {
    return __uint_as_float(((unsigned)h) << 16);
}

// ---------------------------------------------------------------------------
// Elementwise split: fp32 array -> bf16 hi + lo arrays (layout-preserving).
// ---------------------------------------------------------------------------
__global__ __launch_bounds__(256) void split_x(const float* __restrict__ X,
                                               ushort* __restrict__ XH,
                                               ushort* __restrict__ XL) {
    const size_t c = (size_t)blockIdx.x * 256 + threadIdx.x;
    const float4 v = *(const float4*)&X[c * 4];
    ushort4 h, l;
    h.x = f32_to_bf16_rn(v.x); l.x = f32_to_bf16_rn(v.x - bf16_to_f32(h.x));
    h.y = f32_to_bf16_rn(v.y); l.y = f32_to_bf16_rn(v.y - bf16_to_f32(h.y));
    h.z = f32_to_bf16_rn(v.z); l.z = f32_to_bf16_rn(v.z - bf16_to_f32(h.z));
    h.w = f32_to_bf16_rn(v.w); l.w = f32_to_bf16_rn(v.w - bf16_to_f32(h.w));
    *(ushort4*)&XH[c * 4] = h;
    *(ushort4*)&XL[c * 4] = l;
}

// ---------------------------------------------------------------------------
// Prep: transpose + split 4 weight matrices W[k][n] into WT_H/WT_L [n][k] bf16.
// ---------------------------------------------------------------------------
__global__ __launch_bounds__(256) void split_wT(const float* __restrict__ W0,
                                                const float* __restrict__ W1,
                                                const float* __restrict__ W2,
                                                const float* __restrict__ W3,
                                                ushort* __restrict__ WTH,
                                                ushort* __restrict__ WTL) {
    __shared__ float tile[32][33];
    const int z = blockIdx.z;
    const float* W = (z == 0) ? W0 : (z == 1) ? W1 : (z == 2) ? W2 : W3;
    ushort* oh = WTH + (size_t)z * DD * DD;
    ushort* ol = WTL + (size_t)z * DD * DD;
    const int n0 = blockIdx.x * 32, k0 = blockIdx.y * 32;
    const int t = threadIdx.x;
    const int r = t >> 5, c = t & 31;
    #pragma unroll
    for (int i = 0; i < 4; i++)
        tile[r + i * 8][c] = W[(size_t)(k0 + r + i * 8) * DD + n0 + c];
    __syncthreads();
    #pragma unroll
    for (int i = 0; i < 4; i++) {
        int row = r + i * 8;
        float v = tile[c][row];
        ushort h = f32_to_bf16_rn(v);
        oh[(size_t)(n0 + row) * DD + k0 + c] = h;
        ol[(size_t)(n0 + row) * DD + k0 + c] = f32_to_bf16_rn(v - bf16_to_f32(h));
    }
}

// ---------------------------------------------------------------------------
// Split-bf16 MFMA GEMM: A direct-from-global fragments, B LDS-staged.
// (unchanged R4)
// ---------------------------------------------------------------------------
template <int APERM, int YPERM, int WSPLIT>
__global__ __launch_bounds__(256) void mfma_gemm(const ushort* __restrict__ AH,
                                                 const ushort* __restrict__ AL,
                                                 const ushort* __restrict__ BTH,
                                                 const ushort* __restrict__ BTL,
                                                 const float* __restrict__ bias,
                                                 float* __restrict__ Y,
                                                 ushort* __restrict__ YH) {
    __shared__ ushort BHs[64 * 40];
    __shared__ ushort BLs[64 * 40];

    const int t = threadIdx.x;
    const int w = t >> 6, lane = t & 63;
    const int quad = lane >> 4, n16 = lane & 15;
    const int row0 = blockIdx.y * 128;
    const int n0   = blockIdx.x * 64;

    f32x4 acc[2][4] = {};

    size_t arow_off[2];
    #pragma unroll
    for (int mt = 0; mt < 2; mt++) {
        int R = row0 + w * 32 + mt * 16 + n16;
        if (APERM) {
            int b = R >> 11, l = R & 2047;
            arow_off[mt] = ((size_t)b * HH) * LL * DH + (size_t)l * DH;
        } else {
            arow_off[mt] = (size_t)R * DD;
        }
    }

    const int brow = t >> 2, bc8 = t & 3;

    for (int k0 = 0; k0 < DD; k0 += 32) {
        {
            const size_t goff = (size_t)(n0 + brow) * DD + k0 + bc8 * 8;
            const uint4 vh = *(const uint4*)&BTH[goff];
            const uint4 vl = *(const uint4*)&BTL[goff];
            *(uint4*)&BHs[brow * 40 + bc8 * 8] = vh;
            *(uint4*)&BLs[brow * 40 + bc8 * 8] = vl;
        }
        bf16x8 ah[2], al[2];
        #pragma unroll
        for (int mt = 0; mt < 2; mt++) {
            int k = k0 + quad * 8;
            size_t off;
            if (APERM) {
                int h = k >> 6, dh = k & 63;
                off = arow_off[mt] + (size_t)h * LL * DH + dh;
            } else {
                off = arow_off[mt] + k;
            }
            ah[mt] = *(const bf16x8*)&AH[off];
            al[mt] = *(const bf16x8*)&AL[off];
        }
        __syncthreads();

        bf16x8 bh[4], bl[4];
        #pragma unroll
        for (int nt = 0; nt < 4; nt++) {
            int off = (nt * 16 + n16) * 40 + quad * 8;
            bh[nt] = *(const bf16x8*)&BHs[off];
            bl[nt] = *(const bf16x8*)&BLs[off];
        }
        #pragma unroll
        for (int mt = 0; mt < 2; mt++)
            #pragma unroll
            for (int nt = 0; nt < 4; nt++) {
                acc[mt][nt] = __builtin_amdgcn_mfma_f32_16x16x32_bf16(ah[mt], bh[nt], acc[mt][nt], 0, 0, 0);
                acc[mt][nt] = __builtin_amdgcn_mfma_f32_16x16x32_bf16(ah[mt], bl[nt], acc[mt][nt], 0, 0, 0);
                acc[mt][nt] = __builtin_amdgcn_mfma_f32_16x16x32_bf16(al[mt], bh[nt], acc[mt][nt], 0, 0, 0);
            }
        __syncthreads();
    }

    #pragma unroll
    for (int mt = 0; mt < 2; mt++)
        #pragma unroll
        for (int nt = 0; nt < 4; nt++) {
            const int c = n0 + nt * 16 + n16;
            const float bv = bias[c];
            #pragma unroll
            for (int r = 0; r < 4; r++) {
                int m = w * 32 + mt * 16 + quad * 4 + r;
                int R = row0 + m;
                float v = acc[mt][nt][r] + bv;
                size_t off;
                if (YPERM) {
                    int b = R >> 11, l = R & 2047;
                    int h = c >> 6, dh = c & 63;
                    off = (((size_t)(b * HH + h)) * LL + l) * DH + dh;
                } else {
                    off = (size_t)R * DD + c;
                }
                Y[off] = v;
                if (WSPLIT) YH[off] = f32_to_bf16_rn(v);
            }
        }
}

// ---------------------------------------------------------------------------
// Mean phase 1: partial sums. grid (BH, 2, 16); block sums 128 rows.
// ---------------------------------------------------------------------------
__global__ __launch_bounds__(256) void mean_partial(const float* __restrict__ Kp,
                                                    const float* __restrict__ Vp,
                                                    float* __restrict__ partial) {
    __shared__ float red[256];
    const int bh = blockIdx.x;
    const int srcI = blockIdx.y;
    const int z  = blockIdx.z;
    const float* src = srcI ? Vp : Kp;
    const int t = threadIdx.x;
    const int d = t & 63, ch = t >> 6;
    const int l0 = z * 128 + ch * 32;
    float s = 0.f;
    for (int l = l0; l < l0 + 32; l++)
        s += src[((size_t)bh * LL + l) * DH + d];
    red[t] = s;
    __syncthreads();
    if (t < 64)
        partial[((size_t)((bh * 2 + srcI) * 16 + z)) * 64 + t] =
            red[t] + red[t + 64] + red[t + 128] + red[t + 192];
}

// ---------------------------------------------------------------------------
// Mean phase 2: fold 16 partials. grid (BH, 2), 64 thr.
// ---------------------------------------------------------------------------
__global__ __launch_bounds__(64) void mean_reduce(const float* __restrict__ partial,
                                                  float* __restrict__ Kmean,
                                                  float* __restrict__ Vmean) {
    const int bh = blockIdx.x;
    const int srcI = blockIdx.y;
    const int t  = threadIdx.x;
    float s = 0.f;
    #pragma unroll
    for (int z = 0; z < 16; z++)
        s += partial[((size_t)((bh * 2 + srcI) * 16 + z)) * 64 + t];
    float* dst = srcI ? Vmean : Kmean;
    dst[bh * DH + t] = s * (1.0f / LL);
}

// ---------------------------------------------------------------------------
// Approx M: 2-term MFMA (Qhi+Qlo)*Khi. (unchanged R4)
// ---------------------------------------------------------------------------
__global__ __launch_bounds__(256) void mfma_stats(const float* __restrict__ Qp,
                                                  const ushort* __restrict__ KH,
                                                  const float* __restrict__ Kmean,
                                                  float* __restrict__ M) {
    __shared__ ushort KS[128 * 72];
    __shared__ float  Km[64];
    __shared__ float  mdS[128];

    const int bh = blockIdx.y;
    const int q0 = blockIdx.x * 128;
    const int t    = threadIdx.x;
    const int w    = t >> 6;
    const int lane = t & 63;
    const int quad = lane >> 4;
    const int n16  = lane & 15;

    if (t < 64) Km[t] = Kmean[bh * DH + t];
    __syncthreads();
    if (t < 128) {
        const float4* qr = (const float4*)&Qp[((size_t)bh * LL + q0 + t) * DH];
        const float4* km4 = (const float4*)Km;
        float md = 0.f;
        #pragma unroll
        for (int i = 0; i < 16; i++) {
            float4 a = qr[i], b = km4[i];
            md += a.x * b.x + a.y * b.y + a.z * b.z + a.w * b.w;
        }
        mdS[t] = md;
    }

    bf16x8 aH[2][2], aL[2][2];
    #pragma unroll
    for (int mt = 0; mt < 2; mt++) {
        const float* qrp = &Qp[((size_t)bh * LL + q0 + w * 32 + mt * 16 + n16) * DH + quad * 8];
        float v[16];
        *(float4*)&v[0]  = *(const float4*)(qrp);
        *(float4*)&v[4]  = *(const float4*)(qrp + 4);
        *(float4*)&v[8]  = *(const float4*)(qrp + 32);
        *(float4*)&v[12] = *(const float4*)(qrp + 36);
        #pragma unroll
        for (int j = 0; j < 8; j++) {
            ushort h0 = f32_to_bf16_rn(v[j]);
            aH[mt][0][j] = (short)h0;
            aL[mt][0][j] = (short)f32_to_bf16_rn(v[j] - bf16_to_f32(h0));
            ushort h1 = f32_to_bf16_rn(v[8 + j]);
            aH[mt][1][j] = (short)h1;
            aL[mt][1][j] = (short)f32_to_bf16_rn(v[8 + j] - bf16_to_f32(h1));
        }
    }

    f32x4 maxv[2] = {{-3.4e38f, -3.4e38f, -3.4e38f, -3.4e38f},
                     {-3.4e38f, -3.4e38f, -3.4e38f, -3.4e38f}};

    for (int kt0 = 0; kt0 < LL; kt0 += 128) {
        __syncthreads();
        #pragma unroll
        for (int i = 0; i < 4; i++) {
            int f = i * 256 + t;
            int row = f >> 3, c8 = f & 7;
            const uint4 v = *(const uint4*)&KH[((size_t)(bh * LL + kt0 + row)) * DH + c8 * 8];
            *(uint4*)&KS[row * 72 + c8 * 8] = v;
        }
        __syncthreads();

        for (int ktl = 0; ktl < 128; ktl += 16) {
            const ushort* bp = &KS[(size_t)(ktl + n16) * 72 + quad * 8];
            bf16x8 bH0 = *(const bf16x8*)(bp);
            bf16x8 bH1 = *(const bf16x8*)(bp + 32);
            #pragma unroll
            for (int mt = 0; mt < 2; mt++) {
                f32x4 acc = {0.f, 0.f, 0.f, 0.f};
                acc = __builtin_amdgcn_mfma_f32_16x16x32_bf16(aH[mt][0], bH0, acc, 0, 0, 0);
                acc = __builtin_amdgcn_mfma_f32_16x16x32_bf16(aH[mt][1], bH1, acc, 0, 0, 0);
                acc = __builtin_amdgcn_mfma_f32_16x16x32_bf16(aL[mt][0], bH0, acc, 0, 0, 0);
                acc = __builtin_amdgcn_mfma_f32_16x16x32_bf16(aL[mt][1], bH1, acc, 0, 0, 0);
                maxv[mt][0] = fmaxf(maxv[mt][0], acc[0]);
                maxv[mt][1] = fmaxf(maxv[mt][1], acc[1]);
                maxv[mt][2] = fmaxf(maxv[mt][2], acc[2]);
                maxv[mt][3] = fmaxf(maxv[mt][3], acc[3]);
            }
        }
    }

    #pragma unroll
    for (int off = 1; off < 16; off <<= 1)
        #pragma unroll
        for (int mt = 0; mt < 2; mt++)
            #pragma unroll
            for (int r = 0; r < 4; r++)
                maxv[mt][r] = fmaxf(maxv[mt][r], __shfl_xor(maxv[mt][r], off));

    if (n16 == 0) {
        #pragma unroll
        for (int mt = 0; mt < 2; mt++)
            #pragma unroll
            for (int r = 0; r < 4; r++) {
                int lq = w * 32 + mt * 16 + quad * 4 + r;
                M[(size_t)bh * LL + q0 + lq] = SCALEF * maxv[mt][r] - SCALEF * mdS[lq];
            }
    }
}

// ---------------------------------------------------------------------------
// Top-k: values in registers (8/thread), shuffle argmax. (unchanged R5)
// ---------------------------------------------------------------------------
__global__ __launch_bounds__(256) void topk_kernel(const float* __restrict__ M,
                                                   int* __restrict__ out_idx,
                                                   int kcount, int ostride) {
    __shared__ float wv[4];
    __shared__ int   wi[4];
    const int bh = blockIdx.x;
    const int t  = threadIdx.x;
    const int w  = t >> 6;
    float v[8];
    #pragma unroll
    for (int i = 0; i < 8; i++) v[i] = M[(size_t)bh * LL + i * 256 + t];

    for (int it = 0; it < kcount; it++) {
        float bv = v[0]; int bi = 0;
        #pragma unroll
        for (int i = 1; i < 8; i++)
            if (v[i] > bv) { bv = v[i]; bi = i; }
        int bidx = bi * 256 + t;
        #pragma unroll
        for (int off = 1; off < 64; off <<= 1) {
            float ov = __shfl_xor(bv, off);
            int   oi = __shfl_xor(bidx, off);
            if (ov > bv || (ov == bv && oi < bidx)) { bv = ov; bidx = oi; }
        }
        if ((t & 63) == 0) { wv[w] = bv; wi[w] = bidx; }
        __syncthreads();
        float fv = wv[0]; int fi = wi[0];
        #pragma unroll
        for (int j = 1; j < 4; j++)
            if (wv[j] > fv || (wv[j] == fv && wi[j] < fi)) { fv = wv[j]; fi = wi[j]; }
        if (t == 0) out_idx[bh * ostride + it] = fi;
        if ((fi & 255) == t) v[fi >> 8] = -3.4e38f;
        __syncthreads();
    }
}

// ---------------------------------------------------------------------------
// Exact refinement V2, phase 1: per-chunk fp32 max-dot for ALL 64 candidates.
// Grid (8 chunks x BH), 256 thr as 16x16; K streamed through LDS once per
// block (64x reuse across candidates vs R5's per-candidate streaming).
// EMP[(bh*NCAND + cand)*8 + chunk] = max over chunk's 256 keys of Q_cand.K.
// ---------------------------------------------------------------------------
__global__ __launch_bounds__(256) void exact_partial(const float* __restrict__ Qp,
                                                     const float* __restrict__ Kp,
                                                     const int* __restrict__ CAND,
                                                     float* __restrict__ EMP) {
    __shared__ float Qs[64][65];
    __shared__ float Ks[64][65];
    __shared__ int   cidx[64];
    const int bh = blockIdx.y;
    const int chunk = blockIdx.x;       // 256 keys
    const int t = threadIdx.x;
    const int tx = t & 15, ty = t >> 4;

    if (t < 64) cidx[t] = CAND[bh * NCAND + t];
    __syncthreads();
    // stage 64 candidate Q rows (16 threads x float4 per row)
    #pragma unroll
    for (int i = 0; i < 4; i++) {
        int f = i * 256 + t;
        int row = f >> 4, c4 = f & 15;
        const float4 v = *(const float4*)&Qp[((size_t)bh * LL + cidx[row]) * DH + c4 * 4];
        *(float4*)&Qs[row][c4 * 4] = v;
    }

    float mx[4] = {-3.4e38f, -3.4e38f, -3.4e38f, -3.4e38f};

    for (int kt = 0; kt < 4; kt++) {   // 4 tiles x 64 keys
        __syncthreads();
        #pragma unroll
        for (int i = 0; i < 4; i++) {
            int f = i * 256 + t;
            int row = f >> 4, c4 = f & 15;
            const float4 v = *(const float4*)&Kp[((size_t)(bh * LL + chunk * 256 + kt * 64 + row)) * DH + c4 * 4];
            *(float4*)&Ks[row][c4 * 4] = v;
        }
        __syncthreads();
        float acc[4][4] = {};
        #pragma unroll 8
        for (int dd = 0; dd < 64; dd++) {
            float a[4], b[4];
            #pragma unroll
            for (int i = 0; i < 4; i++) a[i] = Qs[ty * 4 + i][dd];
            #pragma unroll
            for (int j = 0; j < 4; j++) b[j] = Ks[tx * 4 + j][dd];
            #pragma unroll
            for (int i = 0; i < 4; i++)
                #pragma unroll
                for (int j = 0; j < 4; j++) acc[i][j] += a[i] * b[j];
        }
        #pragma unroll
        for (int i = 0; i < 4; i++)
            #pragma unroll
            for (int j = 0; j < 4; j++) mx[i] = fmaxf(mx[i], acc[i][j]);
    }

    // reduce max across the 16 tx lanes
    #pragma unroll
    for (int off = 1; off < 16; off <<= 1)
        #pragma unroll
        for (int i = 0; i < 4; i++)
            mx[i] = fmaxf(mx[i], __shfl_xor(mx[i], off));

    if (tx == 0) {
        #pragma unroll
        for (int i = 0; i < 4; i++)
            EMP[((size_t)bh * NCAND + ty * 4 + i) * 8 + chunk] = mx[i];
    }
}

// ---------------------------------------------------------------------------
// Exact refinement V2, phase 2 + final top-38: fold 8 chunk-maxes, exact
// fp32 mean term, shuffle top-38 (value desc, index asc). One wave per bh.
// ---------------------------------------------------------------------------
__global__ __launch_bounds__(64) void select_kernel(const float* __restrict__ EMP,
                                                    const int* __restrict__ CAND,
                                                    const float* __restrict__ Qp,
                                                    const float* __restrict__ Kmean,
                                                    int* __restrict__ TIDX) {
    __shared__ float Km[64];
    const int bh = blockIdx.x;
    const int t  = threadIdx.x;   // 64 threads = 1 wave = 1 candidate each
    Km[t] = Kmean[bh * DH + t];
    __syncthreads();

    const int qi = CAND[bh * NCAND + t];
    float mx = -3.4e38f;
    #pragma unroll
    for (int c = 0; c < 8; c++) mx = fmaxf(mx, EMP[((size_t)bh * NCAND + t) * 8 + c]);

    const float4* qr = (const float4*)&Qp[((size_t)bh * LL + qi) * DH];
    const float4* km4 = (const float4*)Km;
    float md = 0.f;
    #pragma unroll
    for (int i = 0; i < 16; i++) {
        float4 a = qr[i], b = km4[i];
        md += a.x * b.x + a.y * b.y + a.z * b.z + a.w * b.w;
    }
    float v = SCALEF * mx - SCALEF * md;

    for (int it = 0; it < KTOP; it++) {
        float bv = v; int bq = qi;
        #pragma unroll
        for (int off = 1; off < 64; off <<= 1) {
            float ov = __shfl_xor(bv, off);
            int   oq = __shfl_xor(bq, off);
            if (ov > bv || (ov == bv && oq < bq)) { bv = ov; bq = oq; }
        }
        if (t == 0) TIDX[bh * KTOP + it] = bq;
        if (qi == bq) v = -3.4e38f;
    }
}

// ---------------------------------------------------------------------------
// Fill context (bf16 hi/lo) with per-head V mean. (unchanged)
// ---------------------------------------------------------------------------
__global__ __launch_bounds__(256) void fill_kernel(const float* __restrict__ Vmean,
                                                   ushort* __restrict__ CH,
                                                   ushort* __restrict__ CL) {
    const size_t c = (size_t)blockIdx.x * 256 + threadIdx.x;
    const int d4 = (int)(c & 15) * 4;
    const int bh = (int)(c >> 15);
    const float4 v = *(const float4*)&Vmean[bh * DH + d4];
    ushort4 h, l;
    h.x = f32_to_bf16_rn(v.x); l.x = f32_to_bf16_rn(v.x - bf16_to_f32(h.x));
    h.y = f32_to_bf16_rn(v.y); l.y = f32_to_bf16_rn(v.y - bf16_to_f32(h.y));
    h.z = f32_to_bf16_rn(v.z); l.z = f32_to_bf16_rn(v.z - bf16_to_f32(h.z));
    h.w = f32_to_bf16_rn(v.w); l.w = f32_to_bf16_rn(v.w - bf16_to_f32(h.w));
    *(ushort4*)&CH[c * 4] = h;
    *(ushort4*)&CL[c * 4] = l;
}

// ---------------------------------------------------------------------------
// Sparse attention: context row -> bf16 hi/lo. (unchanged)
// ---------------------------------------------------------------------------
__global__ __launch_bounds__(256) void sparse_kernel(const float* __restrict__ Q,
                                                     const float* __restrict__ K,
                                                     const float* __restrict__ V,
                                                     const int* __restrict__ top_idx,
                                                     ushort* __restrict__ CH,
                                                     ushort* __restrict__ CL) {
    __shared__ float Kt[128][65];
    __shared__ float sc[LL];
    __shared__ float qrow[DH];
    __shared__ float red[256];
    const int bh = blockIdx.y;
    const int q  = top_idx[bh * KTOP + blockIdx.x];
    const int t  = threadIdx.x;

    if (t < DH) qrow[t] = Q[((size_t)bh * LL + q) * DH + t];
    __syncthreads();

    const int kk = t & 127, half = t >> 7;
    for (int kt = 0; kt < LL / 128; kt++) {
        #pragma unroll
        for (int i = 0; i < 8; i++) {
            int f = i * 256 + t;
            int row = f >> 4, c4 = f & 15;
            const float4 v = *(const float4*)&K[((size_t)(bh * LL + kt * 128 + row)) * DH + c4 * 4];
            *(float4*)&Kt[row][c4 * 4] = v;
        }
        __syncthreads();
        float s = 0.f;
        #pragma unroll
        for (int c = 0; c < 8; c++) {
            const float4 kv = *(const float4*)&Kt[kk][half * 32 + c * 4];
            const float4 qv = *(const float4*)&qrow[half * 32 + c * 4];
            s += qv.x * kv.x + qv.y * kv.y + qv.z * kv.z + qv.w * kv.w;
        }
        red[t] = s;
        __syncthreads();
        if (t < 128) sc[kt * 128 + t] = (red[t] + red[t + 128]) * SCALEF;
        __syncthreads();
    }

    float m1 = -3.4e38f;
    #pragma unroll
    for (int i = 0; i < 8; i++) m1 = fmaxf(m1, sc[i * 256 + t]);
    red[t] = m1; __syncthreads();
    for (int s = 128; s > 0; s >>= 1) {
        if (t < s) red[t] = fmaxf(red[t], red[t + s]);
        __syncthreads();
    }
    const float mx = red[0];
    __syncthreads();
    float s1 = 0.f;
    #pragma unroll
    for (int i = 0; i < 8; i++) {
        float e = __expf(sc[i * 256 + t] - mx);
        sc[i * 256 + t] = e;
        s1 += e;
    }
    red[t] = s1; __syncthreads();
    for (int s = 128; s > 0; s >>= 1) {
        if (t < s) red[t] += red[t + s];
        __syncthreads();
    }
    const float inv = 1.0f / red[0];
    __syncthreads();

    const int d4 = (t & 15) * 4, ch = t >> 4;
    float4 acc = {0.f, 0.f, 0.f, 0.f};
    for (int i = 0; i < 128; i++) {
        int k = ch * 128 + i;
        const float4 v = *(const float4*)&V[((size_t)(bh * LL + k)) * DH + d4];
        const float p = sc[k];
        acc.x += p * v.x; acc.y += p * v.y; acc.z += p * v.z; acc.w += p * v.w;
    }
    __syncthreads();
    *(float4*)&sc[ch * 64 + d4] = acc;
    __syncthreads();
    if (t < 64) {
        float r = 0.f;
        #pragma unroll
        for (int c = 0; c < 16; c++) r += sc[c * 64 + t];
        const float v = r * inv;
        const size_t off = ((size_t)bh * LL + q) * DH + t;
        const ushort h = f32_to_bf16_rn(v);
        CH[off] = h;
        CL[off] = f32_to_bf16_rn(v - bf16_to_f32(h));
    }
}

// ---------------------------------------------------------------------------
extern "C" void kernel_launch(void* const* d_in, const int* in_sizes, int n_in,
                              void* d_out, int out_size, void* d_ws, size_t ws_size,
                              hipStream_t stream) {
    const float* x  = (const float*)d_in[0];
    const float* Wq = (const float*)d_in[1];
    const float* bq = (const float*)d_in[2];
    const float* Wk = (const float*)d_in[3];
    const float* bk = (const float*)d_in[4];
    const float* Wv = (const float*)d_in[5];
    const float* bv = (const float*)d_in[6];
    const float* Wo = (const float*)d_in[7];
    const float* bo = (const float*)d_in[8];
    float* out = (float*)d_out;

    float* ws = (float*)d_ws;
    const size_t QSZ = (size_t)BH * LL * DH;   // 4,194,304 elements
    float* Qp    = ws;
    float* Kp    = ws + QSZ;
    float* Vp    = ws + 2 * QSZ;
    float* Mp    = ws + 3 * QSZ;               // BH*L
    float* KMEAN = Mp + (size_t)BH * LL;
    float* VMEAN = KMEAN + BH * DH;
    int*   CAND  = (int*)(VMEAN + BH * DH);    // BH*NCAND
    int*   TIDX  = CAND + BH * NCAND;          // BH*KTOP
    float* EMP   = (float*)(TIDX + BH * KTOP); // BH*NCAND*8
    float* MEANP = EMP + (size_t)BH * NCAND * 8;  // 64*16*64
    ushort* WTH  = (ushort*)(ws + 3 * QSZ + 262144);   // 4 x 512x512 bf16 hi
    ushort* WTL  = WTH + (size_t)4 * DD * DD;
    ushort* XH   = WTL + (size_t)4 * DD * DD;          // x split hi
    ushort* XL   = XH + QSZ;
    ushort* CH   = XH;                                 // CTX aliases X
    ushort* CL   = XL;
    ushort* KH   = XL + QSZ;                           // K split hi
    const size_t WOFF = (size_t)DD * DD;

    split_wT<<<dim3(16, 16, 4), 256, 0, stream>>>(Wq, Wk, Wv, Wo, WTH, WTL);
    split_x<<<(int)(QSZ / 1024), 256, 0, stream>>>(x, XH, XL);

    const dim3 gemm_grid(DD / 64, (BB * LL) / 128);    // (8, 64)
    mfma_gemm<0, 1, 0><<<gemm_grid, 256, 0, stream>>>(XH, XL, WTH,            WTL,            bq, Qp, nullptr);
    mfma_gemm<0, 1, 1><<<gemm_grid, 256, 0, stream>>>(XH, XL, WTH + WOFF,     WTL + WOFF,     bk, Kp, KH);
    mfma_gemm<0, 1, 0><<<gemm_grid, 256, 0, stream>>>(XH, XL, WTH + 2 * WOFF, WTL + 2 * WOFF, bv, Vp, nullptr);

    mean_partial<<<dim3(BH, 2, 16), 256, 0, stream>>>(Kp, Vp, MEANP);
    mean_reduce<<<dim3(BH, 2), 64, 0, stream>>>(MEANP, KMEAN, VMEAN);

    mfma_stats<<<dim3(LL / 128, BH), 256, 0, stream>>>(Qp, KH, KMEAN, Mp);

    topk_kernel<<<BH, 256, 0, stream>>>(Mp, CAND, NCAND, NCAND);

    exact_partial<<<dim3(8, BH), 256, 0, stream>>>(Qp, Kp, CAND, EMP);

    select_kernel<<<BH, 64, 0, stream>>>(EMP, CAND, Qp, KMEAN, TIDX);

    fill_kernel<<<(int)(QSZ / 1024), 256, 0, stream>>>(VMEAN, CH, CL);

    sparse_kernel<<<dim3(KTOP, BH), 256, 0, stream>>>(Qp, Kp, Vp, TIDX, CH, CL);

    mfma_gemm<1, 0, 0><<<gemm_grid, 256, 0, stream>>>(CH, CL, WTH + 3 * WOFF, WTL + 3 * WOFF, bo, out, nullptr);
}

// Round 7
// 387.767 us; speedup vs baseline: 3.0782x; 1.1075x over previous
//
#include <hip/hip_runtime.h>

#define BB   4
#define LL   2048
#define DD   512
#define HH   8
#define DH   64
#define BH   32          // B*H
#define KTOP 38
#define NCAND 64         // approx-M candidate pool for exact refinement
#define SCALEF 0.125f    // 1/sqrt(64)

// sparse flash split-K params
#define NSP  16          // key chunks
#define CHK  128         // keys per chunk (LL/NSP)
#define QPAD 48          // queries padded to 3 m-tiles
#define SCS  132         // sc row stride (floats)
#define VST  66          // Vhl row stride (uints)

typedef __attribute__((ext_vector_type(8))) short bf16x8;
typedef __attribute__((ext_vector_type(8))) unsigned short ushort8;
typedef __attribute__((ext_vector_type(4))) float f32x4;

__device__ __forceinline__ ushort f32_to_bf16_rn(float x) {
    unsigned u = __float_as_uint(x);
    u += 0x7fffu + ((u >> 16) & 1u);
    return (ushort)(u >> 16);
}
__device__ __forceinline__ float bf16_to_f32(ushort h) {
    return __uint_as_float(((unsigned)h) << 16);
}
__device__ __forceinline__ unsigned int pack_hl(float x) {
    ushort h = f32_to_bf16_rn(x);
    ushort l = f32_to_bf16_rn(x - bf16_to_f32(h));
    return ((unsigned int)l << 16) | (unsigned int)h;
}

// ---------------------------------------------------------------------------
// Elementwise split: fp32 array -> bf16 hi + lo arrays (layout-preserving).
// ---------------------------------------------------------------------------
__global__ __launch_bounds__(256) void split_x(const float* __restrict__ X,
                                               ushort* __restrict__ XH,
                                               ushort* __restrict__ XL) {
    const size_t c = (size_t)blockIdx.x * 256 + threadIdx.x;
    const float4 v = *(const float4*)&X[c * 4];
    ushort4 h, l;
    h.x = f32_to_bf16_rn(v.x); l.x = f32_to_bf16_rn(v.x - bf16_to_f32(h.x));
    h.y = f32_to_bf16_rn(v.y); l.y = f32_to_bf16_rn(v.y - bf16_to_f32(h.y));
    h.z = f32_to_bf16_rn(v.z); l.z = f32_to_bf16_rn(v.z - bf16_to_f32(h.z));
    h.w = f32_to_bf16_rn(v.w); l.w = f32_to_bf16_rn(v.w - bf16_to_f32(h.w));
    *(ushort4*)&XH[c * 4] = h;
    *(ushort4*)&XL[c * 4] = l;
}

// ---------------------------------------------------------------------------
// Prep: transpose + split 4 weight matrices W[k][n] into WT_H/WT_L [n][k] bf16.
// ---------------------------------------------------------------------------
__global__ __launch_bounds__(256) void split_wT(const float* __restrict__ W0,
                                                const float* __restrict__ W1,
                                                const float* __restrict__ W2,
                                                const float* __restrict__ W3,
                                                ushort* __restrict__ WTH,
                                                ushort* __restrict__ WTL) {
    __shared__ float tile[32][33];
    const int z = blockIdx.z;
    const float* W = (z == 0) ? W0 : (z == 1) ? W1 : (z == 2) ? W2 : W3;
    ushort* oh = WTH + (size_t)z * DD * DD;
    ushort* ol = WTL + (size_t)z * DD * DD;
    const int n0 = blockIdx.x * 32, k0 = blockIdx.y * 32;
    const int t = threadIdx.x;
    const int r = t >> 5, c = t & 31;
    #pragma unroll
    for (int i = 0; i < 4; i++)
        tile[r + i * 8][c] = W[(size_t)(k0 + r + i * 8) * DD + n0 + c];
    __syncthreads();
    #pragma unroll
    for (int i = 0; i < 4; i++) {
        int row = r + i * 8;
        float v = tile[c][row];
        ushort h = f32_to_bf16_rn(v);
        oh[(size_t)(n0 + row) * DD + k0 + c] = h;
        ol[(size_t)(n0 + row) * DD + k0 + c] = f32_to_bf16_rn(v - bf16_to_f32(h));
    }
}

// ---------------------------------------------------------------------------
// Split-bf16 MFMA GEMM: A direct-from-global fragments, B LDS-staged.
// ---------------------------------------------------------------------------
template <int APERM, int YPERM, int WSPLIT>
__global__ __launch_bounds__(256) void mfma_gemm(const ushort* __restrict__ AH,
                                                 const ushort* __restrict__ AL,
                                                 const ushort* __restrict__ BTH,
                                                 const ushort* __restrict__ BTL,
                                                 const float* __restrict__ bias,
                                                 float* __restrict__ Y,
                                                 ushort* __restrict__ YH) {
    __shared__ ushort BHs[64 * 40];
    __shared__ ushort BLs[64 * 40];

    const int t = threadIdx.x;
    const int w = t >> 6, lane = t & 63;
    const int quad = lane >> 4, n16 = lane & 15;
    const int row0 = blockIdx.y * 128;
    const int n0   = blockIdx.x * 64;

    f32x4 acc[2][4] = {};

    size_t arow_off[2];
    #pragma unroll
    for (int mt = 0; mt < 2; mt++) {
        int R = row0 + w * 32 + mt * 16 + n16;
        if (APERM) {
            int b = R >> 11, l = R & 2047;
            arow_off[mt] = ((size_t)b * HH) * LL * DH + (size_t)l * DH;
        } else {
            arow_off[mt] = (size_t)R * DD;
        }
    }

    const int brow = t >> 2, bc8 = t & 3;

    for (int k0 = 0; k0 < DD; k0 += 32) {
        {
            const size_t goff = (size_t)(n0 + brow) * DD + k0 + bc8 * 8;
            const uint4 vh = *(const uint4*)&BTH[goff];
            const uint4 vl = *(const uint4*)&BTL[goff];
            *(uint4*)&BHs[brow * 40 + bc8 * 8] = vh;
            *(uint4*)&BLs[brow * 40 + bc8 * 8] = vl;
        }
        bf16x8 ah[2], al[2];
        #pragma unroll
        for (int mt = 0; mt < 2; mt++) {
            int k = k0 + quad * 8;
            size_t off;
            if (APERM) {
                int h = k >> 6, dh = k & 63;
                off = arow_off[mt] + (size_t)h * LL * DH + dh;
            } else {
                off = arow_off[mt] + k;
            }
            ah[mt] = *(const bf16x8*)&AH[off];
            al[mt] = *(const bf16x8*)&AL[off];
        }
        __syncthreads();

        bf16x8 bh[4], bl[4];
        #pragma unroll
        for (int nt = 0; nt < 4; nt++) {
            int off = (nt * 16 + n16) * 40 + quad * 8;
            bh[nt] = *(const bf16x8*)&BHs[off];
            bl[nt] = *(const bf16x8*)&BLs[off];
        }
        #pragma unroll
        for (int mt = 0; mt < 2; mt++)
            #pragma unroll
            for (int nt = 0; nt < 4; nt++) {
                acc[mt][nt] = __builtin_amdgcn_mfma_f32_16x16x32_bf16(ah[mt], bh[nt], acc[mt][nt], 0, 0, 0);
                acc[mt][nt] = __builtin_amdgcn_mfma_f32_16x16x32_bf16(ah[mt], bl[nt], acc[mt][nt], 0, 0, 0);
                acc[mt][nt] = __builtin_amdgcn_mfma_f32_16x16x32_bf16(al[mt], bh[nt], acc[mt][nt], 0, 0, 0);
            }
        __syncthreads();
    }

    #pragma unroll
    for (int mt = 0; mt < 2; mt++)
        #pragma unroll
        for (int nt = 0; nt < 4; nt++) {
            const int c = n0 + nt * 16 + n16;
            const float bv = bias[c];
            #pragma unroll
            for (int r = 0; r < 4; r++) {
                int m = w * 32 + mt * 16 + quad * 4 + r;
                int R = row0 + m;
                float v = acc[mt][nt][r] + bv;
                size_t off;
                if (YPERM) {
                    int b = R >> 11, l = R & 2047;
                    int h = c >> 6, dh = c & 63;
                    off = (((size_t)(b * HH + h)) * LL + l) * DH + dh;
                } else {
                    off = (size_t)R * DD + c;
                }
                Y[off] = v;
                if (WSPLIT) YH[off] = f32_to_bf16_rn(v);
            }
        }
}

// ---------------------------------------------------------------------------
// Mean phase 1: partial sums. grid (BH, 2, 16); block sums 128 rows.
// ---------------------------------------------------------------------------
__global__ __launch_bounds__(256) void mean_partial(const float* __restrict__ Kp,
                                                    const float* __restrict__ Vp,
                                                    float* __restrict__ partial) {
    __shared__ float red[256];
    const int bh = blockIdx.x;
    const int srcI = blockIdx.y;
    const int z  = blockIdx.z;
    const float* src = srcI ? Vp : Kp;
    const int t = threadIdx.x;
    const int d = t & 63, ch = t >> 6;
    const int l0 = z * 128 + ch * 32;
    float s = 0.f;
    for (int l = l0; l < l0 + 32; l++)
        s += src[((size_t)bh * LL + l) * DH + d];
    red[t] = s;
    __syncthreads();
    if (t < 64)
        partial[((size_t)((bh * 2 + srcI) * 16 + z)) * 64 + t] =
            red[t] + red[t + 64] + red[t + 128] + red[t + 192];
}

// ---------------------------------------------------------------------------
// Mean phase 2: fold 16 partials. grid (BH, 2), 64 thr.
// ---------------------------------------------------------------------------
__global__ __launch_bounds__(64) void mean_reduce(const float* __restrict__ partial,
                                                  float* __restrict__ Kmean,
                                                  float* __restrict__ Vmean) {
    const int bh = blockIdx.x;
    const int srcI = blockIdx.y;
    const int t  = threadIdx.x;
    float s = 0.f;
    #pragma unroll
    for (int z = 0; z < 16; z++)
        s += partial[((size_t)((bh * 2 + srcI) * 16 + z)) * 64 + t];
    float* dst = srcI ? Vmean : Kmean;
    dst[bh * DH + t] = s * (1.0f / LL);
}

// ---------------------------------------------------------------------------
// Approx M: 2-term MFMA (Qhi+Qlo)*Khi. (unchanged)
// ---------------------------------------------------------------------------
__global__ __launch_bounds__(256) void mfma_stats(const float* __restrict__ Qp,
                                                  const ushort* __restrict__ KH,
                                                  const float* __restrict__ Kmean,
                                                  float* __restrict__ M) {
    __shared__ ushort KS[128 * 72];
    __shared__ float  Km[64];
    __shared__ float  mdS[128];

    const int bh = blockIdx.y;
    const int q0 = blockIdx.x * 128;
    const int t    = threadIdx.x;
    const int w    = t >> 6;
    const int lane = t & 63;
    const int quad = lane >> 4;
    const int n16  = lane & 15;

    if (t < 64) Km[t] = Kmean[bh * DH + t];
    __syncthreads();
    if (t < 128) {
        const float4* qr = (const float4*)&Qp[((size_t)bh * LL + q0 + t) * DH];
        const float4* km4 = (const float4*)Km;
        float md = 0.f;
        #pragma unroll
        for (int i = 0; i < 16; i++) {
            float4 a = qr[i], b = km4[i];
            md += a.x * b.x + a.y * b.y + a.z * b.z + a.w * b.w;
        }
        mdS[t] = md;
    }

    bf16x8 aH[2][2], aL[2][2];
    #pragma unroll
    for (int mt = 0; mt < 2; mt++) {
        const float* qrp = &Qp[((size_t)bh * LL + q0 + w * 32 + mt * 16 + n16) * DH + quad * 8];
        float v[16];
        *(float4*)&v[0]  = *(const float4*)(qrp);
        *(float4*)&v[4]  = *(const float4*)(qrp + 4);
        *(float4*)&v[8]  = *(const float4*)(qrp + 32);
        *(float4*)&v[12] = *(const float4*)(qrp + 36);
        #pragma unroll
        for (int j = 0; j < 8; j++) {
            ushort h0 = f32_to_bf16_rn(v[j]);
            aH[mt][0][j] = (short)h0;
            aL[mt][0][j] = (short)f32_to_bf16_rn(v[j] - bf16_to_f32(h0));
            ushort h1 = f32_to_bf16_rn(v[8 + j]);
            aH[mt][1][j] = (short)h1;
            aL[mt][1][j] = (short)f32_to_bf16_rn(v[8 + j] - bf16_to_f32(h1));
        }
    }

    f32x4 maxv[2] = {{-3.4e38f, -3.4e38f, -3.4e38f, -3.4e38f},
                     {-3.4e38f, -3.4e38f, -3.4e38f, -3.4e38f}};

    for (int kt0 = 0; kt0 < LL; kt0 += 128) {
        __syncthreads();
        #pragma unroll
        for (int i = 0; i < 4; i++) {
            int f = i * 256 + t;
            int row = f >> 3, c8 = f & 7;
            const uint4 v = *(const uint4*)&KH[((size_t)(bh * LL + kt0 + row)) * DH + c8 * 8];
            *(uint4*)&KS[row * 72 + c8 * 8] = v;
        }
        __syncthreads();

        for (int ktl = 0; ktl < 128; ktl += 16) {
            const ushort* bp = &KS[(size_t)(ktl + n16) * 72 + quad * 8];
            bf16x8 bH0 = *(const bf16x8*)(bp);
            bf16x8 bH1 = *(const bf16x8*)(bp + 32);
            #pragma unroll
            for (int mt = 0; mt < 2; mt++) {
                f32x4 acc = {0.f, 0.f, 0.f, 0.f};
                acc = __builtin_amdgcn_mfma_f32_16x16x32_bf16(aH[mt][0], bH0, acc, 0, 0, 0);
                acc = __builtin_amdgcn_mfma_f32_16x16x32_bf16(aH[mt][1], bH1, acc, 0, 0, 0);
                acc = __builtin_amdgcn_mfma_f32_16x16x32_bf16(aL[mt][0], bH0, acc, 0, 0, 0);
                acc = __builtin_amdgcn_mfma_f32_16x16x32_bf16(aL[mt][1], bH1, acc, 0, 0, 0);
                maxv[mt][0] = fmaxf(maxv[mt][0], acc[0]);
                maxv[mt][1] = fmaxf(maxv[mt][1], acc[1]);
                maxv[mt][2] = fmaxf(maxv[mt][2], acc[2]);
                maxv[mt][3] = fmaxf(maxv[mt][3], acc[3]);
            }
        }
    }

    #pragma unroll
    for (int off = 1; off < 16; off <<= 1)
        #pragma unroll
        for (int mt = 0; mt < 2; mt++)
            #pragma unroll
            for (int r = 0; r < 4; r++)
                maxv[mt][r] = fmaxf(maxv[mt][r], __shfl_xor(maxv[mt][r], off));

    if (n16 == 0) {
        #pragma unroll
        for (int mt = 0; mt < 2; mt++)
            #pragma unroll
            for (int r = 0; r < 4; r++) {
                int lq = w * 32 + mt * 16 + quad * 4 + r;
                M[(size_t)bh * LL + q0 + lq] = SCALEF * maxv[mt][r] - SCALEF * mdS[lq];
            }
    }
}

// ---------------------------------------------------------------------------
// Top-k: values in registers (8/thread), shuffle argmax. (unchanged)
// ---------------------------------------------------------------------------
__global__ __launch_bounds__(256) void topk_kernel(const float* __restrict__ M,
                                                   int* __restrict__ out_idx,
                                                   int kcount, int ostride) {
    __shared__ float wv[4];
    __shared__ int   wi[4];
    const int bh = blockIdx.x;
    const int t  = threadIdx.x;
    const int w  = t >> 6;
    float v[8];
    #pragma unroll
    for (int i = 0; i < 8; i++) v[i] = M[(size_t)bh * LL + i * 256 + t];

    for (int it = 0; it < kcount; it++) {
        float bv = v[0]; int bi = 0;
        #pragma unroll
        for (int i = 1; i < 8; i++)
            if (v[i] > bv) { bv = v[i]; bi = i; }
        int bidx = bi * 256 + t;
        #pragma unroll
        for (int off = 1; off < 64; off <<= 1) {
            float ov = __shfl_xor(bv, off);
            int   oi = __shfl_xor(bidx, off);
            if (ov > bv || (ov == bv && oi < bidx)) { bv = ov; bidx = oi; }
        }
        if ((t & 63) == 0) { wv[w] = bv; wi[w] = bidx; }
        __syncthreads();
        float fv = wv[0]; int fi = wi[0];
        #pragma unroll
        for (int j = 1; j < 4; j++)
            if (wv[j] > fv || (wv[j] == fv && wi[j] < fi)) { fv = wv[j]; fi = wi[j]; }
        if (t == 0) out_idx[bh * ostride + it] = fi;
        if ((fi & 255) == t) v[fi >> 8] = -3.4e38f;
        __syncthreads();
    }
}

// ---------------------------------------------------------------------------
// Exact refinement phase 1: per-chunk fp32 max-dot for all 64 candidates.
// ---------------------------------------------------------------------------
__global__ __launch_bounds__(256) void exact_partial(const float* __restrict__ Qp,
                                                     const float* __restrict__ Kp,
                                                     const int* __restrict__ CAND,
                                                     float* __restrict__ EMP) {
    __shared__ float Qs[64][65];
    __shared__ float Ks[64][65];
    __shared__ int   cidx[64];
    const int bh = blockIdx.y;
    const int chunk = blockIdx.x;
    const int t = threadIdx.x;
    const int tx = t & 15, ty = t >> 4;

    if (t < 64) cidx[t] = CAND[bh * NCAND + t];
    __syncthreads();
    #pragma unroll
    for (int i = 0; i < 4; i++) {
        int f = i * 256 + t;
        int row = f >> 4, c4 = f & 15;
        const float4 v = *(const float4*)&Qp[((size_t)bh * LL + cidx[row]) * DH + c4 * 4];
        *(float4*)&Qs[row][c4 * 4] = v;
    }

    float mx[4] = {-3.4e38f, -3.4e38f, -3.4e38f, -3.4e38f};

    for (int kt = 0; kt < 4; kt++) {
        __syncthreads();
        #pragma unroll
        for (int i = 0; i < 4; i++) {
            int f = i * 256 + t;
            int row = f >> 4, c4 = f & 15;
            const float4 v = *(const float4*)&Kp[((size_t)(bh * LL + chunk * 256 + kt * 64 + row)) * DH + c4 * 4];
            *(float4*)&Ks[row][c4 * 4] = v;
        }
        __syncthreads();
        float acc[4][4] = {};
        #pragma unroll 8
        for (int dd = 0; dd < 64; dd++) {
            float a[4], b[4];
            #pragma unroll
            for (int i = 0; i < 4; i++) a[i] = Qs[ty * 4 + i][dd];
            #pragma unroll
            for (int j = 0; j < 4; j++) b[j] = Ks[tx * 4 + j][dd];
            #pragma unroll
            for (int i = 0; i < 4; i++)
                #pragma unroll
                for (int j = 0; j < 4; j++) acc[i][j] += a[i] * b[j];
        }
        #pragma unroll
        for (int i = 0; i < 4; i++)
            #pragma unroll
            for (int j = 0; j < 4; j++) mx[i] = fmaxf(mx[i], acc[i][j]);
    }

    #pragma unroll
    for (int off = 1; off < 16; off <<= 1)
        #pragma unroll
        for (int i = 0; i < 4; i++)
            mx[i] = fmaxf(mx[i], __shfl_xor(mx[i], off));

    if (tx == 0) {
        #pragma unroll
        for (int i = 0; i < 4; i++)
            EMP[((size_t)bh * NCAND + ty * 4 + i) * 8 + chunk] = mx[i];
    }
}

// ---------------------------------------------------------------------------
// Exact refinement phase 2 + final top-38. (unchanged)
// ---------------------------------------------------------------------------
__global__ __launch_bounds__(64) void select_kernel(const float* __restrict__ EMP,
                                                    const int* __restrict__ CAND,
                                                    const float* __restrict__ Qp,
                                                    const float* __restrict__ Kmean,
                                                    int* __restrict__ TIDX) {
    __shared__ float Km[64];
    const int bh = blockIdx.x;
    const int t  = threadIdx.x;
    Km[t] = Kmean[bh * DH + t];
    __syncthreads();

    const int qi = CAND[bh * NCAND + t];
    float mx = -3.4e38f;
    #pragma unroll
    for (int c = 0; c < 8; c++) mx = fmaxf(mx, EMP[((size_t)bh * NCAND + t) * 8 + c]);

    const float4* qr = (const float4*)&Qp[((size_t)bh * LL + qi) * DH];
    const float4* km4 = (const float4*)Km;
    float md = 0.f;
    #pragma unroll
    for (int i = 0; i < 16; i++) {
        float4 a = qr[i], b = km4[i];
        md += a.x * b.x + a.y * b.y + a.z * b.z + a.w * b.w;
    }
    float v = SCALEF * mx - SCALEF * md;

    for (int it = 0; it < KTOP; it++) {
        float bv = v; int bq = qi;
        #pragma unroll
        for (int off = 1; off < 64; off <<= 1) {
            float ov = __shfl_xor(bv, off);
            int   oq = __shfl_xor(bq, off);
            if (ov > bv || (ov == bv && oq < bq)) { bv = ov; bq = oq; }
        }
        if (t == 0) TIDX[bh * KTOP + it] = bq;
        if (qi == bq) v = -3.4e38f;
    }
}

// ---------------------------------------------------------------------------
// Fill context (bf16 hi/lo) with per-head V mean. (unchanged)
// ---------------------------------------------------------------------------
__global__ __launch_bounds__(256) void fill_kernel(const float* __restrict__ Vmean,
                                                   ushort* __restrict__ CH,
                                                   ushort* __restrict__ CL) {
    const size_t c = (size_t)blockIdx.x * 256 + threadIdx.x;
    const int d4 = (int)(c & 15) * 4;
    const int bh = (int)(c >> 15);
    const float4 v = *(const float4*)&Vmean[bh * DH + d4];
    ushort4 h, l;
    h.x = f32_to_bf16_rn(v.x); l.x = f32_to_bf16_rn(v.x - bf16_to_f32(h.x));
    h.y = f32_to_bf16_rn(v.y); l.y = f32_to_bf16_rn(v.y - bf16_to_f32(h.y));
    h.z = f32_to_bf16_rn(v.z); l.z = f32_to_bf16_rn(v.z - bf16_to_f32(h.z));
    h.w = f32_to_bf16_rn(v.w); l.w = f32_to_bf16_rn(v.w - bf16_to_f32(h.w));
    *(ushort4*)&CH[c * 4] = h;
    *(ushort4*)&CL[c * 4] = l;
}

// ---------------------------------------------------------------------------
// Sparse attention V3, phase 1: flash split-K MFMA partials.
// Grid (NSP chunks x BH). 48-padded query tile x 128 keys per block.
// Scores: 2-term split-bf16 MFMA (A=Q hi/lo global gather, B=KH global
// gather). Chunk-local softmax (m,l partials). PV: 3-term MFMA, V staged
// once as packed bf16 hi|lo uints (stride-66 rows = conflict-free frags).
// ---------------------------------------------------------------------------
__global__ __launch_bounds__(256) void sparse_partial(const float* __restrict__ Qp,
                                                      const ushort* __restrict__ KH,
                                                      const float* __restrict__ Vp,
                                                      const int* __restrict__ TIDX,
                                                      float* __restrict__ OPART,
                                                      float* __restrict__ MPART,
                                                      float* __restrict__ LPART) {
    __shared__ float sc[QPAD * SCS];            // 48*132*4 = 25.3 KB
    __shared__ unsigned int Vhl[CHK * VST];     // 128*66*4 = 33.8 KB
    const int bh = blockIdx.y;
    const int ck = blockIdx.x;
    const int k0 = ck * CHK;
    const int t = threadIdx.x;
    const int w = t >> 6, lane = t & 63;
    const int quad = lane >> 4, n16 = lane & 15;
    const int mt = w;

    // ---- stage V: fp32 -> packed (lo<<16 | hi) bf16 uints ----
    #pragma unroll
    for (int i = 0; i < 8; i++) {
        int e = i * 256 + t;
        int key = e >> 4, c4 = e & 15;
        const float4 v = *(const float4*)&Vp[((size_t)(bh * LL + k0 + key)) * DH + c4 * 4];
        uint4 p;
        p.x = pack_hl(v.x); p.y = pack_hl(v.y);
        p.z = pack_hl(v.z); p.w = pack_hl(v.w);
        *(uint4*)&Vhl[key * VST + c4 * 4] = p;
    }

    // ---- scores (waves 0..2, wave = m-tile) ----
    if (mt < 3) {
        bf16x8 aH[2], aL[2];
        {
            int q = mt * 16 + n16;
            int qq = q < KTOP ? q : (KTOP - 1);
            const float* qp = &Qp[((size_t)bh * LL + TIDX[bh * KTOP + qq]) * DH];
            #pragma unroll
            for (int kf = 0; kf < 2; kf++) {
                float v[8];
                *(float4*)&v[0] = *(const float4*)(qp + kf * 32 + quad * 8);
                *(float4*)&v[4] = *(const float4*)(qp + kf * 32 + quad * 8 + 4);
                #pragma unroll
                for (int j = 0; j < 8; j++) {
                    ushort h = f32_to_bf16_rn(v[j]);
                    aH[kf][j] = (short)h;
                    aL[kf][j] = (short)f32_to_bf16_rn(v[j] - bf16_to_f32(h));
                }
            }
        }
        #pragma unroll
        for (int nt = 0; nt < 8; nt++) {
            f32x4 acc = {0.f, 0.f, 0.f, 0.f};
            #pragma unroll
            for (int kf = 0; kf < 2; kf++) {
                bf16x8 b = *(const bf16x8*)&KH[((size_t)(bh * LL + k0 + nt * 16 + n16)) * DH + kf * 32 + quad * 8];
                acc = __builtin_amdgcn_mfma_f32_16x16x32_bf16(aH[kf], b, acc, 0, 0, 0);
                acc = __builtin_amdgcn_mfma_f32_16x16x32_bf16(aL[kf], b, acc, 0, 0, 0);
            }
            #pragma unroll
            for (int r = 0; r < 4; r++)
                sc[(mt * 16 + quad * 4 + r) * SCS + nt * 16 + n16] = acc[r];
        }
    }
    __syncthreads();

    // ---- chunk-local softmax partials (rows 0..37, wave-strided) ----
    for (int row = w; row < KTOP; row += 4) {
        float v0 = sc[row * SCS + lane];
        float v1 = sc[row * SCS + 64 + lane];
        float m = fmaxf(v0, v1);
        #pragma unroll
        for (int off = 1; off < 64; off <<= 1)
            m = fmaxf(m, __shfl_xor(m, off));
        const float ms = m * SCALEF;
        float e0 = __expf(v0 * SCALEF - ms);
        float e1 = __expf(v1 * SCALEF - ms);
        float l = e0 + e1;
        #pragma unroll
        for (int off = 1; off < 64; off <<= 1)
            l += __shfl_xor(l, off);
        sc[row * SCS + lane]      = e0;
        sc[row * SCS + 64 + lane] = e1;
        if (lane == 0) {
            MPART[((size_t)ck * BH + bh) * KTOP + row] = ms;
            LPART[((size_t)ck * BH + bh) * KTOP + row] = l;
        }
    }
    __syncthreads();

    // ---- PV: 3-term MFMA (waves 0..2) ----
    if (mt < 3) {
        f32x4 acc[4] = {};
        #pragma unroll
        for (int kf = 0; kf < 4; kf++) {       // 4 x 32-key steps
            bf16x8 ph, pl;
            {
                const float* pp = &sc[(mt * 16 + n16) * SCS + kf * 32 + quad * 8];
                float v[8];
                *(float4*)&v[0] = *(const float4*)(pp);
                *(float4*)&v[4] = *(const float4*)(pp + 4);
                #pragma unroll
                for (int j = 0; j < 8; j++) {
                    ushort h = f32_to_bf16_rn(v[j]);
                    ph[j] = (short)h;
                    pl[j] = (short)f32_to_bf16_rn(v[j] - bf16_to_f32(h));
                }
            }
            #pragma unroll
            for (int nt = 0; nt < 4; nt++) {
                unsigned int u[8];
                #pragma unroll
                for (int j = 0; j < 8; j++)
                    u[j] = Vhl[(kf * 32 + quad * 8 + j) * VST + nt * 16 + n16];
                bf16x8 vh, vl;
                #pragma unroll
                for (int j = 0; j < 8; j++) {
                    vh[j] = (short)(u[j] & 0xffffu);
                    vl[j] = (short)(u[j] >> 16);
                }
                acc[nt] = __builtin_amdgcn_mfma_f32_16x16x32_bf16(ph, vh, acc[nt], 0, 0, 0);
                acc[nt] = __builtin_amdgcn_mfma_f32_16x16x32_bf16(ph, vl, acc[nt], 0, 0, 0);
                acc[nt] = __builtin_amdgcn_mfma_f32_16x16x32_bf16(pl, vh, acc[nt], 0, 0, 0);
            }
        }
        #pragma unroll
        for (int nt = 0; nt < 4; nt++)
            #pragma unroll
            for (int r = 0; r < 4; r++) {
                int q = mt * 16 + quad * 4 + r;
                if (q < KTOP)
                    OPART[(((size_t)ck * BH + bh) * KTOP + q) * DH + nt * 16 + n16] = acc[nt][r];
            }
    }
}

// ---------------------------------------------------------------------------
// Sparse attention V3, phase 2: split-K softmax merge -> CH/CL rows.
// ---------------------------------------------------------------------------
__global__ __launch_bounds__(256) void sparse_combine(const float* __restrict__ OPART,
                                                      const float* __restrict__ MPART,
                                                      const float* __restrict__ LPART,
                                                      const int* __restrict__ TIDX,
                                                      ushort* __restrict__ CH,
                                                      ushort* __restrict__ CL) {
    __shared__ float wts[NSP][KTOP];
    __shared__ float inv[KTOP];
    __shared__ int   tq[KTOP];
    const int bh = blockIdx.x;
    const int t  = threadIdx.x;
    if (t < KTOP) {
        float m[NSP];
        float mx = -3.4e38f;
        #pragma unroll
        for (int c = 0; c < NSP; c++) {
            m[c] = MPART[((size_t)c * BH + bh) * KTOP + t];
            mx = fmaxf(mx, m[c]);
        }
        float L = 0.f;
        #pragma unroll
        for (int c = 0; c < NSP; c++) {
            float wc = __expf(m[c] - mx);
            wts[c][t] = wc;
            L += wc * LPART[((size_t)c * BH + bh) * KTOP + t];
        }
        inv[t] = 1.0f / L;
        tq[t] = TIDX[bh * KTOP + t];
    }
    __syncthreads();
    for (int i = 0; i < 10; i++) {
        int idx = i * 256 + t;
        if (idx >= KTOP * DH) break;
        int q = idx >> 6, d = idx & 63;
        float o = 0.f;
        #pragma unroll
        for (int c = 0; c < NSP; c++)
            o += wts[c][q] * OPART[(((size_t)c * BH + bh) * KTOP + q) * DH + d];
        float val = o * inv[q];
        size_t off = ((size_t)bh * LL + tq[q]) * DH + d;
        ushort h = f32_to_bf16_rn(val);
        CH[off] = h;
        CL[off] = f32_to_bf16_rn(val - bf16_to_f32(h));
    }
}

// ---------------------------------------------------------------------------
extern "C" void kernel_launch(void* const* d_in, const int* in_sizes, int n_in,
                              void* d_out, int out_size, void* d_ws, size_t ws_size,
                              hipStream_t stream) {
    const float* x  = (const float*)d_in[0];
    const float* Wq = (const float*)d_in[1];
    const float* bq = (const float*)d_in[2];
    const float* Wk = (const float*)d_in[3];
    const float* bk = (const float*)d_in[4];
    const float* Wv = (const float*)d_in[5];
    const float* bv = (const float*)d_in[6];
    const float* Wo = (const float*)d_in[7];
    const float* bo = (const float*)d_in[8];
    float* out = (float*)d_out;

    float* ws = (float*)d_ws;
    const size_t QSZ = (size_t)BH * LL * DH;   // 4,194,304 elements
    float* Qp    = ws;
    float* Kp    = ws + QSZ;
    float* Vp    = ws + 2 * QSZ;
    float* Mp    = ws + 3 * QSZ;               // BH*L
    float* KMEAN = Mp + (size_t)BH * LL;
    float* VMEAN = KMEAN + BH * DH;
    int*   CAND  = (int*)(VMEAN + BH * DH);    // BH*NCAND
    int*   TIDX  = CAND + BH * NCAND;          // BH*KTOP
    float* EMP   = (float*)(TIDX + BH * KTOP); // BH*NCAND*8
    float* MEANP = EMP + (size_t)BH * NCAND * 8;  // 64*16*64
    ushort* WTH  = (ushort*)(ws + 3 * QSZ + 262144);   // 4 x 512x512 bf16 hi
    ushort* WTL  = WTH + (size_t)4 * DD * DD;
    ushort* XH   = WTL + (size_t)4 * DD * DD;          // x split hi
    ushort* XL   = XH + QSZ;
    ushort* CH   = XH;                                 // CTX aliases X
    ushort* CL   = XL;
    ushort* KH   = XL + QSZ;                           // K split hi
    float* OPART = (float*)(KH + QSZ);                 // NSP*BH*KTOP*DH
    float* MPART = OPART + (size_t)NSP * BH * KTOP * DH;
    float* LPART = MPART + (size_t)NSP * BH * KTOP;
    const size_t WOFF = (size_t)DD * DD;

    split_wT<<<dim3(16, 16, 4), 256, 0, stream>>>(Wq, Wk, Wv, Wo, WTH, WTL);
    split_x<<<(int)(QSZ / 1024), 256, 0, stream>>>(x, XH, XL);

    const dim3 gemm_grid(DD / 64, (BB * LL) / 128);    // (8, 64)
    mfma_gemm<0, 1, 0><<<gemm_grid, 256, 0, stream>>>(XH, XL, WTH,            WTL,            bq, Qp, nullptr);
    mfma_gemm<0, 1, 1><<<gemm_grid, 256, 0, stream>>>(XH, XL, WTH + WOFF,     WTL + WOFF,     bk, Kp, KH);
    mfma_gemm<0, 1, 0><<<gemm_grid, 256, 0, stream>>>(XH, XL, WTH + 2 * WOFF, WTL + 2 * WOFF, bv, Vp, nullptr);

    mean_partial<<<dim3(BH, 2, 16), 256, 0, stream>>>(Kp, Vp, MEANP);
    mean_reduce<<<dim3(BH, 2), 64, 0, stream>>>(MEANP, KMEAN, VMEAN);

    mfma_stats<<<dim3(LL / 128, BH), 256, 0, stream>>>(Qp, KH, KMEAN, Mp);

    topk_kernel<<<BH, 256, 0, stream>>>(Mp, CAND, NCAND, NCAND);

    exact_partial<<<dim3(8, BH), 256, 0, stream>>>(Qp, Kp, CAND, EMP);

    select_kernel<<<BH, 64, 0, stream>>>(EMP, CAND, Qp, KMEAN, TIDX);

    fill_kernel<<<(int)(QSZ / 1024), 256, 0, stream>>>(VMEAN, CH, CL);

    sparse_partial<<<dim3(NSP, BH), 256, 0, stream>>>(Qp, KH, Vp, TIDX, OPART, MPART, LPART);
    sparse_combine<<<BH, 256, 0, stream>>>(OPART, MPART, LPART, TIDX, CH, CL);

    mfma_gemm<1, 0, 0><<<gemm_grid, 256, 0, stream>>>(CH, CL, WTH + 3 * WOFF, WTL + 3 * WOFF, bo, out, nullptr);
}

// Round 8
// 335.448 us; speedup vs baseline: 3.5582x; 1.1560x over previous
//
#include <hip/hip_runtime.h>

#define BB   4
#define LL   2048
#define DD   512
#define HH   8
#define DH   64
#define BH   32          // B*H
#define KTOP 38
#define NCAND 64         // approx-M candidate pool for exact refinement
#define SCALEF 0.125f    // 1/sqrt(64)

// sparse flash split-K params
#define NSP  16          // key chunks
#define CHK  128         // keys per chunk (LL/NSP)
#define QPAD 48          // queries padded to 3 m-tiles
#define SCS  132         // sc row stride (floats)
#define VST  66          // Vhl row stride (uints)

typedef __attribute__((ext_vector_type(8))) short bf16x8;
typedef __attribute__((ext_vector_type(8))) unsigned short ushort8;
typedef __attribute__((ext_vector_type(4))) float f32x4;

__device__ __forceinline__ ushort f32_to_bf16_rn(float x) {
    unsigned u = __float_as_uint(x);
    u += 0x7fffu + ((u >> 16) & 1u);
    return (ushort)(u >> 16);
}
__device__ __forceinline__ float bf16_to_f32(ushort h) {
    return __uint_as_float(((unsigned)h) << 16);
}
__device__ __forceinline__ unsigned int pack_hl(float x) {
    ushort h = f32_to_bf16_rn(x);
    ushort l = f32_to_bf16_rn(x - bf16_to_f32(h));
    return ((unsigned int)l << 16) | (unsigned int)h;
}

// ---------------------------------------------------------------------------
// Elementwise split: fp32 array -> bf16 hi + lo arrays (layout-preserving).
// ---------------------------------------------------------------------------
__global__ __launch_bounds__(256) void split_x(const float* __restrict__ X,
                                               ushort* __restrict__ XH,
                                               ushort* __restrict__ XL) {
    const size_t c = (size_t)blockIdx.x * 256 + threadIdx.x;
    const float4 v = *(const float4*)&X[c * 4];
    ushort4 h, l;
    h.x = f32_to_bf16_rn(v.x); l.x = f32_to_bf16_rn(v.x - bf16_to_f32(h.x));
    h.y = f32_to_bf16_rn(v.y); l.y = f32_to_bf16_rn(v.y - bf16_to_f32(h.y));
    h.z = f32_to_bf16_rn(v.z); l.z = f32_to_bf16_rn(v.z - bf16_to_f32(h.z));
    h.w = f32_to_bf16_rn(v.w); l.w = f32_to_bf16_rn(v.w - bf16_to_f32(h.w));
    *(ushort4*)&XH[c * 4] = h;
    *(ushort4*)&XL[c * 4] = l;
}

// ---------------------------------------------------------------------------
// Prep: transpose + split 4 weight matrices W[k][n] into WT_H/WT_L [n][k] bf16.
// ---------------------------------------------------------------------------
__global__ __launch_bounds__(256) void split_wT(const float* __restrict__ W0,
                                                const float* __restrict__ W1,
                                                const float* __restrict__ W2,
                                                const float* __restrict__ W3,
                                                ushort* __restrict__ WTH,
                                                ushort* __restrict__ WTL) {
    __shared__ float tile[32][33];
    const int z = blockIdx.z;
    const float* W = (z == 0) ? W0 : (z == 1) ? W1 : (z == 2) ? W2 : W3;
    ushort* oh = WTH + (size_t)z * DD * DD;
    ushort* ol = WTL + (size_t)z * DD * DD;
    const int n0 = blockIdx.x * 32, k0 = blockIdx.y * 32;
    const int t = threadIdx.x;
    const int r = t >> 5, c = t & 31;
    #pragma unroll
    for (int i = 0; i < 4; i++)
        tile[r + i * 8][c] = W[(size_t)(k0 + r + i * 8) * DD + n0 + c];
    __syncthreads();
    #pragma unroll
    for (int i = 0; i < 4; i++) {
        int row = r + i * 8;
        float v = tile[c][row];
        ushort h = f32_to_bf16_rn(v);
        oh[(size_t)(n0 + row) * DD + k0 + c] = h;
        ol[(size_t)(n0 + row) * DD + k0 + c] = f32_to_bf16_rn(v - bf16_to_f32(h));
    }
}

// ---------------------------------------------------------------------------
// Split-bf16 MFMA GEMM: A direct-from-global fragments, B LDS-staged.
// ---------------------------------------------------------------------------
template <int APERM, int YPERM, int WSPLIT>
__global__ __launch_bounds__(256) void mfma_gemm(const ushort* __restrict__ AH,
                                                 const ushort* __restrict__ AL,
                                                 const ushort* __restrict__ BTH,
                                                 const ushort* __restrict__ BTL,
                                                 const float* __restrict__ bias,
                                                 float* __restrict__ Y,
                                                 ushort* __restrict__ YH) {
    __shared__ ushort BHs[64 * 40];
    __shared__ ushort BLs[64 * 40];

    const int t = threadIdx.x;
    const int w = t >> 6, lane = t & 63;
    const int quad = lane >> 4, n16 = lane & 15;
    const int row0 = blockIdx.y * 128;
    const int n0   = blockIdx.x * 64;

    f32x4 acc[2][4] = {};

    size_t arow_off[2];
    #pragma unroll
    for (int mt = 0; mt < 2; mt++) {
        int R = row0 + w * 32 + mt * 16 + n16;
        if (APERM) {
            int b = R >> 11, l = R & 2047;
            arow_off[mt] = ((size_t)b * HH) * LL * DH + (size_t)l * DH;
        } else {
            arow_off[mt] = (size_t)R * DD;
        }
    }

    const int brow = t >> 2, bc8 = t & 3;

    for (int k0 = 0; k0 < DD; k0 += 32) {
        {
            const size_t goff = (size_t)(n0 + brow) * DD + k0 + bc8 * 8;
            const uint4 vh = *(const uint4*)&BTH[goff];
            const uint4 vl = *(const uint4*)&BTL[goff];
            *(uint4*)&BHs[brow * 40 + bc8 * 8] = vh;
            *(uint4*)&BLs[brow * 40 + bc8 * 8] = vl;
        }
        bf16x8 ah[2], al[2];
        #pragma unroll
        for (int mt = 0; mt < 2; mt++) {
            int k = k0 + quad * 8;
            size_t off;
            if (APERM) {
                int h = k >> 6, dh = k & 63;
                off = arow_off[mt] + (size_t)h * LL * DH + dh;
            } else {
                off = arow_off[mt] + k;
            }
            ah[mt] = *(const bf16x8*)&AH[off];
            al[mt] = *(const bf16x8*)&AL[off];
        }
        __syncthreads();

        bf16x8 bh[4], bl[4];
        #pragma unroll
        for (int nt = 0; nt < 4; nt++) {
            int off = (nt * 16 + n16) * 40 + quad * 8;
            bh[nt] = *(const bf16x8*)&BHs[off];
            bl[nt] = *(const bf16x8*)&BLs[off];
        }
        #pragma unroll
        for (int mt = 0; mt < 2; mt++)
            #pragma unroll
            for (int nt = 0; nt < 4; nt++) {
                acc[mt][nt] = __builtin_amdgcn_mfma_f32_16x16x32_bf16(ah[mt], bh[nt], acc[mt][nt], 0, 0, 0);
                acc[mt][nt] = __builtin_amdgcn_mfma_f32_16x16x32_bf16(ah[mt], bl[nt], acc[mt][nt], 0, 0, 0);
                acc[mt][nt] = __builtin_amdgcn_mfma_f32_16x16x32_bf16(al[mt], bh[nt], acc[mt][nt], 0, 0, 0);
            }
        __syncthreads();
    }

    #pragma unroll
    for (int mt = 0; mt < 2; mt++)
        #pragma unroll
        for (int nt = 0; nt < 4; nt++) {
            const int c = n0 + nt * 16 + n16;
            const float bv = bias[c];
            #pragma unroll
            for (int r = 0; r < 4; r++) {
                int m = w * 32 + mt * 16 + quad * 4 + r;
                int R = row0 + m;
                float v = acc[mt][nt][r] + bv;
                size_t off;
                if (YPERM) {
                    int b = R >> 11, l = R & 2047;
                    int h = c >> 6, dh = c & 63;
                    off = (((size_t)(b * HH + h)) * LL + l) * DH + dh;
                } else {
                    off = (size_t)R * DD + c;
                }
                Y[off] = v;
                if (WSPLIT) YH[off] = f32_to_bf16_rn(v);
            }
        }
}

// ---------------------------------------------------------------------------
// Mean phase 1: partial sums. grid (BH, 2, 16); block sums 128 rows.
// ---------------------------------------------------------------------------
__global__ __launch_bounds__(256) void mean_partial(const float* __restrict__ Kp,
                                                    const float* __restrict__ Vp,
                                                    float* __restrict__ partial) {
    __shared__ float red[256];
    const int bh = blockIdx.x;
    const int srcI = blockIdx.y;
    const int z  = blockIdx.z;
    const float* src = srcI ? Vp : Kp;
    const int t = threadIdx.x;
    const int d = t & 63, ch = t >> 6;
    const int l0 = z * 128 + ch * 32;
    float s = 0.f;
    for (int l = l0; l < l0 + 32; l++)
        s += src[((size_t)bh * LL + l) * DH + d];
    red[t] = s;
    __syncthreads();
    if (t < 64)
        partial[((size_t)((bh * 2 + srcI) * 16 + z)) * 64 + t] =
            red[t] + red[t + 64] + red[t + 128] + red[t + 192];
}

// ---------------------------------------------------------------------------
// Mean phase 2: fold 16 partials. grid (BH, 2), 64 thr.
// ---------------------------------------------------------------------------
__global__ __launch_bounds__(64) void mean_reduce(const float* __restrict__ partial,
                                                  float* __restrict__ Kmean,
                                                  float* __restrict__ Vmean) {
    const int bh = blockIdx.x;
    const int srcI = blockIdx.y;
    const int t  = threadIdx.x;
    float s = 0.f;
    #pragma unroll
    for (int z = 0; z < 16; z++)
        s += partial[((size_t)((bh * 2 + srcI) * 16 + z)) * 64 + t];
    float* dst = srcI ? Vmean : Kmean;
    dst[bh * DH + t] = s * (1.0f / LL);
}

// ---------------------------------------------------------------------------
// Approx M: 2-term MFMA (Qhi+Qlo)*Khi. (unchanged)
// ---------------------------------------------------------------------------
__global__ __launch_bounds__(256) void mfma_stats(const float* __restrict__ Qp,
                                                  const ushort* __restrict__ KH,
                                                  const float* __restrict__ Kmean,
                                                  float* __restrict__ M) {
    __shared__ ushort KS[128 * 72];
    __shared__ float  Km[64];
    __shared__ float  mdS[128];

    const int bh = blockIdx.y;
    const int q0 = blockIdx.x * 128;
    const int t    = threadIdx.x;
    const int w    = t >> 6;
    const int lane = t & 63;
    const int quad = lane >> 4;
    const int n16  = lane & 15;

    if (t < 64) Km[t] = Kmean[bh * DH + t];
    __syncthreads();
    if (t < 128) {
        const float4* qr = (const float4*)&Qp[((size_t)bh * LL + q0 + t) * DH];
        const float4* km4 = (const float4*)Km;
        float md = 0.f;
        #pragma unroll
        for (int i = 0; i < 16; i++) {
            float4 a = qr[i], b = km4[i];
            md += a.x * b.x + a.y * b.y + a.z * b.z + a.w * b.w;
        }
        mdS[t] = md;
    }

    bf16x8 aH[2][2], aL[2][2];
    #pragma unroll
    for (int mt = 0; mt < 2; mt++) {
        const float* qrp = &Qp[((size_t)bh * LL + q0 + w * 32 + mt * 16 + n16) * DH + quad * 8];
        float v[16];
        *(float4*)&v[0]  = *(const float4*)(qrp);
        *(float4*)&v[4]  = *(const float4*)(qrp + 4);
        *(float4*)&v[8]  = *(const float4*)(qrp + 32);
        *(float4*)&v[12] = *(const float4*)(qrp + 36);
        #pragma unroll
        for (int j = 0; j < 8; j++) {
            ushort h0 = f32_to_bf16_rn(v[j]);
            aH[mt][0][j] = (short)h0;
            aL[mt][0][j] = (short)f32_to_bf16_rn(v[j] - bf16_to_f32(h0));
            ushort h1 = f32_to_bf16_rn(v[8 + j]);
            aH[mt][1][j] = (short)h1;
            aL[mt][1][j] = (short)f32_to_bf16_rn(v[8 + j] - bf16_to_f32(h1));
        }
    }

    f32x4 maxv[2] = {{-3.4e38f, -3.4e38f, -3.4e38f, -3.4e38f},
                     {-3.4e38f, -3.4e38f, -3.4e38f, -3.4e38f}};

    for (int kt0 = 0; kt0 < LL; kt0 += 128) {
        __syncthreads();
        #pragma unroll
        for (int i = 0; i < 4; i++) {
            int f = i * 256 + t;
            int row = f >> 3, c8 = f & 7;
            const uint4 v = *(const uint4*)&KH[((size_t)(bh * LL + kt0 + row)) * DH + c8 * 8];
            *(uint4*)&KS[row * 72 + c8 * 8] = v;
        }
        __syncthreads();

        for (int ktl = 0; ktl < 128; ktl += 16) {
            const ushort* bp = &KS[(size_t)(ktl + n16) * 72 + quad * 8];
            bf16x8 bH0 = *(const bf16x8*)(bp);
            bf16x8 bH1 = *(const bf16x8*)(bp + 32);
            #pragma unroll
            for (int mt = 0; mt < 2; mt++) {
                f32x4 acc = {0.f, 0.f, 0.f, 0.f};
                acc = __builtin_amdgcn_mfma_f32_16x16x32_bf16(aH[mt][0], bH0, acc, 0, 0, 0);
                acc = __builtin_amdgcn_mfma_f32_16x16x32_bf16(aH[mt][1], bH1, acc, 0, 0, 0);
                acc = __builtin_amdgcn_mfma_f32_16x16x32_bf16(aL[mt][0], bH0, acc, 0, 0, 0);
                acc = __builtin_amdgcn_mfma_f32_16x16x32_bf16(aL[mt][1], bH1, acc, 0, 0, 0);
                maxv[mt][0] = fmaxf(maxv[mt][0], acc[0]);
                maxv[mt][1] = fmaxf(maxv[mt][1], acc[1]);
                maxv[mt][2] = fmaxf(maxv[mt][2], acc[2]);
                maxv[mt][3] = fmaxf(maxv[mt][3], acc[3]);
            }
        }
    }

    #pragma unroll
    for (int off = 1; off < 16; off <<= 1)
        #pragma unroll
        for (int mt = 0; mt < 2; mt++)
            #pragma unroll
            for (int r = 0; r < 4; r++)
                maxv[mt][r] = fmaxf(maxv[mt][r], __shfl_xor(maxv[mt][r], off));

    if (n16 == 0) {
        #pragma unroll
        for (int mt = 0; mt < 2; mt++)
            #pragma unroll
            for (int r = 0; r < 4; r++) {
                int lq = w * 32 + mt * 16 + quad * 4 + r;
                M[(size_t)bh * LL + q0 + lq] = SCALEF * maxv[mt][r] - SCALEF * mdS[lq];
            }
    }
}

// ---------------------------------------------------------------------------
// Top-64 candidate pool via 3-level radix select (O(1) serial depth).
// One block per bh. Pool is order-arbitrary: select_kernel re-ranks by exact
// fp32 M with lax.top_k tie semantics. Level-3 ties span <2^-15 relative
// (< approx error 1.1e-3 << rank-38..64 margin) -> arbitrary fill is safe.
// ---------------------------------------------------------------------------
__global__ __launch_bounds__(256) void topk_radix(const float* __restrict__ M,
                                                  int* __restrict__ out_idx) {
    __shared__ unsigned hist[4096];
    __shared__ unsigned segc[256];
    __shared__ unsigned suf[256];
    __shared__ int sb1, sc1, sb2;
    __shared__ int ncnt;
    const int bh = blockIdx.x;
    const int t  = threadIdx.x;

    // load + monotonic key transform
    unsigned key[8];
    #pragma unroll
    for (int i = 0; i < 8; i++) {
        unsigned u = __float_as_uint(M[(size_t)bh * LL + i * 256 + t]);
        key[i] = (u & 0x80000000u) ? ~u : (u | 0x80000000u);
    }

    // ---- level 1: hist of bits [31:20] ----
    #pragma unroll
    for (int i = 0; i < 16; i++) hist[t * 16 + i] = 0;
    if (t == 0) ncnt = 0;
    __syncthreads();
    #pragma unroll
    for (int i = 0; i < 8; i++) atomicAdd(&hist[key[i] >> 20], 1u);
    __syncthreads();
    unsigned s = 0;
    #pragma unroll
    for (int i = 0; i < 16; i++) s += hist[t * 16 + i];
    segc[t] = s;
    __syncthreads();
    if (t == 0) {
        unsigned run = 0;
        for (int i = 255; i >= 0; i--) { suf[i] = run; run += segc[i]; }
    }
    __syncthreads();
    if (suf[t] < NCAND && suf[t] + segc[t] >= NCAND) {
        unsigned c = suf[t];
        for (int j = 15; j >= 0; j--) {
            int b = t * 16 + j;
            if (c + hist[b] >= NCAND) { sb1 = b; sc1 = (int)c; break; }
            c += hist[b];
        }
    }
    __syncthreads();
    const unsigned b1 = (unsigned)sb1;
    const int c1 = sc1;

    // ---- level 2: hist of bits [19:8] over boundary-bin members ----
    #pragma unroll
    for (int i = 0; i < 16; i++) hist[t * 16 + i] = 0;
    __syncthreads();
    #pragma unroll
    for (int i = 0; i < 8; i++)
        if ((key[i] >> 20) == b1) atomicAdd(&hist[(key[i] >> 8) & 0xfffu], 1u);
    __syncthreads();
    s = 0;
    #pragma unroll
    for (int i = 0; i < 16; i++) s += hist[t * 16 + i];
    segc[t] = s;
    __syncthreads();
    if (t == 0) {
        unsigned run = 0;
        for (int i = 255; i >= 0; i--) { suf[i] = run; run += segc[i]; }
    }
    __syncthreads();
    const int need2 = NCAND - c1;
    if ((int)suf[t] < need2 && (int)(suf[t] + segc[t]) >= need2) {
        unsigned c = suf[t];
        for (int j = 15; j >= 0; j--) {
            int b = t * 16 + j;
            if ((int)(c + hist[b]) >= need2) { sb2 = b; break; }
            c += hist[b];
        }
    }
    __syncthreads();
    const unsigned b2 = (unsigned)sb2;

    // ---- compact: 3 phases ----
    #pragma unroll
    for (int i = 0; i < 8; i++)
        if ((key[i] >> 20) > b1) {
            int p = atomicAdd(&ncnt, 1);
            out_idx[bh * NCAND + p] = i * 256 + t;
        }
    __syncthreads();
    #pragma unroll
    for (int i = 0; i < 8; i++)
        if ((key[i] >> 20) == b1 && ((key[i] >> 8) & 0xfffu) > b2) {
            int p = atomicAdd(&ncnt, 1);
            out_idx[bh * NCAND + p] = i * 256 + t;
        }
    __syncthreads();
    #pragma unroll
    for (int i = 0; i < 8; i++)
        if ((key[i] >> 20) == b1 && ((key[i] >> 8) & 0xfffu) == b2) {
            int p = atomicAdd(&ncnt, 1);
            if (p < NCAND) out_idx[bh * NCAND + p] = i * 256 + t;
        }
}

// ---------------------------------------------------------------------------
// Exact refinement phase 1: per-chunk fp32 max-dot for all 64 candidates.
// ---------------------------------------------------------------------------
__global__ __launch_bounds__(256) void exact_partial(const float* __restrict__ Qp,
                                                     const float* __restrict__ Kp,
                                                     const int* __restrict__ CAND,
                                                     float* __restrict__ EMP) {
    __shared__ float Qs[64][65];
    __shared__ float Ks[64][65];
    __shared__ int   cidx[64];
    const int bh = blockIdx.y;
    const int chunk = blockIdx.x;
    const int t = threadIdx.x;
    const int tx = t & 15, ty = t >> 4;

    if (t < 64) cidx[t] = CAND[bh * NCAND + t];
    __syncthreads();
    #pragma unroll
    for (int i = 0; i < 4; i++) {
        int f = i * 256 + t;
        int row = f >> 4, c4 = f & 15;
        const float4 v = *(const float4*)&Qp[((size_t)bh * LL + cidx[row]) * DH + c4 * 4];
        *(float4*)&Qs[row][c4 * 4] = v;
    }

    float mx[4] = {-3.4e38f, -3.4e38f, -3.4e38f, -3.4e38f};

    for (int kt = 0; kt < 4; kt++) {
        __syncthreads();
        #pragma unroll
        for (int i = 0; i < 4; i++) {
            int f = i * 256 + t;
            int row = f >> 4, c4 = f & 15;
            const float4 v = *(const float4*)&Kp[((size_t)(bh * LL + chunk * 256 + kt * 64 + row)) * DH + c4 * 4];
            *(float4*)&Ks[row][c4 * 4] = v;
        }
        __syncthreads();
        float acc[4][4] = {};
        #pragma unroll 8
        for (int dd = 0; dd < 64; dd++) {
            float a[4], b[4];
            #pragma unroll
            for (int i = 0; i < 4; i++) a[i] = Qs[ty * 4 + i][dd];
            #pragma unroll
            for (int j = 0; j < 4; j++) b[j] = Ks[tx * 4 + j][dd];
            #pragma unroll
            for (int i = 0; i < 4; i++)
                #pragma unroll
                for (int j = 0; j < 4; j++) acc[i][j] += a[i] * b[j];
        }
        #pragma unroll
        for (int i = 0; i < 4; i++)
            #pragma unroll
            for (int j = 0; j < 4; j++) mx[i] = fmaxf(mx[i], acc[i][j]);
    }

    #pragma unroll
    for (int off = 1; off < 16; off <<= 1)
        #pragma unroll
        for (int i = 0; i < 4; i++)
            mx[i] = fmaxf(mx[i], __shfl_xor(mx[i], off));

    if (tx == 0) {
        #pragma unroll
        for (int i = 0; i < 4; i++)
            EMP[((size_t)bh * NCAND + ty * 4 + i) * 8 + chunk] = mx[i];
    }
}

// ---------------------------------------------------------------------------
// Exact refinement phase 2 + final top-38. (unchanged)
// ---------------------------------------------------------------------------
__global__ __launch_bounds__(64) void select_kernel(const float* __restrict__ EMP,
                                                    const int* __restrict__ CAND,
                                                    const float* __restrict__ Qp,
                                                    const float* __restrict__ Kmean,
                                                    int* __restrict__ TIDX) {
    __shared__ float Km[64];
    const int bh = blockIdx.x;
    const int t  = threadIdx.x;
    Km[t] = Kmean[bh * DH + t];
    __syncthreads();

    const int qi = CAND[bh * NCAND + t];
    float mx = -3.4e38f;
    #pragma unroll
    for (int c = 0; c < 8; c++) mx = fmaxf(mx, EMP[((size_t)bh * NCAND + t) * 8 + c]);

    const float4* qr = (const float4*)&Qp[((size_t)bh * LL + qi) * DH];
    const float4* km4 = (const float4*)Km;
    float md = 0.f;
    #pragma unroll
    for (int i = 0; i < 16; i++) {
        float4 a = qr[i], b = km4[i];
        md += a.x * b.x + a.y * b.y + a.z * b.z + a.w * b.w;
    }
    float v = SCALEF * mx - SCALEF * md;

    for (int it = 0; it < KTOP; it++) {
        float bv = v; int bq = qi;
        #pragma unroll
        for (int off = 1; off < 64; off <<= 1) {
            float ov = __shfl_xor(bv, off);
            int   oq = __shfl_xor(bq, off);
            if (ov > bv || (ov == bv && oq < bq)) { bv = ov; bq = oq; }
        }
        if (t == 0) TIDX[bh * KTOP + it] = bq;
        if (qi == bq) v = -3.4e38f;
    }
}

// ---------------------------------------------------------------------------
// Fill context (bf16 hi/lo) with per-head V mean. (unchanged)
// ---------------------------------------------------------------------------
__global__ __launch_bounds__(256) void fill_kernel(const float* __restrict__ Vmean,
                                                   ushort* __restrict__ CH,
                                                   ushort* __restrict__ CL) {
    const size_t c = (size_t)blockIdx.x * 256 + threadIdx.x;
    const int d4 = (int)(c & 15) * 4;
    const int bh = (int)(c >> 15);
    const float4 v = *(const float4*)&Vmean[bh * DH + d4];
    ushort4 h, l;
    h.x = f32_to_bf16_rn(v.x); l.x = f32_to_bf16_rn(v.x - bf16_to_f32(h.x));
    h.y = f32_to_bf16_rn(v.y); l.y = f32_to_bf16_rn(v.y - bf16_to_f32(h.y));
    h.z = f32_to_bf16_rn(v.z); l.z = f32_to_bf16_rn(v.z - bf16_to_f32(h.z));
    h.w = f32_to_bf16_rn(v.w); l.w = f32_to_bf16_rn(v.w - bf16_to_f32(h.w));
    *(ushort4*)&CH[c * 4] = h;
    *(ushort4*)&CL[c * 4] = l;
}

// ---------------------------------------------------------------------------
// Sparse attention V3, phase 1: flash split-K MFMA partials. (unchanged)
// ---------------------------------------------------------------------------
__global__ __launch_bounds__(256) void sparse_partial(const float* __restrict__ Qp,
                                                      const ushort* __restrict__ KH,
                                                      const float* __restrict__ Vp,
                                                      const int* __restrict__ TIDX,
                                                      float* __restrict__ OPART,
                                                      float* __restrict__ MPART,
                                                      float* __restrict__ LPART) {
    __shared__ float sc[QPAD * SCS];
    __shared__ unsigned int Vhl[CHK * VST];
    const int bh = blockIdx.y;
    const int ck = blockIdx.x;
    const int k0 = ck * CHK;
    const int t = threadIdx.x;
    const int w = t >> 6, lane = t & 63;
    const int quad = lane >> 4, n16 = lane & 15;
    const int mt = w;

    #pragma unroll
    for (int i = 0; i < 8; i++) {
        int e = i * 256 + t;
        int key = e >> 4, c4 = e & 15;
        const float4 v = *(const float4*)&Vp[((size_t)(bh * LL + k0 + key)) * DH + c4 * 4];
        uint4 p;
        p.x = pack_hl(v.x); p.y = pack_hl(v.y);
        p.z = pack_hl(v.z); p.w = pack_hl(v.w);
        *(uint4*)&Vhl[key * VST + c4 * 4] = p;
    }

    if (mt < 3) {
        bf16x8 aH[2], aL[2];
        {
            int q = mt * 16 + n16;
            int qq = q < KTOP ? q : (KTOP - 1);
            const float* qp = &Qp[((size_t)bh * LL + TIDX[bh * KTOP + qq]) * DH];
            #pragma unroll
            for (int kf = 0; kf < 2; kf++) {
                float v[8];
                *(float4*)&v[0] = *(const float4*)(qp + kf * 32 + quad * 8);
                *(float4*)&v[4] = *(const float4*)(qp + kf * 32 + quad * 8 + 4);
                #pragma unroll
                for (int j = 0; j < 8; j++) {
                    ushort h = f32_to_bf16_rn(v[j]);
                    aH[kf][j] = (short)h;
                    aL[kf][j] = (short)f32_to_bf16_rn(v[j] - bf16_to_f32(h));
                }
            }
        }
        #pragma unroll
        for (int nt = 0; nt < 8; nt++) {
            f32x4 acc = {0.f, 0.f, 0.f, 0.f};
            #pragma unroll
            for (int kf = 0; kf < 2; kf++) {
                bf16x8 b = *(const bf16x8*)&KH[((size_t)(bh * LL + k0 + nt * 16 + n16)) * DH + kf * 32 + quad * 8];
                acc = __builtin_amdgcn_mfma_f32_16x16x32_bf16(aH[kf], b, acc, 0, 0, 0);
                acc = __builtin_amdgcn_mfma_f32_16x16x32_bf16(aL[kf], b, acc, 0, 0, 0);
            }
            #pragma unroll
            for (int r = 0; r < 4; r++)
                sc[(mt * 16 + quad * 4 + r) * SCS + nt * 16 + n16] = acc[r];
        }
    }
    __syncthreads();

    for (int row = w; row < KTOP; row += 4) {
        float v0 = sc[row * SCS + lane];
        float v1 = sc[row * SCS + 64 + lane];
        float m = fmaxf(v0, v1);
        #pragma unroll
        for (int off = 1; off < 64; off <<= 1)
            m = fmaxf(m, __shfl_xor(m, off));
        const float ms = m * SCALEF;
        float e0 = __expf(v0 * SCALEF - ms);
        float e1 = __expf(v1 * SCALEF - ms);
        float l = e0 + e1;
        #pragma unroll
        for (int off = 1; off < 64; off <<= 1)
            l += __shfl_xor(l, off);
        sc[row * SCS + lane]      = e0;
        sc[row * SCS + 64 + lane] = e1;
        if (lane == 0) {
            MPART[((size_t)ck * BH + bh) * KTOP + row] = ms;
            LPART[((size_t)ck * BH + bh) * KTOP + row] = l;
        }
    }
    __syncthreads();

    if (mt < 3) {
        f32x4 acc[4] = {};
        #pragma unroll
        for (int kf = 0; kf < 4; kf++) {
            bf16x8 ph, pl;
            {
                const float* pp = &sc[(mt * 16 + n16) * SCS + kf * 32 + quad * 8];
                float v[8];
                *(float4*)&v[0] = *(const float4*)(pp);
                *(float4*)&v[4] = *(const float4*)(pp + 4);
                #pragma unroll
                for (int j = 0; j < 8; j++) {
                    ushort h = f32_to_bf16_rn(v[j]);
                    ph[j] = (short)h;
                    pl[j] = (short)f32_to_bf16_rn(v[j] - bf16_to_f32(h));
                }
            }
            #pragma unroll
            for (int nt = 0; nt < 4; nt++) {
                unsigned int u[8];
                #pragma unroll
                for (int j = 0; j < 8; j++)
                    u[j] = Vhl[(kf * 32 + quad * 8 + j) * VST + nt * 16 + n16];
                bf16x8 vh, vl;
                #pragma unroll
                for (int j = 0; j < 8; j++) {
                    vh[j] = (short)(u[j] & 0xffffu);
                    vl[j] = (short)(u[j] >> 16);
                }
                acc[nt] = __builtin_amdgcn_mfma_f32_16x16x32_bf16(ph, vh, acc[nt], 0, 0, 0);
                acc[nt] = __builtin_amdgcn_mfma_f32_16x16x32_bf16(ph, vl, acc[nt], 0, 0, 0);
                acc[nt] = __builtin_amdgcn_mfma_f32_16x16x32_bf16(pl, vh, acc[nt], 0, 0, 0);
            }
        }
        #pragma unroll
        for (int nt = 0; nt < 4; nt++)
            #pragma unroll
            for (int r = 0; r < 4; r++) {
                int q = mt * 16 + quad * 4 + r;
                if (q < KTOP)
                    OPART[(((size_t)ck * BH + bh) * KTOP + q) * DH + nt * 16 + n16] = acc[nt][r];
            }
    }
}

// ---------------------------------------------------------------------------
// Sparse attention V3, phase 2: split-K softmax merge -> CH/CL rows.
// ---------------------------------------------------------------------------
__global__ __launch_bounds__(256) void sparse_combine(const float* __restrict__ OPART,
                                                      const float* __restrict__ MPART,
                                                      const float* __restrict__ LPART,
                                                      const int* __restrict__ TIDX,
                                                      ushort* __restrict__ CH,
                                                      ushort* __restrict__ CL) {
    __shared__ float wts[NSP][KTOP];
    __shared__ float inv[KTOP];
    __shared__ int   tq[KTOP];
    const int bh = blockIdx.x;
    const int t  = threadIdx.x;
    if (t < KTOP) {
        float m[NSP];
        float mx = -3.4e38f;
        #pragma unroll
        for (int c = 0; c < NSP; c++) {
            m[c] = MPART[((size_t)c * BH + bh) * KTOP + t];
            mx = fmaxf(mx, m[c]);
        }
        float L = 0.f;
        #pragma unroll
        for (int c = 0; c < NSP; c++) {
            float wc = __expf(m[c] - mx);
            wts[c][t] = wc;
            L += wc * LPART[((size_t)c * BH + bh) * KTOP + t];
        }
        inv[t] = 1.0f / L;
        tq[t] = TIDX[bh * KTOP + t];
    }
    __syncthreads();
    for (int i = 0; i < 10; i++) {
        int idx = i * 256 + t;
        if (idx >= KTOP * DH) break;
        int q = idx >> 6, d = idx & 63;
        float o = 0.f;
        #pragma unroll
        for (int c = 0; c < NSP; c++)
            o += wts[c][q] * OPART[(((size_t)c * BH + bh) * KTOP + q) * DH + d];
        float val = o * inv[q];
        size_t off = ((size_t)bh * LL + tq[q]) * DH + d;
        ushort h = f32_to_bf16_rn(val);
        CH[off] = h;
        CL[off] = f32_to_bf16_rn(val - bf16_to_f32(h));
    }
}

// ---------------------------------------------------------------------------
extern "C" void kernel_launch(void* const* d_in, const int* in_sizes, int n_in,
                              void* d_out, int out_size, void* d_ws, size_t ws_size,
                              hipStream_t stream) {
    const float* x  = (const float*)d_in[0];
    const float* Wq = (const float*)d_in[1];
    const float* bq = (const float*)d_in[2];
    const float* Wk = (const float*)d_in[3];
    const float* bk = (const float*)d_in[4];
    const float* Wv = (const float*)d_in[5];
    const float* bv = (const float*)d_in[6];
    const float* Wo = (const float*)d_in[7];
    const float* bo = (const float*)d_in[8];
    float* out = (float*)d_out;

    float* ws = (float*)d_ws;
    const size_t QSZ = (size_t)BH * LL * DH;   // 4,194,304 elements
    float* Qp    = ws;
    float* Kp    = ws + QSZ;
    float* Vp    = ws + 2 * QSZ;
    float* Mp    = ws + 3 * QSZ;               // BH*L
    float* KMEAN = Mp + (size_t)BH * LL;
    float* VMEAN = KMEAN + BH * DH;
    int*   CAND  = (int*)(VMEAN + BH * DH);    // BH*NCAND
    int*   TIDX  = CAND + BH * NCAND;          // BH*KTOP
    float* EMP   = (float*)(TIDX + BH * KTOP); // BH*NCAND*8
    float* MEANP = EMP + (size_t)BH * NCAND * 8;  // 64*16*64
    ushort* WTH  = (ushort*)(ws + 3 * QSZ + 262144);   // 4 x 512x512 bf16 hi
    ushort* WTL  = WTH + (size_t)4 * DD * DD;
    ushort* XH   = WTL + (size_t)4 * DD * DD;          // x split hi
    ushort* XL   = XH + QSZ;
    ushort* CH   = XH;                                 // CTX aliases X
    ushort* CL   = XL;
    ushort* KH   = XL + QSZ;                           // K split hi
    float* OPART = (float*)(KH + QSZ);                 // NSP*BH*KTOP*DH
    float* MPART = OPART + (size_t)NSP * BH * KTOP * DH;
    float* LPART = MPART + (size_t)NSP * BH * KTOP;
    const size_t WOFF = (size_t)DD * DD;

    split_wT<<<dim3(16, 16, 4), 256, 0, stream>>>(Wq, Wk, Wv, Wo, WTH, WTL);
    split_x<<<(int)(QSZ / 1024), 256, 0, stream>>>(x, XH, XL);

    const dim3 gemm_grid(DD / 64, (BB * LL) / 128);    // (8, 64)
    mfma_gemm<0, 1, 0><<<gemm_grid, 256, 0, stream>>>(XH, XL, WTH,            WTL,            bq, Qp, nullptr);
    mfma_gemm<0, 1, 1><<<gemm_grid, 256, 0, stream>>>(XH, XL, WTH + WOFF,     WTL + WOFF,     bk, Kp, KH);
    mfma_gemm<0, 1, 0><<<gemm_grid, 256, 0, stream>>>(XH, XL, WTH + 2 * WOFF, WTL + 2 * WOFF, bv, Vp, nullptr);

    mean_partial<<<dim3(BH, 2, 16), 256, 0, stream>>>(Kp, Vp, MEANP);
    mean_reduce<<<dim3(BH, 2), 64, 0, stream>>>(MEANP, KMEAN, VMEAN);

    mfma_stats<<<dim3(LL / 128, BH), 256, 0, stream>>>(Qp, KH, KMEAN, Mp);

    topk_radix<<<BH, 256, 0, stream>>>(Mp, CAND);

    exact_partial<<<dim3(8, BH), 256, 0, stream>>>(Qp, Kp, CAND, EMP);

    select_kernel<<<BH, 64, 0, stream>>>(EMP, CAND, Qp, KMEAN, TIDX);

    fill_kernel<<<(int)(QSZ / 1024), 256, 0, stream>>>(VMEAN, CH, CL);

    sparse_partial<<<dim3(NSP, BH), 256, 0, stream>>>(Qp, KH, Vp, TIDX, OPART, MPART, LPART);
    sparse_combine<<<BH, 256, 0, stream>>>(OPART, MPART, LPART, TIDX, CH, CL);

    mfma_gemm<1, 0, 0><<<gemm_grid, 256, 0, stream>>>(CH, CL, WTH + 3 * WOFF, WTL + 3 * WOFF, bo, out, nullptr);
}

// Round 9
// 301.546 us; speedup vs baseline: 3.9583x; 1.1124x over previous
//
#include <hip/hip_runtime.h>

#define BB   4
#define LL   2048
#define DD   512
#define HH   8
#define DH   64
#define BH   32          // B*H
#define KTOP 38
#define NCAND 64         // approx-M candidate pool for exact refinement
#define SCALEF 0.125f    // 1/sqrt(64)

// sparse flash split-K params
#define NSP  16          // key chunks
#define CHK  128         // keys per chunk (LL/NSP)
#define QPAD 48          // queries padded to 3 m-tiles
#define SCS  132         // sc row stride (floats)
#define VST  66          // Vhl row stride (uints)

typedef __attribute__((ext_vector_type(8))) short bf16x8;
typedef __attribute__((ext_vector_type(8))) unsigned short ushort8;
typedef __attribute__((ext_vector_type(4))) float f32x4;

__device__ __forceinline__ ushort f32_to_bf16_rn(float x) {
    unsigned u = __float_as_uint(x);
    u += 0x7fffu + ((u >> 16) & 1u);
    return (ushort)(u >> 16);
}
__device__ __forceinline__ float bf16_to_f32(ushort h) {
    return __uint_as_float(((unsigned)h) << 16);
}
__device__ __forceinline__ unsigned int pack_hl(float x) {
    ushort h = f32_to_bf16_rn(x);
    ushort l = f32_to_bf16_rn(x - bf16_to_f32(h));
    return ((unsigned int)l << 16) | (unsigned int)h;
}

// ---------------------------------------------------------------------------
// Elementwise split: fp32 array -> bf16 hi + lo arrays (layout-preserving).
// ---------------------------------------------------------------------------
__global__ __launch_bounds__(256) void split_x(const float* __restrict__ X,
                                               ushort* __restrict__ XH,
                                               ushort* __restrict__ XL) {
    const size_t c = (size_t)blockIdx.x * 256 + threadIdx.x;
    const float4 v = *(const float4*)&X[c * 4];
    ushort4 h, l;
    h.x = f32_to_bf16_rn(v.x); l.x = f32_to_bf16_rn(v.x - bf16_to_f32(h.x));
    h.y = f32_to_bf16_rn(v.y); l.y = f32_to_bf16_rn(v.y - bf16_to_f32(h.y));
    h.z = f32_to_bf16_rn(v.z); l.z = f32_to_bf16_rn(v.z - bf16_to_f32(h.z));
    h.w = f32_to_bf16_rn(v.w); l.w = f32_to_bf16_rn(v.w - bf16_to_f32(h.w));
    *(ushort4*)&XH[c * 4] = h;
    *(ushort4*)&XL[c * 4] = l;
}

// ---------------------------------------------------------------------------
// Prep: transpose + split 4 weight matrices W[k][n] into WT_H/WT_L [n][k] bf16.
// ---------------------------------------------------------------------------
__global__ __launch_bounds__(256) void split_wT(const float* __restrict__ W0,
                                                const float* __restrict__ W1,
                                                const float* __restrict__ W2,
                                                const float* __restrict__ W3,
                                                ushort* __restrict__ WTH,
                                                ushort* __restrict__ WTL) {
    __shared__ float tile[32][33];
    const int z = blockIdx.z;
    const float* W = (z == 0) ? W0 : (z == 1) ? W1 : (z == 2) ? W2 : W3;
    ushort* oh = WTH + (size_t)z * DD * DD;
    ushort* ol = WTL + (size_t)z * DD * DD;
    const int n0 = blockIdx.x * 32, k0 = blockIdx.y * 32;
    const int t = threadIdx.x;
    const int r = t >> 5, c = t & 31;
    #pragma unroll
    for (int i = 0; i < 4; i++)
        tile[r + i * 8][c] = W[(size_t)(k0 + r + i * 8) * DD + n0 + c];
    __syncthreads();
    #pragma unroll
    for (int i = 0; i < 4; i++) {
        int row = r + i * 8;
        float v = tile[c][row];
        ushort h = f32_to_bf16_rn(v);
        oh[(size_t)(n0 + row) * DD + k0 + c] = h;
        ol[(size_t)(n0 + row) * DD + k0 + c] = f32_to_bf16_rn(v - bf16_to_f32(h));
    }
}

// ---------------------------------------------------------------------------
// FUSED QKV projection GEMM: Y{q,k,v} = x @ W{q,k,v} + b{q,k,v}.
// N = 1536 (3 matrices side by side in WTH/WTL). Grid (24, 64) = 1536 blocks
// (6/CU -> 3x latency hiding vs 3 separate 512-block launches).
// z = n0/512 selects output tensor & bias (wave-uniform). K-output also
// writes bf16-hi (KH) for the stats/sparse kernels.
// ---------------------------------------------------------------------------
__global__ __launch_bounds__(256) void mfma_gemm_qkv(const ushort* __restrict__ AH,
                                                     const ushort* __restrict__ AL,
                                                     const ushort* __restrict__ BTH,
                                                     const ushort* __restrict__ BTL,
                                                     const float* __restrict__ bq,
                                                     const float* __restrict__ bk,
                                                     const float* __restrict__ bv,
                                                     float* __restrict__ Qp,
                                                     float* __restrict__ Kp,
                                                     float* __restrict__ Vp,
                                                     ushort* __restrict__ KH) {
    __shared__ ushort BHs[64 * 40];
    __shared__ ushort BLs[64 * 40];

    const int t = threadIdx.x;
    const int w = t >> 6, lane = t & 63;
    const int quad = lane >> 4, n16 = lane & 15;
    const int row0 = blockIdx.y * 128;
    const int n0   = blockIdx.x * 64;        // 0..1472
    const int z    = n0 >> 9;                // 0=Q 1=K 2=V
    const int nloc0 = n0 & 511;

    const float* bias = (z == 0) ? bq : (z == 1) ? bk : bv;
    float* Y          = (z == 0) ? Qp : (z == 1) ? Kp : Vp;

    f32x4 acc[2][4] = {};

    size_t arow_off[2];
    #pragma unroll
    for (int mt = 0; mt < 2; mt++)
        arow_off[mt] = (size_t)(row0 + w * 32 + mt * 16 + n16) * DD;

    const int brow = t >> 2, bc8 = t & 3;
    const size_t bbase = (size_t)z * DD * DD;

    for (int k0 = 0; k0 < DD; k0 += 32) {
        {
            const size_t goff = bbase + (size_t)(nloc0 + brow) * DD + k0 + bc8 * 8;
            const uint4 vh = *(const uint4*)&BTH[goff];
            const uint4 vl = *(const uint4*)&BTL[goff];
            *(uint4*)&BHs[brow * 40 + bc8 * 8] = vh;
            *(uint4*)&BLs[brow * 40 + bc8 * 8] = vl;
        }
        bf16x8 ah[2], al[2];
        #pragma unroll
        for (int mt = 0; mt < 2; mt++) {
            size_t off = arow_off[mt] + k0 + quad * 8;
            ah[mt] = *(const bf16x8*)&AH[off];
            al[mt] = *(const bf16x8*)&AL[off];
        }
        __syncthreads();

        bf16x8 bh[4], bl[4];
        #pragma unroll
        for (int nt = 0; nt < 4; nt++) {
            int off = (nt * 16 + n16) * 40 + quad * 8;
            bh[nt] = *(const bf16x8*)&BHs[off];
            bl[nt] = *(const bf16x8*)&BLs[off];
        }
        #pragma unroll
        for (int mt = 0; mt < 2; mt++)
            #pragma unroll
            for (int nt = 0; nt < 4; nt++) {
                acc[mt][nt] = __builtin_amdgcn_mfma_f32_16x16x32_bf16(ah[mt], bh[nt], acc[mt][nt], 0, 0, 0);
                acc[mt][nt] = __builtin_amdgcn_mfma_f32_16x16x32_bf16(ah[mt], bl[nt], acc[mt][nt], 0, 0, 0);
                acc[mt][nt] = __builtin_amdgcn_mfma_f32_16x16x32_bf16(al[mt], bh[nt], acc[mt][nt], 0, 0, 0);
            }
        __syncthreads();
    }

    #pragma unroll
    for (int mt = 0; mt < 2; mt++)
        #pragma unroll
        for (int nt = 0; nt < 4; nt++) {
            const int c = nloc0 + nt * 16 + n16;       // 0..511 within tensor
            const float bvv = bias[c];
            const int h = c >> 6, dh = c & 63;
            #pragma unroll
            for (int r = 0; r < 4; r++) {
                int R = row0 + w * 32 + mt * 16 + quad * 4 + r;
                int b = R >> 11, l = R & 2047;
                float v = acc[mt][nt][r] + bvv;
                size_t off = (((size_t)(b * HH + h)) * LL + l) * DH + dh;
                Y[off] = v;
                if (z == 1) KH[off] = f32_to_bf16_rn(v);
            }
        }
}

// ---------------------------------------------------------------------------
// Output GEMM (unchanged structure): out = ctx @ Wo + bo.
// ---------------------------------------------------------------------------
__global__ __launch_bounds__(256) void mfma_gemm_out(const ushort* __restrict__ AH,
                                                     const ushort* __restrict__ AL,
                                                     const ushort* __restrict__ BTH,
                                                     const ushort* __restrict__ BTL,
                                                     const float* __restrict__ bias,
                                                     float* __restrict__ Y) {
    __shared__ ushort BHs[64 * 40];
    __shared__ ushort BLs[64 * 40];

    const int t = threadIdx.x;
    const int w = t >> 6, lane = t & 63;
    const int quad = lane >> 4, n16 = lane & 15;
    const int row0 = blockIdx.y * 128;
    const int n0   = blockIdx.x * 64;

    f32x4 acc[2][4] = {};

    size_t arow_off[2];
    #pragma unroll
    for (int mt = 0; mt < 2; mt++) {
        int R = row0 + w * 32 + mt * 16 + n16;
        int b = R >> 11, l = R & 2047;
        arow_off[mt] = ((size_t)b * HH) * LL * DH + (size_t)l * DH;
    }

    const int brow = t >> 2, bc8 = t & 3;

    for (int k0 = 0; k0 < DD; k0 += 32) {
        {
            const size_t goff = (size_t)(n0 + brow) * DD + k0 + bc8 * 8;
            const uint4 vh = *(const uint4*)&BTH[goff];
            const uint4 vl = *(const uint4*)&BTL[goff];
            *(uint4*)&BHs[brow * 40 + bc8 * 8] = vh;
            *(uint4*)&BLs[brow * 40 + bc8 * 8] = vl;
        }
        bf16x8 ah[2], al[2];
        #pragma unroll
        for (int mt = 0; mt < 2; mt++) {
            int k = k0 + quad * 8;
            int h = k >> 6, dh = k & 63;
            size_t off = arow_off[mt] + (size_t)h * LL * DH + dh;
            ah[mt] = *(const bf16x8*)&AH[off];
            al[mt] = *(const bf16x8*)&AL[off];
        }
        __syncthreads();

        bf16x8 bh[4], bl[4];
        #pragma unroll
        for (int nt = 0; nt < 4; nt++) {
            int off = (nt * 16 + n16) * 40 + quad * 8;
            bh[nt] = *(const bf16x8*)&BHs[off];
            bl[nt] = *(const bf16x8*)&BLs[off];
        }
        #pragma unroll
        for (int mt = 0; mt < 2; mt++)
            #pragma unroll
            for (int nt = 0; nt < 4; nt++) {
                acc[mt][nt] = __builtin_amdgcn_mfma_f32_16x16x32_bf16(ah[mt], bh[nt], acc[mt][nt], 0, 0, 0);
                acc[mt][nt] = __builtin_amdgcn_mfma_f32_16x16x32_bf16(ah[mt], bl[nt], acc[mt][nt], 0, 0, 0);
                acc[mt][nt] = __builtin_amdgcn_mfma_f32_16x16x32_bf16(al[mt], bh[nt], acc[mt][nt], 0, 0, 0);
            }
        __syncthreads();
    }

    #pragma unroll
    for (int mt = 0; mt < 2; mt++)
        #pragma unroll
        for (int nt = 0; nt < 4; nt++) {
            const int c = n0 + nt * 16 + n16;
            const float bvv = bias[c];
            #pragma unroll
            for (int r = 0; r < 4; r++) {
                int R = row0 + w * 32 + mt * 16 + quad * 4 + r;
                Y[(size_t)R * DD + c] = acc[mt][nt][r] + bvv;
            }
        }
}

// ---------------------------------------------------------------------------
// Mean phase 1: partial sums. grid (BH, 2, 16); block sums 128 rows.
// ---------------------------------------------------------------------------
__global__ __launch_bounds__(256) void mean_partial(const float* __restrict__ Kp,
                                                    const float* __restrict__ Vp,
                                                    float* __restrict__ partial) {
    __shared__ float red[256];
    const int bh = blockIdx.x;
    const int srcI = blockIdx.y;
    const int z  = blockIdx.z;
    const float* src = srcI ? Vp : Kp;
    const int t = threadIdx.x;
    const int d = t & 63, ch = t >> 6;
    const int l0 = z * 128 + ch * 32;
    float s = 0.f;
    for (int l = l0; l < l0 + 32; l++)
        s += src[((size_t)bh * LL + l) * DH + d];
    red[t] = s;
    __syncthreads();
    if (t < 64)
        partial[((size_t)((bh * 2 + srcI) * 16 + z)) * 64 + t] =
            red[t] + red[t + 64] + red[t + 128] + red[t + 192];
}

// ---------------------------------------------------------------------------
// Mean phase 2: fold 16 partials. grid (BH, 2), 64 thr.
// ---------------------------------------------------------------------------
__global__ __launch_bounds__(64) void mean_reduce(const float* __restrict__ partial,
                                                  float* __restrict__ Kmean,
                                                  float* __restrict__ Vmean) {
    const int bh = blockIdx.x;
    const int srcI = blockIdx.y;
    const int t  = threadIdx.x;
    float s = 0.f;
    #pragma unroll
    for (int z = 0; z < 16; z++)
        s += partial[((size_t)((bh * 2 + srcI) * 16 + z)) * 64 + t];
    float* dst = srcI ? Vmean : Kmean;
    dst[bh * DH + t] = s * (1.0f / LL);
}

// ---------------------------------------------------------------------------
// Approx M, split-K: grid (16, BH, 2). Each block: 128 queries x 1024 keys.
// Writes MP[z][bh][q] = SCALEF * chunk-max; z==0 also writes
// MMD[bh][q] = SCALEF * (Q.Kmean). topk_radix folds M = max(MP0,MP1) - MMD.
// ---------------------------------------------------------------------------
__global__ __launch_bounds__(256) void mfma_stats(const float* __restrict__ Qp,
                                                  const ushort* __restrict__ KH,
                                                  const float* __restrict__ Kmean,
                                                  float* __restrict__ MP,
                                                  float* __restrict__ MMD) {
    __shared__ ushort KS[128 * 72];
    __shared__ float  Km[64];

    const int bh = blockIdx.y;
    const int q0 = blockIdx.x * 128;
    const int z  = blockIdx.z;
    const int t    = threadIdx.x;
    const int w    = t >> 6;
    const int lane = t & 63;
    const int quad = lane >> 4;
    const int n16  = lane & 15;

    if (z == 0) {
        if (t < 64) Km[t] = Kmean[bh * DH + t];
        __syncthreads();
        if (t < 128) {
            const float4* qr = (const float4*)&Qp[((size_t)bh * LL + q0 + t) * DH];
            const float4* km4 = (const float4*)Km;
            float md = 0.f;
            #pragma unroll
            for (int i = 0; i < 16; i++) {
                float4 a = qr[i], b = km4[i];
                md += a.x * b.x + a.y * b.y + a.z * b.z + a.w * b.w;
            }
            MMD[(size_t)bh * LL + q0 + t] = SCALEF * md;
        }
    }

    bf16x8 aH[2][2], aL[2][2];
    #pragma unroll
    for (int mt = 0; mt < 2; mt++) {
        const float* qrp = &Qp[((size_t)bh * LL + q0 + w * 32 + mt * 16 + n16) * DH + quad * 8];
        float v[16];
        *(float4*)&v[0]  = *(const float4*)(qrp);
        *(float4*)&v[4]  = *(const float4*)(qrp + 4);
        *(float4*)&v[8]  = *(const float4*)(qrp + 32);
        *(float4*)&v[12] = *(const float4*)(qrp + 36);
        #pragma unroll
        for (int j = 0; j < 8; j++) {
            ushort h0 = f32_to_bf16_rn(v[j]);
            aH[mt][0][j] = (short)h0;
            aL[mt][0][j] = (short)f32_to_bf16_rn(v[j] - bf16_to_f32(h0));
            ushort h1 = f32_to_bf16_rn(v[8 + j]);
            aH[mt][1][j] = (short)h1;
            aL[mt][1][j] = (short)f32_to_bf16_rn(v[8 + j] - bf16_to_f32(h1));
        }
    }

    f32x4 maxv[2] = {{-3.4e38f, -3.4e38f, -3.4e38f, -3.4e38f},
                     {-3.4e38f, -3.4e38f, -3.4e38f, -3.4e38f}};

    const int kbase = z * (LL / 2);
    for (int kt0 = kbase; kt0 < kbase + LL / 2; kt0 += 128) {
        __syncthreads();
        #pragma unroll
        for (int i = 0; i < 4; i++) {
            int f = i * 256 + t;
            int row = f >> 3, c8 = f & 7;
            const uint4 v = *(const uint4*)&KH[((size_t)(bh * LL + kt0 + row)) * DH + c8 * 8];
            *(uint4*)&KS[row * 72 + c8 * 8] = v;
        }
        __syncthreads();

        for (int ktl = 0; ktl < 128; ktl += 16) {
            const ushort* bp = &KS[(size_t)(ktl + n16) * 72 + quad * 8];
            bf16x8 bH0 = *(const bf16x8*)(bp);
            bf16x8 bH1 = *(const bf16x8*)(bp + 32);
            #pragma unroll
            for (int mt = 0; mt < 2; mt++) {
                f32x4 acc = {0.f, 0.f, 0.f, 0.f};
                acc = __builtin_amdgcn_mfma_f32_16x16x32_bf16(aH[mt][0], bH0, acc, 0, 0, 0);
                acc = __builtin_amdgcn_mfma_f32_16x16x32_bf16(aH[mt][1], bH1, acc, 0, 0, 0);
                acc = __builtin_amdgcn_mfma_f32_16x16x32_bf16(aL[mt][0], bH0, acc, 0, 0, 0);
                acc = __builtin_amdgcn_mfma_f32_16x16x32_bf16(aL[mt][1], bH1, acc, 0, 0, 0);
                maxv[mt][0] = fmaxf(maxv[mt][0], acc[0]);
                maxv[mt][1] = fmaxf(maxv[mt][1], acc[1]);
                maxv[mt][2] = fmaxf(maxv[mt][2], acc[2]);
                maxv[mt][3] = fmaxf(maxv[mt][3], acc[3]);
            }
        }
    }

    #pragma unroll
    for (int off = 1; off < 16; off <<= 1)
        #pragma unroll
        for (int mt = 0; mt < 2; mt++)
            #pragma unroll
            for (int r = 0; r < 4; r++)
                maxv[mt][r] = fmaxf(maxv[mt][r], __shfl_xor(maxv[mt][r], off));

    if (n16 == 0) {
        #pragma unroll
        for (int mt = 0; mt < 2; mt++)
            #pragma unroll
            for (int r = 0; r < 4; r++) {
                int lq = w * 32 + mt * 16 + quad * 4 + r;
                MP[((size_t)z * BH + bh) * LL + q0 + lq] = SCALEF * maxv[mt][r];
            }
    }
}

// ---------------------------------------------------------------------------
// Top-64 candidate pool via 3-level radix select. Folds split-K stats:
// M = max(MP0, MP1) - MMD at load.
// ---------------------------------------------------------------------------
__global__ __launch_bounds__(256) void topk_radix(const float* __restrict__ MP,
                                                  const float* __restrict__ MMD,
                                                  int* __restrict__ out_idx) {
    __shared__ unsigned hist[4096];
    __shared__ unsigned segc[256];
    __shared__ unsigned suf[256];
    __shared__ int sb1, sc1, sb2;
    __shared__ int ncnt;
    const int bh = blockIdx.x;
    const int t  = threadIdx.x;

    unsigned key[8];
    #pragma unroll
    for (int i = 0; i < 8; i++) {
        size_t q = (size_t)i * 256 + t;
        float v = fmaxf(MP[(size_t)bh * LL + q], MP[((size_t)BH + bh) * LL + q])
                  - MMD[(size_t)bh * LL + q];
        unsigned u = __float_as_uint(v);
        key[i] = (u & 0x80000000u) ? ~u : (u | 0x80000000u);
    }

    #pragma unroll
    for (int i = 0; i < 16; i++) hist[t * 16 + i] = 0;
    if (t == 0) ncnt = 0;
    __syncthreads();
    #pragma unroll
    for (int i = 0; i < 8; i++) atomicAdd(&hist[key[i] >> 20], 1u);
    __syncthreads();
    unsigned s = 0;
    #pragma unroll
    for (int i = 0; i < 16; i++) s += hist[t * 16 + i];
    segc[t] = s;
    __syncthreads();
    if (t == 0) {
        unsigned run = 0;
        for (int i = 255; i >= 0; i--) { suf[i] = run; run += segc[i]; }
    }
    __syncthreads();
    if (suf[t] < NCAND && suf[t] + segc[t] >= NCAND) {
        unsigned c = suf[t];
        for (int j = 15; j >= 0; j--) {
            int b = t * 16 + j;
            if (c + hist[b] >= NCAND) { sb1 = b; sc1 = (int)c; break; }
            c += hist[b];
        }
    }
    __syncthreads();
    const unsigned b1 = (unsigned)sb1;
    const int c1 = sc1;

    #pragma unroll
    for (int i = 0; i < 16; i++) hist[t * 16 + i] = 0;
    __syncthreads();
    #pragma unroll
    for (int i = 0; i < 8; i++)
        if ((key[i] >> 20) == b1) atomicAdd(&hist[(key[i] >> 8) & 0xfffu], 1u);
    __syncthreads();
    s = 0;
    #pragma unroll
    for (int i = 0; i < 16; i++) s += hist[t * 16 + i];
    segc[t] = s;
    __syncthreads();
    if (t == 0) {
        unsigned run = 0;
        for (int i = 255; i >= 0; i--) { suf[i] = run; run += segc[i]; }
    }
    __syncthreads();
    const int need2 = NCAND - c1;
    if ((int)suf[t] < need2 && (int)(suf[t] + segc[t]) >= need2) {
        unsigned c = suf[t];
        for (int j = 15; j >= 0; j--) {
            int b = t * 16 + j;
            if ((int)(c + hist[b]) >= need2) { sb2 = b; break; }
            c += hist[b];
        }
    }
    __syncthreads();
    const unsigned b2 = (unsigned)sb2;

    #pragma unroll
    for (int i = 0; i < 8; i++)
        if ((key[i] >> 20) > b1) {
            int p = atomicAdd(&ncnt, 1);
            out_idx[bh * NCAND + p] = i * 256 + t;
        }
    __syncthreads();
    #pragma unroll
    for (int i = 0; i < 8; i++)
        if ((key[i] >> 20) == b1 && ((key[i] >> 8) & 0xfffu) > b2) {
            int p = atomicAdd(&ncnt, 1);
            out_idx[bh * NCAND + p] = i * 256 + t;
        }
    __syncthreads();
    #pragma unroll
    for (int i = 0; i < 8; i++)
        if ((key[i] >> 20) == b1 && ((key[i] >> 8) & 0xfffu) == b2) {
            int p = atomicAdd(&ncnt, 1);
            if (p < NCAND) out_idx[bh * NCAND + p] = i * 256 + t;
        }
}

// ---------------------------------------------------------------------------
// Exact refinement phase 1: per-chunk fp32 max-dot for all 64 candidates.
// ---------------------------------------------------------------------------
__global__ __launch_bounds__(256) void exact_partial(const float* __restrict__ Qp,
                                                     const float* __restrict__ Kp,
                                                     const int* __restrict__ CAND,
                                                     float* __restrict__ EMP) {
    __shared__ float Qs[64][65];
    __shared__ float Ks[64][65];
    __shared__ int   cidx[64];
    const int bh = blockIdx.y;
    const int chunk = blockIdx.x;
    const int t = threadIdx.x;
    const int tx = t & 15, ty = t >> 4;

    if (t < 64) cidx[t] = CAND[bh * NCAND + t];
    __syncthreads();
    #pragma unroll
    for (int i = 0; i < 4; i++) {
        int f = i * 256 + t;
        int row = f >> 4, c4 = f & 15;
        const float4 v = *(const float4*)&Qp[((size_t)bh * LL + cidx[row]) * DH + c4 * 4];
        *(float4*)&Qs[row][c4 * 4] = v;
    }

    float mx[4] = {-3.4e38f, -3.4e38f, -3.4e38f, -3.4e38f};

    for (int kt = 0; kt < 4; kt++) {
        __syncthreads();
        #pragma unroll
        for (int i = 0; i < 4; i++) {
            int f = i * 256 + t;
            int row = f >> 4, c4 = f & 15;
            const float4 v = *(const float4*)&Kp[((size_t)(bh * LL + chunk * 256 + kt * 64 + row)) * DH + c4 * 4];
            *(float4*)&Ks[row][c4 * 4] = v;
        }
        __syncthreads();
        float acc[4][4] = {};
        #pragma unroll 8
        for (int dd = 0; dd < 64; dd++) {
            float a[4], b[4];
            #pragma unroll
            for (int i = 0; i < 4; i++) a[i] = Qs[ty * 4 + i][dd];
            #pragma unroll
            for (int j = 0; j < 4; j++) b[j] = Ks[tx * 4 + j][dd];
            #pragma unroll
            for (int i = 0; i < 4; i++)
                #pragma unroll
                for (int j = 0; j < 4; j++) acc[i][j] += a[i] * b[j];
        }
        #pragma unroll
        for (int i = 0; i < 4; i++)
            #pragma unroll
            for (int j = 0; j < 4; j++) mx[i] = fmaxf(mx[i], acc[i][j]);
    }

    #pragma unroll
    for (int off = 1; off < 16; off <<= 1)
        #pragma unroll
        for (int i = 0; i < 4; i++)
            mx[i] = fmaxf(mx[i], __shfl_xor(mx[i], off));

    if (tx == 0) {
        #pragma unroll
        for (int i = 0; i < 4; i++)
            EMP[((size_t)bh * NCAND + ty * 4 + i) * 8 + chunk] = mx[i];
    }
}

// ---------------------------------------------------------------------------
// Exact refinement phase 2 + final top-38. (unchanged)
// ---------------------------------------------------------------------------
__global__ __launch_bounds__(64) void select_kernel(const float* __restrict__ EMP,
                                                    const int* __restrict__ CAND,
                                                    const float* __restrict__ Qp,
                                                    const float* __restrict__ Kmean,
                                                    int* __restrict__ TIDX) {
    __shared__ float Km[64];
    const int bh = blockIdx.x;
    const int t  = threadIdx.x;
    Km[t] = Kmean[bh * DH + t];
    __syncthreads();

    const int qi = CAND[bh * NCAND + t];
    float mx = -3.4e38f;
    #pragma unroll
    for (int c = 0; c < 8; c++) mx = fmaxf(mx, EMP[((size_t)bh * NCAND + t) * 8 + c]);

    const float4* qr = (const float4*)&Qp[((size_t)bh * LL + qi) * DH];
    const float4* km4 = (const float4*)Km;
    float md = 0.f;
    #pragma unroll
    for (int i = 0; i < 16; i++) {
        float4 a = qr[i], b = km4[i];
        md += a.x * b.x + a.y * b.y + a.z * b.z + a.w * b.w;
    }
    float v = SCALEF * mx - SCALEF * md;

    for (int it = 0; it < KTOP; it++) {
        float bv = v; int bq = qi;
        #pragma unroll
        for (int off = 1; off < 64; off <<= 1) {
            float ov = __shfl_xor(bv, off);
            int   oq = __shfl_xor(bq, off);
            if (ov > bv || (ov == bv && oq < bq)) { bv = ov; bq = oq; }
        }
        if (t == 0) TIDX[bh * KTOP + it] = bq;
        if (qi == bq) v = -3.4e38f;
    }
}

// ---------------------------------------------------------------------------
// Fill context (bf16 hi/lo) with per-head V mean. (unchanged)
// ---------------------------------------------------------------------------
__global__ __launch_bounds__(256) void fill_kernel(const float* __restrict__ Vmean,
                                                   ushort* __restrict__ CH,
                                                   ushort* __restrict__ CL) {
    const size_t c = (size_t)blockIdx.x * 256 + threadIdx.x;
    const int d4 = (int)(c & 15) * 4;
    const int bh = (int)(c >> 15);
    const float4 v = *(const float4*)&Vmean[bh * DH + d4];
    ushort4 h, l;
    h.x = f32_to_bf16_rn(v.x); l.x = f32_to_bf16_rn(v.x - bf16_to_f32(h.x));
    h.y = f32_to_bf16_rn(v.y); l.y = f32_to_bf16_rn(v.y - bf16_to_f32(h.y));
    h.z = f32_to_bf16_rn(v.z); l.z = f32_to_bf16_rn(v.z - bf16_to_f32(h.z));
    h.w = f32_to_bf16_rn(v.w); l.w = f32_to_bf16_rn(v.w - bf16_to_f32(h.w));
    *(ushort4*)&CH[c * 4] = h;
    *(ushort4*)&CL[c * 4] = l;
}

// ---------------------------------------------------------------------------
// Sparse attention, phase 1: flash split-K MFMA partials. (unchanged)
// ---------------------------------------------------------------------------
__global__ __launch_bounds__(256) void sparse_partial(const float* __restrict__ Qp,
                                                      const ushort* __restrict__ KH,
                                                      const float* __restrict__ Vp,
                                                      const int* __restrict__ TIDX,
                                                      float* __restrict__ OPART,
                                                      float* __restrict__ MPART,
                                                      float* __restrict__ LPART) {
    __shared__ float sc[QPAD * SCS];
    __shared__ unsigned int Vhl[CHK * VST];
    const int bh = blockIdx.y;
    const int ck = blockIdx.x;
    const int k0 = ck * CHK;
    const int t = threadIdx.x;
    const int w = t >> 6, lane = t & 63;
    const int quad = lane >> 4, n16 = lane & 15;
    const int mt = w;

    #pragma unroll
    for (int i = 0; i < 8; i++) {
        int e = i * 256 + t;
        int key = e >> 4, c4 = e & 15;
        const float4 v = *(const float4*)&Vp[((size_t)(bh * LL + k0 + key)) * DH + c4 * 4];
        uint4 p;
        p.x = pack_hl(v.x); p.y = pack_hl(v.y);
        p.z = pack_hl(v.z); p.w = pack_hl(v.w);
        *(uint4*)&Vhl[key * VST + c4 * 4] = p;
    }

    if (mt < 3) {
        bf16x8 aH[2], aL[2];
        {
            int q = mt * 16 + n16;
            int qq = q < KTOP ? q : (KTOP - 1);
            const float* qp = &Qp[((size_t)bh * LL + TIDX[bh * KTOP + qq]) * DH];
            #pragma unroll
            for (int kf = 0; kf < 2; kf++) {
                float v[8];
                *(float4*)&v[0] = *(const float4*)(qp + kf * 32 + quad * 8);
                *(float4*)&v[4] = *(const float4*)(qp + kf * 32 + quad * 8 + 4);
                #pragma unroll
                for (int j = 0; j < 8; j++) {
                    ushort h = f32_to_bf16_rn(v[j]);
                    aH[kf][j] = (short)h;
                    aL[kf][j] = (short)f32_to_bf16_rn(v[j] - bf16_to_f32(h));
                }
            }
        }
        #pragma unroll
        for (int nt = 0; nt < 8; nt++) {
            f32x4 acc = {0.f, 0.f, 0.f, 0.f};
            #pragma unroll
            for (int kf = 0; kf < 2; kf++) {
                bf16x8 b = *(const bf16x8*)&KH[((size_t)(bh * LL + k0 + nt * 16 + n16)) * DH + kf * 32 + quad * 8];
                acc = __builtin_amdgcn_mfma_f32_16x16x32_bf16(aH[kf], b, acc, 0, 0, 0);
                acc = __builtin_amdgcn_mfma_f32_16x16x32_bf16(aL[kf], b, acc, 0, 0, 0);
            }
            #pragma unroll
            for (int r = 0; r < 4; r++)
                sc[(mt * 16 + quad * 4 + r) * SCS + nt * 16 + n16] = acc[r];
        }
    }
    __syncthreads();

    for (int row = w; row < KTOP; row += 4) {
        float v0 = sc[row * SCS + lane];
        float v1 = sc[row * SCS + 64 + lane];
        float m = fmaxf(v0, v1);
        #pragma unroll
        for (int off = 1; off < 64; off <<= 1)
            m = fmaxf(m, __shfl_xor(m, off));
        const float ms = m * SCALEF;
        float e0 = __expf(v0 * SCALEF - ms);
        float e1 = __expf(v1 * SCALEF - ms);
        float l = e0 + e1;
        #pragma unroll
        for (int off = 1; off < 64; off <<= 1)
            l += __shfl_xor(l, off);
        sc[row * SCS + lane]      = e0;
        sc[row * SCS + 64 + lane] = e1;
        if (lane == 0) {
            MPART[((size_t)ck * BH + bh) * KTOP + row] = ms;
            LPART[((size_t)ck * BH + bh) * KTOP + row] = l;
        }
    }
    __syncthreads();

    if (mt < 3) {
        f32x4 acc[4] = {};
        #pragma unroll
        for (int kf = 0; kf < 4; kf++) {
            bf16x8 ph, pl;
            {
                const float* pp = &sc[(mt * 16 + n16) * SCS + kf * 32 + quad * 8];
                float v[8];
                *(float4*)&v[0] = *(const float4*)(pp);
                *(float4*)&v[4] = *(const float4*)(pp + 4);
                #pragma unroll
                for (int j = 0; j < 8; j++) {
                    ushort h = f32_to_bf16_rn(v[j]);
                    ph[j] = (short)h;
                    pl[j] = (short)f32_to_bf16_rn(v[j] - bf16_to_f32(h));
                }
            }
            #pragma unroll
            for (int nt = 0; nt < 4; nt++) {
                unsigned int u[8];
                #pragma unroll
                for (int j = 0; j < 8; j++)
                    u[j] = Vhl[(kf * 32 + quad * 8 + j) * VST + nt * 16 + n16];
                bf16x8 vh, vl;
                #pragma unroll
                for (int j = 0; j < 8; j++) {
                    vh[j] = (short)(u[j] & 0xffffu);
                    vl[j] = (short)(u[j] >> 16);
                }
                acc[nt] = __builtin_amdgcn_mfma_f32_16x16x32_bf16(ph, vh, acc[nt], 0, 0, 0);
                acc[nt] = __builtin_amdgcn_mfma_f32_16x16x32_bf16(ph, vl, acc[nt], 0, 0, 0);
                acc[nt] = __builtin_amdgcn_mfma_f32_16x16x32_bf16(pl, vh, acc[nt], 0, 0, 0);
            }
        }
        #pragma unroll
        for (int nt = 0; nt < 4; nt++)
            #pragma unroll
            for (int r = 0; r < 4; r++) {
                int q = mt * 16 + quad * 4 + r;
                if (q < KTOP)
                    OPART[(((size_t)ck * BH + bh) * KTOP + q) * DH + nt * 16 + n16] = acc[nt][r];
            }
    }
}

// ---------------------------------------------------------------------------
// Sparse attention, phase 2: split-K softmax merge -> CH/CL rows. (unchanged)
// ---------------------------------------------------------------------------
__global__ __launch_bounds__(256) void sparse_combine(const float* __restrict__ OPART,
                                                      const float* __restrict__ MPART,
                                                      const float* __restrict__ LPART,
                                                      const int* __restrict__ TIDX,
                                                      ushort* __restrict__ CH,
                                                      ushort* __restrict__ CL) {
    __shared__ float wts[NSP][KTOP];
    __shared__ float inv[KTOP];
    __shared__ int   tq[KTOP];
    const int bh = blockIdx.x;
    const int t  = threadIdx.x;
    if (t < KTOP) {
        float m[NSP];
        float mx = -3.4e38f;
        #pragma unroll
        for (int c = 0; c < NSP; c++) {
            m[c] = MPART[((size_t)c * BH + bh) * KTOP + t];
            mx = fmaxf(mx, m[c]);
        }
        float L = 0.f;
        #pragma unroll
        for (int c = 0; c < NSP; c++) {
            float wc = __expf(m[c] - mx);
            wts[c][t] = wc;
            L += wc * LPART[((size_t)c * BH + bh) * KTOP + t];
        }
        inv[t] = 1.0f / L;
        tq[t] = TIDX[bh * KTOP + t];
    }
    __syncthreads();
    for (int i = 0; i < 10; i++) {
        int idx = i * 256 + t;
        if (idx >= KTOP * DH) break;
        int q = idx >> 6, d = idx & 63;
        float o = 0.f;
        #pragma unroll
        for (int c = 0; c < NSP; c++)
            o += wts[c][q] * OPART[(((size_t)c * BH + bh) * KTOP + q) * DH + d];
        float val = o * inv[q];
        size_t off = ((size_t)bh * LL + tq[q]) * DH + d;
        ushort h = f32_to_bf16_rn(val);
        CH[off] = h;
        CL[off] = f32_to_bf16_rn(val - bf16_to_f32(h));
    }
}

// ---------------------------------------------------------------------------
extern "C" void kernel_launch(void* const* d_in, const int* in_sizes, int n_in,
                              void* d_out, int out_size, void* d_ws, size_t ws_size,
                              hipStream_t stream) {
    const float* x  = (const float*)d_in[0];
    const float* Wq = (const float*)d_in[1];
    const float* bq = (const float*)d_in[2];
    const float* Wk = (const float*)d_in[3];
    const float* bk = (const float*)d_in[4];
    const float* Wv = (const float*)d_in[5];
    const float* bv = (const float*)d_in[6];
    const float* Wo = (const float*)d_in[7];
    const float* bo = (const float*)d_in[8];
    float* out = (float*)d_out;

    float* ws = (float*)d_ws;
    const size_t QSZ = (size_t)BH * LL * DH;   // 4,194,304 elements
    float* Qp    = ws;
    float* Kp    = ws + QSZ;
    float* Vp    = ws + 2 * QSZ;
    float* MMD   = ws + 3 * QSZ;               // BH*L  (SCALEF * Q.Kmean)
    float* KMEAN = MMD + (size_t)BH * LL;
    float* VMEAN = KMEAN + BH * DH;
    int*   CAND  = (int*)(VMEAN + BH * DH);    // BH*NCAND
    int*   TIDX  = CAND + BH * NCAND;          // BH*KTOP
    float* EMP   = (float*)(TIDX + BH * KTOP); // BH*NCAND*8
    float* MEANP = EMP + (size_t)BH * NCAND * 8;  // 64*16*64
    float* MP    = MEANP + 65536;              // 2*BH*LL (split-K stats maxes)
    ushort* WTH  = (ushort*)(ws + 3 * QSZ + 524288);   // 4 x 512x512 bf16 hi
    ushort* WTL  = WTH + (size_t)4 * DD * DD;
    ushort* XH   = WTL + (size_t)4 * DD * DD;          // x split hi
    ushort* XL   = XH + QSZ;
    ushort* CH   = XH;                                 // CTX aliases X
    ushort* CL   = XL;
    ushort* KH   = XL + QSZ;                           // K split hi
    float* OPART = (float*)(KH + QSZ);                 // NSP*BH*KTOP*DH
    float* MPART = OPART + (size_t)NSP * BH * KTOP * DH;
    float* LPART = MPART + (size_t)NSP * BH * KTOP;
    const size_t WOFF = (size_t)DD * DD;

    split_wT<<<dim3(16, 16, 4), 256, 0, stream>>>(Wq, Wk, Wv, Wo, WTH, WTL);
    split_x<<<(int)(QSZ / 1024), 256, 0, stream>>>(x, XH, XL);

    // fused QKV projection: grid (1536/64, 8192/128) = (24, 64)
    mfma_gemm_qkv<<<dim3(24, 64), 256, 0, stream>>>(XH, XL, WTH, WTL,
                                                    bq, bk, bv, Qp, Kp, Vp, KH);

    mean_partial<<<dim3(BH, 2, 16), 256, 0, stream>>>(Kp, Vp, MEANP);
    mean_reduce<<<dim3(BH, 2), 64, 0, stream>>>(MEANP, KMEAN, VMEAN);

    mfma_stats<<<dim3(16, BH, 2), 256, 0, stream>>>(Qp, KH, KMEAN, MP, MMD);

    topk_radix<<<BH, 256, 0, stream>>>(MP, MMD, CAND);

    exact_partial<<<dim3(8, BH), 256, 0, stream>>>(Qp, Kp, CAND, EMP);

    select_kernel<<<BH, 64, 0, stream>>>(EMP, CAND, Qp, KMEAN, TIDX);

    fill_kernel<<<(int)(QSZ / 1024), 256, 0, stream>>>(VMEAN, CH, CL);

    sparse_partial<<<dim3(NSP, BH), 256, 0, stream>>>(Qp, KH, Vp, TIDX, OPART, MPART, LPART);
    sparse_combine<<<BH, 256, 0, stream>>>(OPART, MPART, LPART, TIDX, CH, CL);

    mfma_gemm_out<<<dim3(8, 64), 256, 0, stream>>>(CH, CL, WTH + 3 * WOFF, WTL + 3 * WOFF, bo, out);
}